// Round 1
// baseline (983.565 us; speedup 1.0000x reference)
//
#include <hip/hip_runtime.h>
#include <math.h>

#define N_NODES 20000
#define N_EDGES 40000
#define SE 46
#define TE 82
// D = 128, 4D = 512, F = 256, HID = 128

__device__ __forceinline__ float sigf(float x){ return 1.0f/(1.0f+__expf(-x)); }

// ---------------- transpose: out[c*R+r] = in[r*C+c] ----------------
__global__ void k_transpose(const float* __restrict__ in, float* __restrict__ out, int R, int C){
  int i = blockIdx.x*blockDim.x + threadIdx.x;
  if (i < R*C){ int r = i / C, c = i - r*C; out[c*R + r] = in[i]; }
}

// ---------------- edge features + pre = scores @ Wih^T + bih ----------------
__global__ void k_edge(const int* __restrict__ heads, const int* __restrict__ rels,
                       const int* __restrict__ tails, const float* __restrict__ weeks,
                       const float* __restrict__ ent, const float* __restrict__ rel_embs,
                       const float* __restrict__ wfreq, const float* __restrict__ wphi,
                       const float* __restrict__ wamp,
                       const float* __restrict__ WihT, const float* __restrict__ bih,
                       float* __restrict__ pre){
  __shared__ float s[8][128];
  int e0 = blockIdx.x * 8;
  int tid = threadIdx.x;
  #pragma unroll
  for (int q=0;q<4;q++){
    int idx = tid + 256*q;
    int el = idx >> 7, d = idx & 127;
    int e = e0 + el;
    int hd = heads[e], tl = tails[e], rl = rels[e];
    float wk = weeks[e];
    float hv, tv;
    if (d < SE){
      hv = ent[(size_t)hd*SE + d];
      tv = ent[(size_t)tl*SE + d];
    } else {
      int dt = d - SE;
      hv = wamp[(size_t)hd*TE+dt] * sinf(wfreq[(size_t)hd*TE+dt]*wk + wphi[(size_t)hd*TE+dt]);
      tv = wamp[(size_t)tl*TE+dt] * sinf(wfreq[(size_t)tl*TE+dt]*wk + wphi[(size_t)tl*TE+dt]);
    }
    float rv = rel_embs[rl*128 + d];
    s[el][d] = hv * rv * tv;
  }
  __syncthreads();
  float acc0[8], acc1[8];
  #pragma unroll
  for (int e=0;e<8;e++){ acc0[e]=0.f; acc1[e]=0.f; }
  for (int k=0;k<128;k++){
    float w0 = WihT[k*512 + tid];
    float w1 = WihT[k*512 + tid + 256];
    #pragma unroll
    for (int e=0;e<8;e++){
      float sv = s[e][k];
      acc0[e] += w0*sv; acc1[e] += w1*sv;
    }
  }
  float b0 = bih[tid], b1 = bih[tid+256];
  #pragma unroll
  for (int e=0;e<8;e++){
    pre[(size_t)(e0+e)*512 + tid]       = acc0[e] + b0;
    pre[(size_t)(e0+e)*512 + tid + 256] = acc1[e] + b1;
  }
}

// ---------------- grouping machinery ----------------
__global__ void k_hist(const int* __restrict__ src, const int* __restrict__ dst,
                       int* __restrict__ scnt, int* __restrict__ dcnt){
  int e = blockIdx.x*blockDim.x + threadIdx.x;
  if (e < N_EDGES){ atomicAdd(&scnt[src[e]],1); atomicAdd(&dcnt[dst[e]],1); }
}

__global__ void k_scan(const int* __restrict__ scnt, const int* __restrict__ dcnt,
                       int* __restrict__ sstart, int* __restrict__ dstart){
  const int* cnt = blockIdx.x ? dcnt : scnt;
  int* start = blockIdx.x ? dstart : sstart;
  __shared__ int buf[1024];
  __shared__ int carry_s;
  if (threadIdx.x==0) carry_s = 0;
  __syncthreads();
  for (int base=0; base<N_NODES; base+=1024){
    int i = base + threadIdx.x;
    int v = (i<N_NODES)? cnt[i] : 0;
    buf[threadIdx.x] = v;
    __syncthreads();
    for (int off=1; off<1024; off<<=1){
      int t = (threadIdx.x>=off) ? buf[threadIdx.x-off] : 0;
      __syncthreads();
      buf[threadIdx.x] += t;
      __syncthreads();
    }
    int incl = buf[threadIdx.x];
    int carry = carry_s;
    if (i < N_NODES) start[i] = carry + incl - v;
    __syncthreads();
    if (threadIdx.x == 1023) carry_s = carry + incl;
    __syncthreads();
  }
  if (threadIdx.x==0) start[N_NODES] = carry_s;
}

__global__ void k_scatter(const int* __restrict__ src, const int* __restrict__ dst,
                          const int* __restrict__ sstart, const int* __restrict__ dstart,
                          int* __restrict__ sc2, int* __restrict__ dc2,
                          int* __restrict__ slist, int* __restrict__ dlist){
  int e = blockIdx.x*blockDim.x + threadIdx.x;
  if (e < N_EDGES){
    int s = src[e]; int p  = sstart[s] + atomicAdd(&sc2[s],1); slist[p]=e;
    int d = dst[e]; int p2 = dstart[d] + atomicAdd(&dc2[d],1); dlist[p2]=e;
  }
}

__global__ void k_sortlists(const int* __restrict__ sstart, const int* __restrict__ dstart,
                            int* __restrict__ slist, int* __restrict__ dlist){
  int n = blockIdx.x*blockDim.x + threadIdx.x;
  if (n < N_NODES){
    #pragma unroll
    for (int pass=0; pass<2; pass++){
      const int* st = pass ? dstart : sstart;
      int* ls = pass ? dlist : slist;
      int a = st[n], b = st[n+1];
      for (int i=a+1;i<b;i++){
        int v = ls[i]; int j=i-1;
        while (j>=a && ls[j]>v){ ls[j+1]=ls[j]; j--; }
        ls[j+1]=v;
      }
    }
  }
}

// ---------------- segmented LSTM: one wave per node chain ----------------
__global__ void k_lstm(const float* __restrict__ pre, const float* __restrict__ WhhT,
                       const float* __restrict__ bhh, const int* __restrict__ start,
                       const int* __restrict__ list, float* __restrict__ emb){
  __shared__ float hb[4][128];
  int wv = threadIdx.x >> 6, lane = threadIdx.x & 63;
  int node = blockIdx.x*4 + wv;
  if (node >= N_NODES) return;
  int s = start[node], cnt = start[node+1]-s;
  if (cnt == 0) return;
  float* h = hb[wv];
  h[lane] = 0.f; h[lane+64] = 0.f;
  float c0=0.f, c1=0.f;
  float bh[8];
  #pragma unroll
  for (int q=0;q<8;q++) bh[q] = bhh[lane + 64*q];
  float h0=0.f, h1=0.f;
  for (int t=0;t<cnt;t++){
    int e = list[s+t];
    const float* p = pre + (size_t)e*512;
    float g[8];
    #pragma unroll
    for (int q=0;q<8;q++) g[q] = p[lane+64*q] + bh[q];
    for (int k=0;k<128;k++){
      float hk = h[k];
      #pragma unroll
      for (int q=0;q<8;q++) g[q] += WhhT[k*512 + lane + 64*q] * hk;
    }
    float i0=sigf(g[0]), i1=sigf(g[1]), f0=sigf(g[2]), f1=sigf(g[3]);
    float t0=tanhf(g[4]), t1=tanhf(g[5]), o0=sigf(g[6]), o1=sigf(g[7]);
    c0 = f0*c0 + i0*t0; c1 = f1*c1 + i1*t1;
    h0 = o0*tanhf(c0); h1 = o1*tanhf(c1);
    h[lane]=h0; h[lane+64]=h1;
  }
  emb[(size_t)node*128 + lane]      = h0;
  emb[(size_t)node*128 + lane + 64] = h1;
}

// ---------------- final MLP + LayerNorm + out ----------------
__global__ void k_mlp(const float* __restrict__ x, const float* __restrict__ emb,
                      const float* __restrict__ fc1wT, const float* __restrict__ fc1b,
                      const float* __restrict__ lng, const float* __restrict__ lnb,
                      const float* __restrict__ outw, const float* __restrict__ outb,
                      float* __restrict__ out){
  int n = blockIdx.x, tid = threadIdx.x;
  __shared__ float xc[384];
  __shared__ float red[128];
  xc[tid]     = x[(size_t)n*256 + tid];
  xc[tid+128] = x[(size_t)n*256 + 128 + tid];
  xc[tid+256] = emb[(size_t)n*128 + tid];
  __syncthreads();
  float acc = fc1b[tid];
  for (int k=0;k<384;k++) acc += fc1wT[k*128+tid]*xc[k];
  red[tid]=acc; __syncthreads();
  for (int off=64;off>0;off>>=1){ if (tid<off) red[tid]+=red[tid+off]; __syncthreads(); }
  float mu = red[0]*(1.f/128.f); __syncthreads();
  float dm = acc-mu;
  red[tid]=dm*dm; __syncthreads();
  for (int off=64;off>0;off>>=1){ if (tid<off) red[tid]+=red[tid+off]; __syncthreads(); }
  float var = red[0]*(1.f/128.f); __syncthreads();
  float h1 = dm * rsqrtf(var+1e-5f)*lng[tid]+lnb[tid];
  h1 = fmaxf(h1,0.f);
  red[tid] = h1*outw[tid]; __syncthreads();
  for (int off=64;off>0;off>>=1){ if (tid<off) red[tid]+=red[tid+off]; __syncthreads(); }
  if (tid==0) out[(size_t)n*2] = red[0]+outb[0];
  __syncthreads();
  red[tid] = h1*outw[128+tid]; __syncthreads();
  for (int off=64;off>0;off>>=1){ if (tid<off) red[tid]+=red[tid+off]; __syncthreads(); }
  if (tid==0) out[(size_t)n*2+1] = red[0]+outb[1];
}

extern "C" void kernel_launch(void* const* d_in, const int* in_sizes, int n_in,
                              void* d_out, int out_size, void* d_ws, size_t ws_size,
                              hipStream_t stream){
  const float* x      = (const float*)d_in[0];
  const int*   heads  = (const int*)d_in[1];
  const int*   rels   = (const int*)d_in[2];
  const int*   tails  = (const int*)d_in[3];
  const float* weeks  = (const float*)d_in[4];
  const int*   esrc   = (const int*)d_in[5];
  const int*   edst   = (const int*)d_in[6];
  const float* ent    = (const float*)d_in[10];
  const float* rel_e  = (const float*)d_in[11];
  const float* wfreq  = (const float*)d_in[12];
  const float* wphi   = (const float*)d_in[13];
  const float* wamp   = (const float*)d_in[14];
  const float* Wih    = (const float*)d_in[15];
  const float* Whh    = (const float*)d_in[16];
  const float* bih    = (const float*)d_in[17];
  const float* bhh    = (const float*)d_in[18];
  const float* fc1w   = (const float*)d_in[19];
  const float* fc1b   = (const float*)d_in[20];
  const float* lng    = (const float*)d_in[21];
  const float* lnb    = (const float*)d_in[22];
  const float* outw   = (const float*)d_in[23];
  const float* outb   = (const float*)d_in[24];
  float* out = (float*)d_out;

  char* ws = (char*)d_ws;
  size_t off = 0;
  auto alloc = [&](size_t bytes){ void* p = ws + off; off += (bytes + 255) & ~(size_t)255; return p; };
  float* pre    = (float*)alloc((size_t)N_EDGES*512*4);
  float* WihT   = (float*)alloc(512*128*4);
  float* WhhT   = (float*)alloc(512*128*4);
  float* fc1wT  = (float*)alloc(384*128*4);
  float* emb    = (float*)alloc((size_t)N_NODES*128*4);
  int* sstart   = (int*)alloc((N_NODES+1)*4);
  int* dstart   = (int*)alloc((N_NODES+1)*4);
  int* cnts     = (int*)alloc((size_t)4*N_NODES*4);
  int* scnt = cnts, *dcnt = cnts+N_NODES, *sc2 = cnts+2*N_NODES, *dc2 = cnts+3*N_NODES;
  int* slist    = (int*)alloc(N_EDGES*4);
  int* dlist    = (int*)alloc(N_EDGES*4);

  hipMemsetAsync(cnts, 0, (size_t)4*N_NODES*4, stream);
  hipMemsetAsync(emb, 0, (size_t)N_NODES*128*4, stream);

  k_transpose<<<(512*128+255)/256, 256, 0, stream>>>(Wih, WihT, 512, 128);
  k_transpose<<<(512*128+255)/256, 256, 0, stream>>>(Whh, WhhT, 512, 128);
  k_transpose<<<(128*384+255)/256, 256, 0, stream>>>(fc1w, fc1wT, 128, 384);

  k_edge<<<N_EDGES/8, 256, 0, stream>>>(heads, rels, tails, weeks, ent, rel_e,
                                        wfreq, wphi, wamp, WihT, bih, pre);
  k_hist<<<(N_EDGES+255)/256, 256, 0, stream>>>(esrc, edst, scnt, dcnt);
  k_scan<<<2, 1024, 0, stream>>>(scnt, dcnt, sstart, dstart);
  k_scatter<<<(N_EDGES+255)/256, 256, 0, stream>>>(esrc, edst, sstart, dstart, sc2, dc2, slist, dlist);
  k_sortlists<<<(N_NODES+255)/256, 256, 0, stream>>>(sstart, dstart, slist, dlist);
  k_lstm<<<(N_NODES+3)/4, 256, 0, stream>>>(pre, WhhT, bhh, sstart, slist, emb);
  k_lstm<<<(N_NODES+3)/4, 256, 0, stream>>>(pre, WhhT, bhh, dstart, dlist, emb);
  k_mlp<<<N_NODES, 128, 0, stream>>>(x, emb, fc1wT, fc1b, lng, lnb, outw, outb, out);
}

// Round 2
// 801.021 us; speedup vs baseline: 1.2279x; 1.2279x over previous
//
#include <hip/hip_runtime.h>
#include <math.h>

#define N_NODES 20000
#define N_EDGES 40000
#define SE 46
#define TE 82
// D = 128, 4D = 512, F = 256, HID = 128

__device__ __forceinline__ float sigf(float x){ return 1.0f/(1.0f+__expf(-x)); }
__device__ __forceinline__ float tanh_f(float x){ return 1.0f - 2.0f/(__expf(2.0f*x)+1.0f); }
__device__ __forceinline__ int perm_out(int i){ return (i&3)*128 + (i>>2); }

// ---------------- plain transpose: out[c*R+r] = in[r*C+c] ----------------
__global__ void k_transpose(const float* __restrict__ in, float* __restrict__ out, int R, int C){
  int i = blockIdx.x*blockDim.x + threadIdx.x;
  if (i < R*C){ int r = i / C, c = i - r*C; out[c*R + r] = in[i]; }
}

// gate-interleaved transpose: out[k*512 + i] = in[perm(i)*128 + k], perm(i)=(i&3)*128+(i>>2)
__global__ void k_transperm(const float* __restrict__ in, float* __restrict__ out){
  int idx = blockIdx.x*blockDim.x + threadIdx.x;
  if (idx < 512*128){
    int k = idx >> 9, i = idx & 511;
    out[idx] = in[perm_out(i)*128 + k];
  }
}

// ---------------- edge features + pre2 = permuted(scores @ Wih^T + bih) ----------------
__global__ void k_edge(const int* __restrict__ heads, const int* __restrict__ rels,
                       const int* __restrict__ tails, const float* __restrict__ weeks,
                       const float* __restrict__ ent, const float* __restrict__ rel_embs,
                       const float* __restrict__ wfreq, const float* __restrict__ wphi,
                       const float* __restrict__ wamp,
                       const float* __restrict__ WihT2, const float* __restrict__ bih,
                       float* __restrict__ pre2){
  __shared__ float s2[128][16];   // s2[k][edge]
  int e0 = blockIdx.x * 16;
  int tid = threadIdx.x;
  #pragma unroll
  for (int q=0;q<8;q++){
    int idx = tid + 256*q;          // 0..2047
    int el = idx >> 7, d = idx & 127;
    int e = e0 + el;
    int hd = heads[e], tl = tails[e], rl = rels[e];
    float wk = weeks[e];
    float hv, tv;
    if (d < SE){
      hv = ent[(size_t)hd*SE + d];
      tv = ent[(size_t)tl*SE + d];
    } else {
      int dt = d - SE;
      hv = wamp[(size_t)hd*TE+dt] * __sinf(wfreq[(size_t)hd*TE+dt]*wk + wphi[(size_t)hd*TE+dt]);
      tv = wamp[(size_t)tl*TE+dt] * __sinf(wfreq[(size_t)tl*TE+dt]*wk + wphi[(size_t)tl*TE+dt]);
    }
    float rv = rel_embs[rl*128 + d];
    s2[d][el] = hv * rv * tv;
  }
  __syncthreads();
  float acc0[16], acc1[16];
  #pragma unroll
  for (int e=0;e<16;e++){ acc0[e]=0.f; acc1[e]=0.f; }
  for (int k=0;k<128;k++){
    float w0 = WihT2[k*512 + tid];
    float w1 = WihT2[k*512 + tid + 256];
    const float4* sp = (const float4*)&s2[k][0];
    float4 sa = sp[0], sb = sp[1], sc = sp[2], sd = sp[3];
    float sv[16] = {sa.x,sa.y,sa.z,sa.w, sb.x,sb.y,sb.z,sb.w,
                    sc.x,sc.y,sc.z,sc.w, sd.x,sd.y,sd.z,sd.w};
    #pragma unroll
    for (int e=0;e<16;e++){ acc0[e] += w0*sv[e]; acc1[e] += w1*sv[e]; }
  }
  float b0 = bih[perm_out(tid)], b1 = bih[perm_out(tid+256)];
  #pragma unroll
  for (int e=0;e<16;e++){
    pre2[(size_t)(e0+e)*512 + tid]       = acc0[e] + b0;
    pre2[(size_t)(e0+e)*512 + tid + 256] = acc1[e] + b1;
  }
}

// ---------------- grouping machinery ----------------
__global__ void k_hist(const int* __restrict__ src, const int* __restrict__ dst,
                       int* __restrict__ scnt, int* __restrict__ dcnt){
  int e = blockIdx.x*blockDim.x + threadIdx.x;
  if (e < N_EDGES){ atomicAdd(&scnt[src[e]],1); atomicAdd(&dcnt[dst[e]],1); }
}

__global__ void k_scan(const int* __restrict__ scnt, const int* __restrict__ dcnt,
                       int* __restrict__ sstart, int* __restrict__ dstart){
  const int* cnt = blockIdx.x ? dcnt : scnt;
  int* start = blockIdx.x ? dstart : sstart;
  __shared__ int buf[1024];
  __shared__ int carry_s;
  if (threadIdx.x==0) carry_s = 0;
  __syncthreads();
  for (int base=0; base<N_NODES; base+=1024){
    int i = base + threadIdx.x;
    int v = (i<N_NODES)? cnt[i] : 0;
    buf[threadIdx.x] = v;
    __syncthreads();
    for (int off=1; off<1024; off<<=1){
      int t = (threadIdx.x>=off) ? buf[threadIdx.x-off] : 0;
      __syncthreads();
      buf[threadIdx.x] += t;
      __syncthreads();
    }
    int incl = buf[threadIdx.x];
    int carry = carry_s;
    if (i < N_NODES) start[i] = carry + incl - v;
    __syncthreads();
    if (threadIdx.x == 1023) carry_s = carry + incl;
    __syncthreads();
  }
  if (threadIdx.x==0) start[N_NODES] = carry_s;
}

__global__ void k_scatter(const int* __restrict__ src, const int* __restrict__ dst,
                          const int* __restrict__ sstart, const int* __restrict__ dstart,
                          int* __restrict__ sc2, int* __restrict__ dc2,
                          int* __restrict__ slist, int* __restrict__ dlist){
  int e = blockIdx.x*blockDim.x + threadIdx.x;
  if (e < N_EDGES){
    int s = src[e]; int p  = sstart[s] + atomicAdd(&sc2[s],1); slist[p]=e;
    int d = dst[e]; int p2 = dstart[d] + atomicAdd(&dc2[d],1); dlist[p2]=e;
  }
}

__global__ void k_sortlists(const int* __restrict__ sstart, const int* __restrict__ dstart,
                            int* __restrict__ slist, int* __restrict__ dlist){
  int n = blockIdx.x*blockDim.x + threadIdx.x;
  if (n < N_NODES){
    #pragma unroll
    for (int pass=0; pass<2; pass++){
      const int* st = pass ? dstart : sstart;
      int* ls = pass ? dlist : slist;
      int a = st[n], b = st[n+1];
      for (int i=a+1;i<b;i++){
        int v = ls[i]; int j=i-1;
        while (j>=a && ls[j]>v){ ls[j+1]=ls[j]; j--; }
        ls[j+1]=v;
      }
    }
  }
}

// ---------------- chain compaction: counting-sort chains by length desc ----------------
__global__ void k_chainhist(const int* __restrict__ sstart, const int* __restrict__ dstart,
                            int* __restrict__ lenhist){
  int n = blockIdx.x*blockDim.x + threadIdx.x;
  if (n < N_NODES){
    int c = sstart[n+1]-sstart[n];
    if (c>0) atomicAdd(&lenhist[min(c,63)],1);
    int c2 = dstart[n+1]-dstart[n];
    if (c2>0) atomicAdd(&lenhist[64+min(c2,63)],1);
  }
}

__global__ void k_lenscan(const int* __restrict__ lenhist, int* __restrict__ off,
                          int* __restrict__ nchains){
  if (threadIdx.x==0 && blockIdx.x==0){
    for (int p=0;p<2;p++){
      int run = 0;
      for (int l=63;l>=1;l--){ off[p*64+l] = run; run += lenhist[p*64+l]; }
      nchains[p] = run;
    }
  }
}

__global__ void k_chainscatter(const int* __restrict__ sstart, const int* __restrict__ dstart,
                               const int* __restrict__ off, int* __restrict__ cur,
                               int* __restrict__ cnode, int* __restrict__ cstart,
                               int* __restrict__ clen){
  int n = blockIdx.x*blockDim.x + threadIdx.x;
  if (n >= N_NODES) return;
  #pragma unroll
  for (int p=0;p<2;p++){
    const int* st = p ? dstart : sstart;
    int a = st[n], c = st[n+1]-a;
    if (c>0){
      int l = min(c,63);
      int pos = off[p*64+l] + atomicAdd(&cur[p*64+l],1);
      cnode [p*N_NODES+pos] = n;
      cstart[p*N_NODES+pos] = a;
      clen  [p*N_NODES+pos] = c;
    }
  }
}

// ---------------- batched segmented LSTM: 8 chains per block, both passes ----------------
// wave w owns dims d = w*32 + (lane&31); lanes 0-31 -> chains 0-3, lanes 32-63 -> chains 4-7
__global__ void k_lstm2(const float* __restrict__ pre2, const float* __restrict__ WhhT2,
                        const float* __restrict__ bhh,
                        const int* __restrict__ cnode, const int* __restrict__ cstart,
                        const int* __restrict__ clen, const int* __restrict__ nchains,
                        const int* __restrict__ slist, const int* __restrict__ dlist,
                        const int* __restrict__ dcnt, float* __restrict__ emb){
  __shared__ float hbuf[128][8];
  int b = blockIdx.x;
  int pass = (b >= 2500) ? 1 : 0;
  int batch = pass ? (b - 2500) : b;
  int nch = nchains[pass];
  int b0 = batch*8;
  if (b0 >= nch) return;
  const int* list = pass ? dlist : slist;
  int nact = min(8, nch - b0);
  int tid = threadIdx.x;
  int lane = tid & 63, wv = tid >> 6;
  int d = wv*32 + (lane & 31);
  int j0 = (lane >> 5) * 4;
  int st[4], ln[4], nd[4];
  #pragma unroll
  for (int jj=0;jj<4;jj++){
    int j = j0+jj;
    bool v = (j < nact);
    int ci = pass*N_NODES + b0 + j;
    st[jj] = v ? cstart[ci] : 0;
    ln[jj] = v ? clen[ci]   : 0;
    nd[jj] = v ? cnode[ci]  : -1;
  }
  int ml = max(max(ln[0],ln[1]), max(ln[2],ln[3]));
  ml = max(ml, __shfl_xor(ml, 32));
  for (int i=tid; i<128*8; i+=256) ((float*)hbuf)[i] = 0.f;
  float bv[4];
  #pragma unroll
  for (int g=0; g<4; g++) bv[g] = bhh[g*128 + d];
  float cst[4] = {0.f,0.f,0.f,0.f};
  __syncthreads();

  for (int t=0; t<ml; t++){
    float acc[4][4];
    int ej[4];
    #pragma unroll
    for (int jj=0;jj<4;jj++){
      ej[jj] = (t < ln[jj]) ? list[st[jj]+t] : -1;
      if (ej[jj] >= 0){
        float4 pv = *(const float4*)&pre2[(size_t)ej[jj]*512 + d*4];
        acc[jj][0] = pv.x + bv[0]; acc[jj][1] = pv.y + bv[1];
        acc[jj][2] = pv.z + bv[2]; acc[jj][3] = pv.w + bv[3];
      } else {
        acc[jj][0]=acc[jj][1]=acc[jj][2]=acc[jj][3]=0.f;
      }
    }
    for (int k=0;k<128;k++){
      float4 hv = *(const float4*)&hbuf[k][j0];
      float4 w  = *(const float4*)&WhhT2[k*512 + d*4];
      float hj[4] = {hv.x, hv.y, hv.z, hv.w};
      #pragma unroll
      for (int jj=0;jj<4;jj++){
        acc[jj][0] += w.x*hj[jj];
        acc[jj][1] += w.y*hj[jj];
        acc[jj][2] += w.z*hj[jj];
        acc[jj][3] += w.w*hj[jj];
      }
    }
    __syncthreads();   // everyone done reading old h
    #pragma unroll
    for (int jj=0;jj<4;jj++){
      if (ej[jj] >= 0){
        float iv = sigf(acc[jj][0]);
        float fv = sigf(acc[jj][1]);
        float gv = tanh_f(acc[jj][2]);
        float ov = sigf(acc[jj][3]);
        cst[jj] = fv*cst[jj] + iv*gv;
        hbuf[d][j0+jj] = ov * tanh_f(cst[jj]);
      }
    }
    __syncthreads();   // new h visible
  }

  #pragma unroll
  for (int jj=0;jj<4;jj++){
    int n = nd[jj];
    if (n >= 0 && !(pass==0 && dcnt[n] > 0)){
      emb[(size_t)n*128 + d] = hbuf[d][j0+jj];
    }
  }
}

// ---------------- final MLP + LayerNorm + out : 8 nodes per block ----------------
__global__ void k_mlp(const float* __restrict__ x, const float* __restrict__ emb,
                      const float* __restrict__ fc1wT, const float* __restrict__ fc1b,
                      const float* __restrict__ lng, const float* __restrict__ lnb,
                      const float* __restrict__ outw, const float* __restrict__ outb,
                      float* __restrict__ out){
  __shared__ float xc[8][384];
  int nb = blockIdx.x*8;
  int tid = threadIdx.x;
  for (int i=tid; i<8*256; i+=256){ int nd=i>>8, dd=i&255; xc[nd][dd] = x[(size_t)(nb+nd)*256 + dd]; }
  for (int i=tid; i<8*128; i+=256){ int nd=i>>7, dd=i&127; xc[nd][256+dd] = emb[(size_t)(nb+nd)*128 + dd]; }
  __syncthreads();
  int nd = tid >> 5;       // node within block
  int lo = tid & 31;       // 32 threads per node
  float acc[4];
  #pragma unroll
  for (int q=0;q<4;q++) acc[q] = fc1b[lo + 32*q];
  for (int k=0;k<384;k++){
    float xv = xc[nd][k];
    #pragma unroll
    for (int q=0;q<4;q++) acc[q] += fc1wT[k*128 + lo + 32*q] * xv;
  }
  float s = acc[0]+acc[1]+acc[2]+acc[3];
  #pragma unroll
  for (int m=16;m>=1;m>>=1) s += __shfl_xor(s, m);
  float mu = s * (1.f/128.f);
  float v = 0.f;
  #pragma unroll
  for (int q=0;q<4;q++){ float dm = acc[q]-mu; v += dm*dm; }
  #pragma unroll
  for (int m=16;m>=1;m>>=1) v += __shfl_xor(v, m);
  float rstd = rsqrtf(v*(1.f/128.f) + 1e-5f);
  float o0 = 0.f, o1 = 0.f;
  #pragma unroll
  for (int q=0;q<4;q++){
    int o = lo + 32*q;
    float h1 = (acc[q]-mu)*rstd*lng[o] + lnb[o];
    h1 = fmaxf(h1, 0.f);
    o0 += h1*outw[o];
    o1 += h1*outw[128+o];
  }
  #pragma unroll
  for (int m=16;m>=1;m>>=1){ o0 += __shfl_xor(o0, m); o1 += __shfl_xor(o1, m); }
  if (lo==0){
    out[(size_t)(nb+nd)*2]   = o0 + outb[0];
    out[(size_t)(nb+nd)*2+1] = o1 + outb[1];
  }
}

extern "C" void kernel_launch(void* const* d_in, const int* in_sizes, int n_in,
                              void* d_out, int out_size, void* d_ws, size_t ws_size,
                              hipStream_t stream){
  const float* x      = (const float*)d_in[0];
  const int*   heads  = (const int*)d_in[1];
  const int*   rels   = (const int*)d_in[2];
  const int*   tails  = (const int*)d_in[3];
  const float* weeks  = (const float*)d_in[4];
  const int*   esrc   = (const int*)d_in[5];
  const int*   edst   = (const int*)d_in[6];
  const float* ent    = (const float*)d_in[10];
  const float* rel_e  = (const float*)d_in[11];
  const float* wfreq  = (const float*)d_in[12];
  const float* wphi   = (const float*)d_in[13];
  const float* wamp   = (const float*)d_in[14];
  const float* Wih    = (const float*)d_in[15];
  const float* Whh    = (const float*)d_in[16];
  const float* bih    = (const float*)d_in[17];
  const float* bhh    = (const float*)d_in[18];
  const float* fc1w   = (const float*)d_in[19];
  const float* fc1b   = (const float*)d_in[20];
  const float* lng    = (const float*)d_in[21];
  const float* lnb    = (const float*)d_in[22];
  const float* outw   = (const float*)d_in[23];
  const float* outb   = (const float*)d_in[24];
  float* out = (float*)d_out;

  char* ws = (char*)d_ws;
  size_t off = 0;
  auto alloc = [&](size_t bytes){ void* p = ws + off; off += (bytes + 255) & ~(size_t)255; return p; };
  float* pre2   = (float*)alloc((size_t)N_EDGES*512*4);
  float* WihT2  = (float*)alloc(512*128*4);
  float* WhhT2  = (float*)alloc(512*128*4);
  float* fc1wT  = (float*)alloc(384*128*4);
  float* emb    = (float*)alloc((size_t)N_NODES*128*4);
  int* sstart   = (int*)alloc((N_NODES+1)*4);
  int* dstart   = (int*)alloc((N_NODES+1)*4);
  // zero-region: cnts(4N) + lenhist(128) + cur(128) + nchains(2)
  int* zreg     = (int*)alloc((size_t)(4*N_NODES + 258)*4);
  int* scnt = zreg, *dcnt = zreg+N_NODES, *sc2 = zreg+2*N_NODES, *dc2 = zreg+3*N_NODES;
  int* lenhist  = zreg + 4*N_NODES;
  int* cur      = lenhist + 128;
  int* nchains  = cur + 128;
  int* loff     = (int*)alloc(128*4);
  int* slist    = (int*)alloc(N_EDGES*4);
  int* dlist    = (int*)alloc(N_EDGES*4);
  int* cnode    = (int*)alloc((size_t)2*N_NODES*4);
  int* cstart   = (int*)alloc((size_t)2*N_NODES*4);
  int* clen     = (int*)alloc((size_t)2*N_NODES*4);

  hipMemsetAsync(zreg, 0, (size_t)(4*N_NODES + 258)*4, stream);
  hipMemsetAsync(emb, 0, (size_t)N_NODES*128*4, stream);

  k_transperm<<<(512*128+255)/256, 256, 0, stream>>>(Wih, WihT2);
  k_transperm<<<(512*128+255)/256, 256, 0, stream>>>(Whh, WhhT2);
  k_transpose<<<(128*384+255)/256, 256, 0, stream>>>(fc1w, fc1wT, 128, 384);

  k_edge<<<N_EDGES/16, 256, 0, stream>>>(heads, rels, tails, weeks, ent, rel_e,
                                         wfreq, wphi, wamp, WihT2, bih, pre2);
  k_hist<<<(N_EDGES+255)/256, 256, 0, stream>>>(esrc, edst, scnt, dcnt);
  k_scan<<<2, 1024, 0, stream>>>(scnt, dcnt, sstart, dstart);
  k_scatter<<<(N_EDGES+255)/256, 256, 0, stream>>>(esrc, edst, sstart, dstart, sc2, dc2, slist, dlist);
  k_sortlists<<<(N_NODES+255)/256, 256, 0, stream>>>(sstart, dstart, slist, dlist);
  k_chainhist<<<(N_NODES+255)/256, 256, 0, stream>>>(sstart, dstart, lenhist);
  k_lenscan<<<1, 64, 0, stream>>>(lenhist, loff, nchains);
  k_chainscatter<<<(N_NODES+255)/256, 256, 0, stream>>>(sstart, dstart, loff, cur, cnode, cstart, clen);
  k_lstm2<<<5000, 256, 0, stream>>>(pre2, WhhT2, bhh, cnode, cstart, clen, nchains,
                                    slist, dlist, dcnt, emb);
  k_mlp<<<N_NODES/8, 256, 0, stream>>>(x, emb, fc1wT, fc1b, lng, lnb, outw, outb, out);
}

// Round 3
// 655.593 us; speedup vs baseline: 1.5003x; 1.2218x over previous
//
#include <hip/hip_runtime.h>
#include <math.h>

#define N_NODES 20000
#define N_EDGES 40000
#define SE 46
#define TE 82
// D = 128, 4D = 512, F = 256, HID = 128

typedef short  s16x8 __attribute__((ext_vector_type(8)));
typedef short  s16x4 __attribute__((ext_vector_type(4)));
typedef float  f32x4 __attribute__((ext_vector_type(4)));

__device__ __forceinline__ float sigf(float x){ return 1.0f/(1.0f+__expf(-x)); }
__device__ __forceinline__ float tanh_f(float x){ return 1.0f - 2.0f/(__expf(2.0f*x)+1.0f); }
__device__ __forceinline__ int perm_out(int i){ return (i&3)*128 + (i>>2); }
__device__ __forceinline__ unsigned short f2bf(float f){
  unsigned u = __builtin_bit_cast(unsigned, f);
  unsigned r = (u + 0x7fff + ((u>>16)&1)) >> 16;
  return (unsigned short)r;
}
__device__ __forceinline__ float bf2f(short s){
  unsigned u = ((unsigned)(unsigned short)s) << 16;
  return __builtin_bit_cast(float, u);
}

// ---------------- plain transpose: out[c*R+r] = in[r*C+c] ----------------
__global__ void k_transpose(const float* __restrict__ in, float* __restrict__ out, int R, int C){
  int i = blockIdx.x*blockDim.x + threadIdx.x;
  if (i < R*C){ int r = i / C, c = i - r*C; out[c*R + r] = in[i]; }
}

// gate-interleaved transpose: out[k*512 + i] = in[perm(i)*128 + k]
__global__ void k_transperm(const float* __restrict__ in, float* __restrict__ out){
  int idx = blockIdx.x*blockDim.x + threadIdx.x;
  if (idx < 512*128){
    int k = idx >> 9, i = idx & 511;
    out[idx] = in[perm_out(i)*128 + k];
  }
}

// ---------------- edge features + pre2 = permuted(scores @ Wih^T + bih + bhh) ----------------
__global__ void k_edge(const int* __restrict__ heads, const int* __restrict__ rels,
                       const int* __restrict__ tails, const float* __restrict__ weeks,
                       const float* __restrict__ ent, const float* __restrict__ rel_embs,
                       const float* __restrict__ wfreq, const float* __restrict__ wphi,
                       const float* __restrict__ wamp,
                       const float* __restrict__ WihT2, const float* __restrict__ bih,
                       const float* __restrict__ bhh, float* __restrict__ pre2){
  __shared__ float s2[128][16];   // s2[k][edge]
  int e0 = blockIdx.x * 16;
  int tid = threadIdx.x;
  #pragma unroll
  for (int q=0;q<8;q++){
    int idx = tid + 256*q;          // 0..2047
    int el = idx >> 7, d = idx & 127;
    int e = e0 + el;
    int hd = heads[e], tl = tails[e], rl = rels[e];
    float wk = weeks[e];
    float hv, tv;
    if (d < SE){
      hv = ent[(size_t)hd*SE + d];
      tv = ent[(size_t)tl*SE + d];
    } else {
      int dt = d - SE;
      hv = wamp[(size_t)hd*TE+dt] * __sinf(wfreq[(size_t)hd*TE+dt]*wk + wphi[(size_t)hd*TE+dt]);
      tv = wamp[(size_t)tl*TE+dt] * __sinf(wfreq[(size_t)tl*TE+dt]*wk + wphi[(size_t)tl*TE+dt]);
    }
    float rv = rel_embs[rl*128 + d];
    s2[d][el] = hv * rv * tv;
  }
  __syncthreads();
  float acc0[16], acc1[16];
  #pragma unroll
  for (int e=0;e<16;e++){ acc0[e]=0.f; acc1[e]=0.f; }
  for (int k=0;k<128;k++){
    float w0 = WihT2[k*512 + tid];
    float w1 = WihT2[k*512 + tid + 256];
    const float4* sp = (const float4*)&s2[k][0];
    float4 sa = sp[0], sb = sp[1], sc = sp[2], sd = sp[3];
    float sv[16] = {sa.x,sa.y,sa.z,sa.w, sb.x,sb.y,sb.z,sb.w,
                    sc.x,sc.y,sc.z,sc.w, sd.x,sd.y,sd.z,sd.w};
    #pragma unroll
    for (int e=0;e<16;e++){ acc0[e] += w0*sv[e]; acc1[e] += w1*sv[e]; }
  }
  float b0 = bih[perm_out(tid)]     + bhh[perm_out(tid)];
  float b1 = bih[perm_out(tid+256)] + bhh[perm_out(tid+256)];
  #pragma unroll
  for (int e=0;e<16;e++){
    pre2[(size_t)(e0+e)*512 + tid]       = acc0[e] + b0;
    pre2[(size_t)(e0+e)*512 + tid + 256] = acc1[e] + b1;
  }
}

// ---------------- grouping machinery ----------------
__global__ void k_hist(const int* __restrict__ src, const int* __restrict__ dst,
                       int* __restrict__ scnt, int* __restrict__ dcnt){
  int e = blockIdx.x*blockDim.x + threadIdx.x;
  if (e < N_EDGES){ atomicAdd(&scnt[src[e]],1); atomicAdd(&dcnt[dst[e]],1); }
}

// fast scan: 1024 threads, 20 elems each, shuffle-based (4 barriers)
__global__ void k_scan(const int* __restrict__ scnt, const int* __restrict__ dcnt,
                       int* __restrict__ sstart, int* __restrict__ dstart){
  const int* cnt = blockIdx.x ? dcnt : scnt;
  int* start = blockIdx.x ? dstart : sstart;
  const int CH = 20;
  int tid = threadIdx.x;
  int base = tid*CH;
  int v[CH]; int tsum = 0;
  #pragma unroll
  for (int j=0;j<CH;j++){ int i = base+j; v[j] = (i<N_NODES)? cnt[i] : 0; tsum += v[j]; }
  int lane = tid & 63, wv = tid >> 6;
  int incl = tsum;
  #pragma unroll
  for (int m=1;m<64;m<<=1){ int u = __shfl_up(incl, m); if (lane >= m) incl += u; }
  __shared__ int wsum[16], woff[16];
  if (lane==63) wsum[wv] = incl;
  __syncthreads();
  if (tid < 16){ int s=0; for (int k=0;k<tid;k++) s += wsum[k]; woff[tid]=s; }
  __syncthreads();
  int run = woff[wv] + incl - tsum;
  #pragma unroll
  for (int j=0;j<CH;j++){ int i = base+j; if (i<N_NODES) start[i] = run; run += v[j]; }
  if (tid == 1023) start[N_NODES] = run;
}

__global__ void k_scatter(const int* __restrict__ src, const int* __restrict__ dst,
                          const int* __restrict__ sstart, const int* __restrict__ dstart,
                          int* __restrict__ sc2, int* __restrict__ dc2,
                          int* __restrict__ slist, int* __restrict__ dlist){
  int e = blockIdx.x*blockDim.x + threadIdx.x;
  if (e < N_EDGES){
    int s = src[e]; int p  = sstart[s] + atomicAdd(&sc2[s],1); slist[p]=e;
    int d = dst[e]; int p2 = dstart[d] + atomicAdd(&dc2[d],1); dlist[p2]=e;
  }
}

__global__ void k_sortlists(const int* __restrict__ sstart, const int* __restrict__ dstart,
                            int* __restrict__ slist, int* __restrict__ dlist){
  int n = blockIdx.x*blockDim.x + threadIdx.x;
  if (n < N_NODES){
    #pragma unroll
    for (int pass=0; pass<2; pass++){
      const int* st = pass ? dstart : sstart;
      int* ls = pass ? dlist : slist;
      int a = st[n], b = st[n+1];
      for (int i=a+1;i<b;i++){
        int v = ls[i]; int j=i-1;
        while (j>=a && ls[j]>v){ ls[j+1]=ls[j]; j--; }
        ls[j+1]=v;
      }
    }
  }
}

// ---------------- chain compaction: counting-sort chains by length desc ----------------
__global__ void k_chainhist(const int* __restrict__ sstart, const int* __restrict__ dstart,
                            int* __restrict__ lenhist){
  int n = blockIdx.x*blockDim.x + threadIdx.x;
  if (n < N_NODES){
    int c = sstart[n+1]-sstart[n];
    if (c>0) atomicAdd(&lenhist[min(c,63)],1);
    int c2 = dstart[n+1]-dstart[n];
    if (c2>0) atomicAdd(&lenhist[64+min(c2,63)],1);
  }
}

// one wave per pass: suffix-sum via shuffles
__global__ void k_lenscan(const int* __restrict__ lenhist, int* __restrict__ off,
                          int* __restrict__ nchains){
  int tid = threadIdx.x;
  int p = tid >> 6, l = tid & 63;
  int v = (l >= 1) ? lenhist[p*64 + l] : 0;
  int s = v;
  #pragma unroll
  for (int m=1;m<64;m<<=1){ int u = __shfl_down(s, m); if (l + m < 64) s += u; }
  off[p*64 + l] = s - v;
  if (l == 0) nchains[p] = s;
}

__global__ void k_chainscatter(const int* __restrict__ sstart, const int* __restrict__ dstart,
                               const int* __restrict__ off, int* __restrict__ cur,
                               int* __restrict__ cnode, int* __restrict__ cstart,
                               int* __restrict__ clen){
  int n = blockIdx.x*blockDim.x + threadIdx.x;
  if (n >= N_NODES) return;
  #pragma unroll
  for (int p=0;p<2;p++){
    const int* st = p ? dstart : sstart;
    int a = st[n], c = st[n+1]-a;
    if (c>0){
      int l = min(c,63);
      int pos = off[p*64+l] + atomicAdd(&cur[p*64+l],1);
      cnode [p*N_NODES+pos] = n;
      cstart[p*N_NODES+pos] = a;
      clen  [p*N_NODES+pos] = c;
    }
  }
}

// ---------------- persistent MFMA LSTM: Whh bf16 in LDS, 16 chains/batch ----------------
// LDS layout: W (512 rows x 256B bf16, swz) | G (16 x 1024B bf16, swz) | H (16 x 256B bf16, swz) | meta
#define LDS_G 131072
#define LDS_H 147456
#define LDS_META 151552
#define LDSZ 151936

__global__ __launch_bounds__(512, 1) void k_lstm3(
    const float* __restrict__ pre2, const float* __restrict__ Whh,
    const int* __restrict__ cnode, const int* __restrict__ cstart,
    const int* __restrict__ clen, const int* __restrict__ nchains,
    const int* __restrict__ slist, const int* __restrict__ dlist,
    const int* __restrict__ dcnt, int* __restrict__ ctr,
    float* __restrict__ emb){
  extern __shared__ char smem[];
  int tid = threadIdx.x;
  int lane = tid & 63, wv = tid >> 6;
  // load Whh -> LDS bf16, permuted row order n -> orig (n&3)*128+(n>>2)
  #pragma unroll 1
  for (int q=0;q<16;q++){
    int c = q*512 + tid;
    int n = c >> 4, k8 = c & 15;
    int orig = (n&3)*128 + (n>>2);
    const float* src = Whh + (size_t)orig*128 + k8*8;
    s16x8 v8;
    #pragma unroll
    for (int j=0;j<8;j++) v8[j] = (short)f2bf(src[j]);
    int byt = (n*256 + k8*16) ^ ((n&7)<<4);
    *(s16x8*)(smem + byt) = v8;
  }
  int nch0 = nchains[0], nch1 = nchains[1];
  int B0 = (nch0+15)>>4, B1 = (nch1+15)>>4;
  int* M = (int*)(smem + LDS_META);  // [0..15] len, [16..31] start, [32..47] node, [48..79] eids[2][16], [80] nb
  int d  = tid & 127, cg = tid >> 7;
  __syncthreads();
  while (true){
    if (tid==0) M[80] = atomicAdd(ctr, 1);
    __syncthreads();
    int nb = M[80];
    if (nb >= B0 + B1) break;
    int pass = (nb >= B0) ? 1 : 0;
    int batch = pass ? nb - B0 : nb;
    int b0 = batch << 4;
    int nch = pass ? nch1 : nch0;
    const int* list = pass ? dlist : slist;
    if (tid < 16){
      int j = b0 + tid;
      int valid = (j < nch);
      int ci = pass*N_NODES + j;
      int st = valid ? cstart[ci] : 0;
      int ln = valid ? clen[ci] : 0;
      M[tid] = ln; M[16+tid] = st; M[32+tid] = valid ? cnode[ci] : -1;
      M[48+tid] = (ln > 0) ? list[st] : 0;
    }
    *(unsigned long long*)(smem + LDS_H + tid*8) = 0ull;  // zero h (4KB)
    float cst[4]  = {0.f,0.f,0.f,0.f};
    float hreg[4] = {0.f,0.f,0.f,0.f};
    __syncthreads();
    int ml = 0;
    #pragma unroll 1
    for (int j=0;j<16;j++) ml = max(ml, M[j]);
    for (int t=0; t<ml; t++){
      // ---- MFMA: gates_raw = h @ Whh_perm^T  (16x512, K=128) ----
      f32x4 D[4];
      #pragma unroll
      for (int i=0;i<4;i++) D[i] = (f32x4){0.f,0.f,0.f,0.f};
      int row = lane & 15;
      int col = lane & 15;
      #pragma unroll
      for (int ks=0; ks<4; ks++){
        int kb = ks*64 + (lane>>4)*16;   // byte offset of k-chunk
        s16x8 a = *(const s16x8*)(smem + LDS_H + ((row*256 + kb) ^ ((row&7)<<4)));
        #pragma unroll
        for (int i=0;i<4;i++){
          int n = wv*64 + i*16 + col;
          s16x8 b = *(const s16x8*)(smem + ((n*256 + kb) ^ ((n&7)<<4)));
          D[i] = __builtin_amdgcn_mfma_f32_16x16x32_bf16(a, b, D[i], 0, 0, 0);
        }
      }
      // ---- D -> G (bf16) ----
      int rb = (lane>>4)*4;
      #pragma unroll
      for (int i=0;i<4;i++){
        int n = wv*64 + i*16 + col;
        #pragma unroll
        for (int q=0;q<4;q++){
          int r = rb + q;
          *(short*)(smem + LDS_G + ((r*1024 + n*2) ^ ((r&7)<<4))) = (short)f2bf(D[i][q]);
        }
      }
      __syncthreads();
      // ---- gate combine: thread owns (d, chains cg*4..+3) ----
      const int* eid = M + 48 + ((t&1)<<4);
      #pragma unroll
      for (int jj=0;jj<4;jj++){
        int r = cg*4 + jj;
        if (t < M[r]){
          f32x4 pv = *(const f32x4*)(pre2 + (size_t)eid[r]*512 + d*4);
          s16x4 gs = *(const s16x4*)(smem + LDS_G + ((r*1024 + d*8) ^ ((r&7)<<4)));
          float g0 = bf2f(gs[0]) + pv[0];
          float g1 = bf2f(gs[1]) + pv[1];
          float g2 = bf2f(gs[2]) + pv[2];
          float g3 = bf2f(gs[3]) + pv[3];
          float iv = sigf(g0), fv = sigf(g1), gv = tanh_f(g2), ov = sigf(g3);
          cst[jj] = fv*cst[jj] + iv*gv;
          float h = ov * tanh_f(cst[jj]);
          hreg[jj] = h;
          *(short*)(smem + LDS_H + ((r*256 + d*2) ^ ((r&7)<<4))) = (short)f2bf(h);
        }
      }
      if (tid < 16){
        int ln = M[tid];
        M[48 + (((t+1)&1)<<4) + tid] = (t+1 < ln) ? list[M[16+tid] + t+1] : 0;
      }
      __syncthreads();
    }
    // ---- emb writes (pass0 only if node has no dst edges; pass1 always) ----
    #pragma unroll
    for (int jj=0;jj<4;jj++){
      int r = cg*4 + jj;
      int n = M[32+r];
      if (M[r] > 0 && n >= 0 && !(pass==0 && dcnt[n] > 0)){
        emb[(size_t)n*128 + d] = hreg[jj];
      }
    }
    __syncthreads();
  }
}

// ---------------- final MLP + LayerNorm + out : 8 nodes per block ----------------
__global__ void k_mlp(const float* __restrict__ x, const float* __restrict__ emb,
                      const float* __restrict__ fc1wT, const float* __restrict__ fc1b,
                      const float* __restrict__ lng, const float* __restrict__ lnb,
                      const float* __restrict__ outw, const float* __restrict__ outb,
                      float* __restrict__ out){
  __shared__ float xc[8][384];
  int nb = blockIdx.x*8;
  int tid = threadIdx.x;
  for (int i=tid; i<8*256; i+=256){ int nd=i>>8, dd=i&255; xc[nd][dd] = x[(size_t)(nb+nd)*256 + dd]; }
  for (int i=tid; i<8*128; i+=256){ int nd=i>>7, dd=i&127; xc[nd][256+dd] = emb[(size_t)(nb+nd)*128 + dd]; }
  __syncthreads();
  int nd = tid >> 5;
  int lo = tid & 31;
  float acc[4];
  #pragma unroll
  for (int q=0;q<4;q++) acc[q] = fc1b[lo + 32*q];
  for (int k=0;k<384;k++){
    float xv = xc[nd][k];
    #pragma unroll
    for (int q=0;q<4;q++) acc[q] += fc1wT[k*128 + lo + 32*q] * xv;
  }
  float s = acc[0]+acc[1]+acc[2]+acc[3];
  #pragma unroll
  for (int m=16;m>=1;m>>=1) s += __shfl_xor(s, m);
  float mu = s * (1.f/128.f);
  float v = 0.f;
  #pragma unroll
  for (int q=0;q<4;q++){ float dm = acc[q]-mu; v += dm*dm; }
  #pragma unroll
  for (int m=16;m>=1;m>>=1) v += __shfl_xor(v, m);
  float rstd = rsqrtf(v*(1.f/128.f) + 1e-5f);
  float o0 = 0.f, o1 = 0.f;
  #pragma unroll
  for (int q=0;q<4;q++){
    int o = lo + 32*q;
    float h1 = (acc[q]-mu)*rstd*lng[o] + lnb[o];
    h1 = fmaxf(h1, 0.f);
    o0 += h1*outw[o];
    o1 += h1*outw[128+o];
  }
  #pragma unroll
  for (int m=16;m>=1;m>>=1){ o0 += __shfl_xor(o0, m); o1 += __shfl_xor(o1, m); }
  if (lo==0){
    out[(size_t)(nb+nd)*2]   = o0 + outb[0];
    out[(size_t)(nb+nd)*2+1] = o1 + outb[1];
  }
}

extern "C" void kernel_launch(void* const* d_in, const int* in_sizes, int n_in,
                              void* d_out, int out_size, void* d_ws, size_t ws_size,
                              hipStream_t stream){
  const float* x      = (const float*)d_in[0];
  const int*   heads  = (const int*)d_in[1];
  const int*   rels   = (const int*)d_in[2];
  const int*   tails  = (const int*)d_in[3];
  const float* weeks  = (const float*)d_in[4];
  const int*   esrc   = (const int*)d_in[5];
  const int*   edst   = (const int*)d_in[6];
  const float* ent    = (const float*)d_in[10];
  const float* rel_e  = (const float*)d_in[11];
  const float* wfreq  = (const float*)d_in[12];
  const float* wphi   = (const float*)d_in[13];
  const float* wamp   = (const float*)d_in[14];
  const float* Wih    = (const float*)d_in[15];
  const float* Whh    = (const float*)d_in[16];
  const float* bih    = (const float*)d_in[17];
  const float* bhh    = (const float*)d_in[18];
  const float* fc1w   = (const float*)d_in[19];
  const float* fc1b   = (const float*)d_in[20];
  const float* lng    = (const float*)d_in[21];
  const float* lnb    = (const float*)d_in[22];
  const float* outw   = (const float*)d_in[23];
  const float* outb   = (const float*)d_in[24];
  float* out = (float*)d_out;

  char* ws = (char*)d_ws;
  size_t off = 0;
  auto alloc = [&](size_t bytes){ void* p = ws + off; off += (bytes + 255) & ~(size_t)255; return p; };
  float* pre2   = (float*)alloc((size_t)N_EDGES*512*4);
  float* WihT2  = (float*)alloc(512*128*4);
  float* fc1wT  = (float*)alloc(384*128*4);
  float* emb    = (float*)alloc((size_t)N_NODES*128*4);
  int* sstart   = (int*)alloc((N_NODES+1)*4);
  int* dstart   = (int*)alloc((N_NODES+1)*4);
  // zero-region: cnts(4N) + lenhist(128) + cur(128) + nchains(2) + ctr(1)
  int* zreg     = (int*)alloc((size_t)(4*N_NODES + 259)*4);
  int* scnt = zreg, *dcnt = zreg+N_NODES, *sc2 = zreg+2*N_NODES, *dc2 = zreg+3*N_NODES;
  int* lenhist  = zreg + 4*N_NODES;
  int* cur      = lenhist + 128;
  int* nchains  = cur + 128;
  int* ctr      = nchains + 2;
  int* loff     = (int*)alloc(128*4);
  int* slist    = (int*)alloc(N_EDGES*4);
  int* dlist    = (int*)alloc(N_EDGES*4);
  int* cnode    = (int*)alloc((size_t)2*N_NODES*4);
  int* cstart   = (int*)alloc((size_t)2*N_NODES*4);
  int* clen     = (int*)alloc((size_t)2*N_NODES*4);

  hipMemsetAsync(zreg, 0, (size_t)(4*N_NODES + 259)*4, stream);
  hipMemsetAsync(emb, 0, (size_t)N_NODES*128*4, stream);

  hipFuncSetAttribute((const void*)k_lstm3, hipFuncAttributeMaxDynamicSharedMemorySize, LDSZ);

  k_transperm<<<(512*128+255)/256, 256, 0, stream>>>(Wih, WihT2);
  k_transpose<<<(128*384+255)/256, 256, 0, stream>>>(fc1w, fc1wT, 128, 384);

  k_edge<<<N_EDGES/16, 256, 0, stream>>>(heads, rels, tails, weeks, ent, rel_e,
                                         wfreq, wphi, wamp, WihT2, bih, bhh, pre2);
  k_hist<<<(N_EDGES+255)/256, 256, 0, stream>>>(esrc, edst, scnt, dcnt);
  k_scan<<<2, 1024, 0, stream>>>(scnt, dcnt, sstart, dstart);
  k_scatter<<<(N_EDGES+255)/256, 256, 0, stream>>>(esrc, edst, sstart, dstart, sc2, dc2, slist, dlist);
  k_sortlists<<<(N_NODES+255)/256, 256, 0, stream>>>(sstart, dstart, slist, dlist);
  k_chainhist<<<(N_NODES+255)/256, 256, 0, stream>>>(sstart, dstart, lenhist);
  k_lenscan<<<1, 128, 0, stream>>>(lenhist, loff, nchains);
  k_chainscatter<<<(N_NODES+255)/256, 256, 0, stream>>>(sstart, dstart, loff, cur, cnode, cstart, clen);
  k_lstm3<<<256, 512, LDSZ, stream>>>(pre2, Whh, cnode, cstart, clen, nchains,
                                      slist, dlist, dcnt, ctr, emb);
  k_mlp<<<N_NODES/8, 256, 0, stream>>>(x, emb, fc1wT, fc1b, lng, lnb, outw, outb, out);
}

// Round 4
// 357.252 us; speedup vs baseline: 2.7531x; 1.8351x over previous
//
#include <hip/hip_runtime.h>
#include <math.h>

#define N_NODES 20000
#define N_EDGES 40000
#define SE 46
#define TE 82
#define NBLK 79   // ceil(N_NODES/256)
// D = 128, 4D = 512, F = 256, HID = 128

typedef short  s16x8 __attribute__((ext_vector_type(8)));
typedef short  s16x4 __attribute__((ext_vector_type(4)));
typedef float  f32x4 __attribute__((ext_vector_type(4)));

__device__ __forceinline__ float sigf(float x){ return 1.0f/(1.0f+__expf(-x)); }
__device__ __forceinline__ float tanh_f(float x){ return 1.0f - 2.0f/(__expf(2.0f*x)+1.0f); }
__device__ __forceinline__ int perm_out(int i){ return (i&3)*128 + (i>>2); }
__device__ __forceinline__ unsigned short f2bf(float f){
  unsigned u = __builtin_bit_cast(unsigned, f);
  unsigned r = (u + 0x7fff + ((u>>16)&1)) >> 16;
  return (unsigned short)r;
}
__device__ __forceinline__ float bf2f(short s){
  unsigned u = ((unsigned)(unsigned short)s) << 16;
  return __builtin_bit_cast(float, u);
}

// ---------------- plain transpose: out[c*R+r] = in[r*C+c] ----------------
__global__ void k_transpose(const float* __restrict__ in, float* __restrict__ out, int R, int C){
  int i = blockIdx.x*blockDim.x + threadIdx.x;
  if (i < R*C){ int r = i / C, c = i - r*C; out[c*R + r] = in[i]; }
}

// gate-interleaved transpose: out[k*512 + i] = in[perm(i)*128 + k]
__global__ void k_transperm(const float* __restrict__ in, float* __restrict__ out){
  int idx = blockIdx.x*blockDim.x + threadIdx.x;
  if (idx < 512*128){
    int k = idx >> 9, i = idx & 511;
    out[idx] = in[perm_out(i)*128 + k];
  }
}

// ---------------- edge features + pre2 = permuted(scores @ Wih^T + bih + bhh) ----------------
__global__ void k_edge(const int* __restrict__ heads, const int* __restrict__ rels,
                       const int* __restrict__ tails, const float* __restrict__ weeks,
                       const float* __restrict__ ent, const float* __restrict__ rel_embs,
                       const float* __restrict__ wfreq, const float* __restrict__ wphi,
                       const float* __restrict__ wamp,
                       const float* __restrict__ WihT2, const float* __restrict__ bih,
                       const float* __restrict__ bhh, float* __restrict__ pre2){
  __shared__ float s2[128][16];   // s2[k][edge]
  int e0 = blockIdx.x * 16;
  int tid = threadIdx.x;
  #pragma unroll
  for (int q=0;q<8;q++){
    int idx = tid + 256*q;          // 0..2047
    int el = idx >> 7, d = idx & 127;
    int e = e0 + el;
    int hd = heads[e], tl = tails[e], rl = rels[e];
    float wk = weeks[e];
    float hv, tv;
    if (d < SE){
      hv = ent[(size_t)hd*SE + d];
      tv = ent[(size_t)tl*SE + d];
    } else {
      int dt = d - SE;
      hv = wamp[(size_t)hd*TE+dt] * __sinf(wfreq[(size_t)hd*TE+dt]*wk + wphi[(size_t)hd*TE+dt]);
      tv = wamp[(size_t)tl*TE+dt] * __sinf(wfreq[(size_t)tl*TE+dt]*wk + wphi[(size_t)tl*TE+dt]);
    }
    float rv = rel_embs[rl*128 + d];
    s2[d][el] = hv * rv * tv;
  }
  __syncthreads();
  float acc0[16], acc1[16];
  #pragma unroll
  for (int e=0;e<16;e++){ acc0[e]=0.f; acc1[e]=0.f; }
  for (int k=0;k<128;k++){
    float w0 = WihT2[k*512 + tid];
    float w1 = WihT2[k*512 + tid + 256];
    const float4* sp = (const float4*)&s2[k][0];
    float4 sa = sp[0], sb = sp[1], sc = sp[2], sd = sp[3];
    float sv[16] = {sa.x,sa.y,sa.z,sa.w, sb.x,sb.y,sb.z,sb.w,
                    sc.x,sc.y,sc.z,sc.w, sd.x,sd.y,sd.z,sd.w};
    #pragma unroll
    for (int e=0;e<16;e++){ acc0[e] += w0*sv[e]; acc1[e] += w1*sv[e]; }
  }
  float b0 = bih[perm_out(tid)]     + bhh[perm_out(tid)];
  float b1 = bih[perm_out(tid+256)] + bhh[perm_out(tid+256)];
  #pragma unroll
  for (int e=0;e<16;e++){
    pre2[(size_t)(e0+e)*512 + tid]       = acc0[e] + b0;
    pre2[(size_t)(e0+e)*512 + tid + 256] = acc1[e] + b1;
  }
}

// ---------------- grouping machinery ----------------
__global__ void k_hist(const int* __restrict__ src, const int* __restrict__ dst,
                       int* __restrict__ scnt, int* __restrict__ dcnt){
  int e = blockIdx.x*blockDim.x + threadIdx.x;
  if (e < N_EDGES){ atomicAdd(&scnt[src[e]],1); atomicAdd(&dcnt[dst[e]],1); }
}

// fast scan: 1024 threads, 20 elems each, shuffle-based
__global__ void k_scan(const int* __restrict__ scnt, const int* __restrict__ dcnt,
                       int* __restrict__ sstart, int* __restrict__ dstart){
  const int* cnt = blockIdx.x ? dcnt : scnt;
  int* start = blockIdx.x ? dstart : sstart;
  const int CH = 20;
  int tid = threadIdx.x;
  int base = tid*CH;
  int v[CH]; int tsum = 0;
  #pragma unroll
  for (int j=0;j<CH;j++){ int i = base+j; v[j] = (i<N_NODES)? cnt[i] : 0; tsum += v[j]; }
  int lane = tid & 63, wv = tid >> 6;
  int incl = tsum;
  #pragma unroll
  for (int m=1;m<64;m<<=1){ int u = __shfl_up(incl, m); if (lane >= m) incl += u; }
  __shared__ int wsum[16], woff[16];
  if (lane==63) wsum[wv] = incl;
  __syncthreads();
  if (tid < 16){ int s=0; for (int k=0;k<tid;k++) s += wsum[k]; woff[tid]=s; }
  __syncthreads();
  int run = woff[wv] + incl - tsum;
  #pragma unroll
  for (int j=0;j<CH;j++){ int i = base+j; if (i<N_NODES) start[i] = run; run += v[j]; }
  if (tid == 1023) start[N_NODES] = run;
}

__global__ void k_scatter(const int* __restrict__ src, const int* __restrict__ dst,
                          const int* __restrict__ sstart, const int* __restrict__ dstart,
                          int* __restrict__ sc2, int* __restrict__ dc2,
                          int* __restrict__ slist, int* __restrict__ dlist){
  int e = blockIdx.x*blockDim.x + threadIdx.x;
  if (e < N_EDGES){
    int s = src[e]; int p  = sstart[s] + atomicAdd(&sc2[s],1); slist[p]=e;
    int d = dst[e]; int p2 = dstart[d] + atomicAdd(&dc2[d],1); dlist[p2]=e;
  }
}

__global__ void k_sortlists(const int* __restrict__ sstart, const int* __restrict__ dstart,
                            int* __restrict__ slist, int* __restrict__ dlist){
  int n = blockIdx.x*blockDim.x + threadIdx.x;
  if (n < N_NODES){
    #pragma unroll
    for (int pass=0; pass<2; pass++){
      const int* st = pass ? dstart : sstart;
      int* ls = pass ? dlist : slist;
      int a = st[n], b = st[n+1];
      for (int i=a+1;i<b;i++){
        int v = ls[i]; int j=i-1;
        while (j>=a && ls[j]>v){ ls[j+1]=ls[j]; j--; }
        ls[j+1]=v;
      }
    }
  }
}

// ---------------- chain compaction: block-local counting sort (no hot global atomics) ----------------
// bin = p*64 + min(len,63), len>=1. bhist layout: bhist[bin*NBLK + blk].
__global__ void k_cbin1(const int* __restrict__ sstart, const int* __restrict__ dstart,
                        int* __restrict__ bhist){
  __shared__ int h[128];
  int tid = threadIdx.x, blk = blockIdx.x;
  if (tid < 128) h[tid] = 0;
  __syncthreads();
  int n = blk*256 + tid;
  if (n < N_NODES){
    int c = sstart[n+1]-sstart[n];
    if (c>0) atomicAdd(&h[min(c,63)], 1);
    int c2 = dstart[n+1]-dstart[n];
    if (c2>0) atomicAdd(&h[64+min(c2,63)], 1);
  }
  __syncthreads();
  if (tid < 128) bhist[tid*NBLK + blk] = h[tid];
}

// exclusive scan over sequence ordered (pass, len desc 63..1, block 0..NBLK-1)
__global__ void k_cbin2(const int* __restrict__ bhist, int* __restrict__ boff,
                        int* __restrict__ nchains){
  const int S = 2*63*NBLK;   // 9954
  const int CH = 10;
  int tid = threadIdx.x;
  int v[CH]; int tsum = 0;
  int binidx[CH];
  #pragma unroll
  for (int j=0;j<CH;j++){
    int s = tid*CH + j;
    int val = 0, bi = -1;
    if (s < S){
      int p = s / (63*NBLK);
      int r = s - p*63*NBLK;
      int li = r / NBLK;           // 0..62
      int b  = r - li*NBLK;
      int l  = 63 - li;            // 63..1
      bi = (p*64 + l)*NBLK + b;
      val = bhist[bi];
    }
    binidx[j] = bi; v[j] = val; tsum += val;
  }
  int lane = tid & 63, wv = tid >> 6;
  int incl = tsum;
  #pragma unroll
  for (int m=1;m<64;m<<=1){ int u = __shfl_up(incl, m); if (lane >= m) incl += u; }
  __shared__ int wsum[16], woff[16];
  __shared__ int pend[2];
  if (lane==63) wsum[wv] = incl;
  __syncthreads();
  if (tid < 16){ int s=0; for (int k=0;k<tid;k++) s += wsum[k]; woff[tid]=s; }
  __syncthreads();
  int run = woff[wv] + incl - tsum;
  #pragma unroll
  for (int j=0;j<CH;j++){
    int s = tid*CH + j;
    if (s < S){
      boff[binidx[j]] = run;
      run += v[j];
      if (s == 63*NBLK - 1) pend[0] = run;
      if (s == S - 1)       pend[1] = run;
    }
  }
  __syncthreads();
  if (tid == 0){
    nchains[0] = pend[0];
    nchains[1] = pend[1] - pend[0];
  }
}

__global__ void k_cbin3(const int* __restrict__ sstart, const int* __restrict__ dstart,
                        const int* __restrict__ boff, const int* __restrict__ nchains,
                        int* __restrict__ cnode, int* __restrict__ cstart,
                        int* __restrict__ clen){
  __shared__ int h[128];
  int tid = threadIdx.x, blk = blockIdx.x;
  if (tid < 128) h[tid] = 0;
  __syncthreads();
  int n = blk*256 + tid;
  int bin0=-1, bin1=-1, r0=0, r1=0, a0=0, c0=0, a1=0, c1=0;
  if (n < N_NODES){
    a0 = sstart[n]; c0 = sstart[n+1]-a0;
    if (c0>0){ bin0 = min(c0,63);      r0 = atomicAdd(&h[bin0], 1); }
    a1 = dstart[n]; c1 = dstart[n+1]-a1;
    if (c1>0){ bin1 = 64+min(c1,63);   r1 = atomicAdd(&h[bin1], 1); }
  }
  __syncthreads();
  int nch0 = nchains[0];
  if (bin0 >= 0){
    int pos = boff[bin0*NBLK + blk] + r0;
    cnode[pos] = n; cstart[pos] = a0; clen[pos] = c0;
  }
  if (bin1 >= 0){
    int pos = boff[bin1*NBLK + blk] + r1 - nch0;
    cnode[N_NODES+pos] = n; cstart[N_NODES+pos] = a1; clen[N_NODES+pos] = c1;
  }
}

// ---------------- persistent MFMA LSTM: Whh bf16 in LDS, 16 chains/batch ----------------
#define LDS_G 131072
#define LDS_H 147456
#define LDS_META 151552
#define LDSZ 151936

__global__ __launch_bounds__(512, 1) void k_lstm3(
    const float* __restrict__ pre2, const float* __restrict__ Whh,
    const int* __restrict__ cnode, const int* __restrict__ cstart,
    const int* __restrict__ clen, const int* __restrict__ nchains,
    const int* __restrict__ slist, const int* __restrict__ dlist,
    const int* __restrict__ dcnt, int* __restrict__ ctr,
    float* __restrict__ emb){
  extern __shared__ char smem[];
  int tid = threadIdx.x;
  int lane = tid & 63, wv = tid >> 6;
  #pragma unroll 1
  for (int q=0;q<16;q++){
    int c = q*512 + tid;
    int n = c >> 4, k8 = c & 15;
    int orig = (n&3)*128 + (n>>2);
    const float* src = Whh + (size_t)orig*128 + k8*8;
    s16x8 v8;
    #pragma unroll
    for (int j=0;j<8;j++) v8[j] = (short)f2bf(src[j]);
    int byt = (n*256 + k8*16) ^ ((n&7)<<4);
    *(s16x8*)(smem + byt) = v8;
  }
  int nch0 = nchains[0], nch1 = nchains[1];
  int B0 = (nch0+15)>>4, B1 = (nch1+15)>>4;
  int* M = (int*)(smem + LDS_META);
  int d  = tid & 127, cg = tid >> 7;
  __syncthreads();
  while (true){
    if (tid==0) M[80] = atomicAdd(ctr, 1);
    __syncthreads();
    int nb = M[80];
    if (nb >= B0 + B1) break;
    int pass = (nb >= B0) ? 1 : 0;
    int batch = pass ? nb - B0 : nb;
    int b0 = batch << 4;
    int nch = pass ? nch1 : nch0;
    const int* list = pass ? dlist : slist;
    if (tid < 16){
      int j = b0 + tid;
      int valid = (j < nch);
      int ci = pass*N_NODES + j;
      int st = valid ? cstart[ci] : 0;
      int ln = valid ? clen[ci] : 0;
      M[tid] = ln; M[16+tid] = st; M[32+tid] = valid ? cnode[ci] : -1;
      M[48+tid] = (ln > 0) ? list[st] : 0;
    }
    *(unsigned long long*)(smem + LDS_H + tid*8) = 0ull;
    float cst[4]  = {0.f,0.f,0.f,0.f};
    float hreg[4] = {0.f,0.f,0.f,0.f};
    __syncthreads();
    int ml = 0;
    #pragma unroll 1
    for (int j=0;j<16;j++) ml = max(ml, M[j]);
    for (int t=0; t<ml; t++){
      f32x4 D[4];
      #pragma unroll
      for (int i=0;i<4;i++) D[i] = (f32x4){0.f,0.f,0.f,0.f};
      int row = lane & 15;
      int col = lane & 15;
      #pragma unroll
      for (int ks=0; ks<4; ks++){
        int kb = ks*64 + (lane>>4)*16;
        s16x8 a = *(const s16x8*)(smem + LDS_H + ((row*256 + kb) ^ ((row&7)<<4)));
        #pragma unroll
        for (int i=0;i<4;i++){
          int n = wv*64 + i*16 + col;
          s16x8 b = *(const s16x8*)(smem + ((n*256 + kb) ^ ((n&7)<<4)));
          D[i] = __builtin_amdgcn_mfma_f32_16x16x32_bf16(a, b, D[i], 0, 0, 0);
        }
      }
      int rb = (lane>>4)*4;
      #pragma unroll
      for (int i=0;i<4;i++){
        int n = wv*64 + i*16 + col;
        #pragma unroll
        for (int q=0;q<4;q++){
          int r = rb + q;
          *(short*)(smem + LDS_G + ((r*1024 + n*2) ^ ((r&7)<<4))) = (short)f2bf(D[i][q]);
        }
      }
      __syncthreads();
      const int* eid = M + 48 + ((t&1)<<4);
      #pragma unroll
      for (int jj=0;jj<4;jj++){
        int r = cg*4 + jj;
        if (t < M[r]){
          f32x4 pv = *(const f32x4*)(pre2 + (size_t)eid[r]*512 + d*4);
          s16x4 gs = *(const s16x4*)(smem + LDS_G + ((r*1024 + d*8) ^ ((r&7)<<4)));
          float g0 = bf2f(gs[0]) + pv[0];
          float g1 = bf2f(gs[1]) + pv[1];
          float g2 = bf2f(gs[2]) + pv[2];
          float g3 = bf2f(gs[3]) + pv[3];
          float iv = sigf(g0), fv = sigf(g1), gv = tanh_f(g2), ov = sigf(g3);
          cst[jj] = fv*cst[jj] + iv*gv;
          float h = ov * tanh_f(cst[jj]);
          hreg[jj] = h;
          *(short*)(smem + LDS_H + ((r*256 + d*2) ^ ((r&7)<<4))) = (short)f2bf(h);
        }
      }
      if (tid < 16){
        int ln = M[tid];
        M[48 + (((t+1)&1)<<4) + tid] = (t+1 < ln) ? list[M[16+tid] + t+1] : 0;
      }
      __syncthreads();
    }
    #pragma unroll
    for (int jj=0;jj<4;jj++){
      int r = cg*4 + jj;
      int n = M[32+r];
      if (M[r] > 0 && n >= 0 && !(pass==0 && dcnt[n] > 0)){
        emb[(size_t)n*128 + d] = hreg[jj];
      }
    }
    __syncthreads();
  }
}

// ---------------- final MLP + LayerNorm + out : 8 nodes per block ----------------
__global__ void k_mlp(const float* __restrict__ x, const float* __restrict__ emb,
                      const float* __restrict__ fc1wT, const float* __restrict__ fc1b,
                      const float* __restrict__ lng, const float* __restrict__ lnb,
                      const float* __restrict__ outw, const float* __restrict__ outb,
                      float* __restrict__ out){
  __shared__ float xc[8][384];
  int nb = blockIdx.x*8;
  int tid = threadIdx.x;
  for (int i=tid; i<8*256; i+=256){ int nd=i>>8, dd=i&255; xc[nd][dd] = x[(size_t)(nb+nd)*256 + dd]; }
  for (int i=tid; i<8*128; i+=256){ int nd=i>>7, dd=i&127; xc[nd][256+dd] = emb[(size_t)(nb+nd)*128 + dd]; }
  __syncthreads();
  int nd = tid >> 5;
  int lo = tid & 31;
  float acc[4];
  #pragma unroll
  for (int q=0;q<4;q++) acc[q] = fc1b[lo + 32*q];
  for (int k=0;k<384;k++){
    float xv = xc[nd][k];
    #pragma unroll
    for (int q=0;q<4;q++) acc[q] += fc1wT[k*128 + lo + 32*q] * xv;
  }
  float s = acc[0]+acc[1]+acc[2]+acc[3];
  #pragma unroll
  for (int m=16;m>=1;m>>=1) s += __shfl_xor(s, m);
  float mu = s * (1.f/128.f);
  float v = 0.f;
  #pragma unroll
  for (int q=0;q<4;q++){ float dm = acc[q]-mu; v += dm*dm; }
  #pragma unroll
  for (int m=16;m>=1;m>>=1) v += __shfl_xor(v, m);
  float rstd = rsqrtf(v*(1.f/128.f) + 1e-5f);
  float o0 = 0.f, o1 = 0.f;
  #pragma unroll
  for (int q=0;q<4;q++){
    int o = lo + 32*q;
    float h1 = (acc[q]-mu)*rstd*lng[o] + lnb[o];
    h1 = fmaxf(h1, 0.f);
    o0 += h1*outw[o];
    o1 += h1*outw[128+o];
  }
  #pragma unroll
  for (int m=16;m>=1;m>>=1){ o0 += __shfl_xor(o0, m); o1 += __shfl_xor(o1, m); }
  if (lo==0){
    out[(size_t)(nb+nd)*2]   = o0 + outb[0];
    out[(size_t)(nb+nd)*2+1] = o1 + outb[1];
  }
}

extern "C" void kernel_launch(void* const* d_in, const int* in_sizes, int n_in,
                              void* d_out, int out_size, void* d_ws, size_t ws_size,
                              hipStream_t stream){
  const float* x      = (const float*)d_in[0];
  const int*   heads  = (const int*)d_in[1];
  const int*   rels   = (const int*)d_in[2];
  const int*   tails  = (const int*)d_in[3];
  const float* weeks  = (const float*)d_in[4];
  const int*   esrc   = (const int*)d_in[5];
  const int*   edst   = (const int*)d_in[6];
  const float* ent    = (const float*)d_in[10];
  const float* rel_e  = (const float*)d_in[11];
  const float* wfreq  = (const float*)d_in[12];
  const float* wphi   = (const float*)d_in[13];
  const float* wamp   = (const float*)d_in[14];
  const float* Wih    = (const float*)d_in[15];
  const float* Whh    = (const float*)d_in[16];
  const float* bih    = (const float*)d_in[17];
  const float* bhh    = (const float*)d_in[18];
  const float* fc1w   = (const float*)d_in[19];
  const float* fc1b   = (const float*)d_in[20];
  const float* lng    = (const float*)d_in[21];
  const float* lnb    = (const float*)d_in[22];
  const float* outw   = (const float*)d_in[23];
  const float* outb   = (const float*)d_in[24];
  float* out = (float*)d_out;

  char* ws = (char*)d_ws;
  size_t off = 0;
  auto alloc = [&](size_t bytes){ void* p = ws + off; off += (bytes + 255) & ~(size_t)255; return p; };
  float* pre2   = (float*)alloc((size_t)N_EDGES*512*4);
  float* WihT2  = (float*)alloc(512*128*4);
  float* fc1wT  = (float*)alloc(384*128*4);
  float* emb    = (float*)alloc((size_t)N_NODES*128*4);
  int* sstart   = (int*)alloc((N_NODES+1)*4);
  int* dstart   = (int*)alloc((N_NODES+1)*4);
  // zero-region: cnts(4N) + nchains(2) + ctr(1)
  int* zreg     = (int*)alloc((size_t)(4*N_NODES + 3)*4);
  int* scnt = zreg, *dcnt = zreg+N_NODES, *sc2 = zreg+2*N_NODES, *dc2 = zreg+3*N_NODES;
  int* nchains  = zreg + 4*N_NODES;
  int* ctr      = nchains + 2;
  int* bhist    = (int*)alloc((size_t)128*NBLK*4);
  int* boff     = (int*)alloc((size_t)128*NBLK*4);
  int* slist    = (int*)alloc(N_EDGES*4);
  int* dlist    = (int*)alloc(N_EDGES*4);
  int* cnode    = (int*)alloc((size_t)2*N_NODES*4);
  int* cstart   = (int*)alloc((size_t)2*N_NODES*4);
  int* clen     = (int*)alloc((size_t)2*N_NODES*4);

  hipMemsetAsync(zreg, 0, (size_t)(4*N_NODES + 3)*4, stream);
  hipMemsetAsync(emb, 0, (size_t)N_NODES*128*4, stream);

  hipFuncSetAttribute((const void*)k_lstm3, hipFuncAttributeMaxDynamicSharedMemorySize, LDSZ);

  k_transperm<<<(512*128+255)/256, 256, 0, stream>>>(Wih, WihT2);
  k_transpose<<<(128*384+255)/256, 256, 0, stream>>>(fc1w, fc1wT, 128, 384);

  k_edge<<<N_EDGES/16, 256, 0, stream>>>(heads, rels, tails, weeks, ent, rel_e,
                                         wfreq, wphi, wamp, WihT2, bih, bhh, pre2);
  k_hist<<<(N_EDGES+255)/256, 256, 0, stream>>>(esrc, edst, scnt, dcnt);
  k_scan<<<2, 1024, 0, stream>>>(scnt, dcnt, sstart, dstart);
  k_scatter<<<(N_EDGES+255)/256, 256, 0, stream>>>(esrc, edst, sstart, dstart, sc2, dc2, slist, dlist);
  k_sortlists<<<(N_NODES+255)/256, 256, 0, stream>>>(sstart, dstart, slist, dlist);
  k_cbin1<<<NBLK, 256, 0, stream>>>(sstart, dstart, bhist);
  k_cbin2<<<1, 1024, 0, stream>>>(bhist, boff, nchains);
  k_cbin3<<<NBLK, 256, 0, stream>>>(sstart, dstart, boff, nchains, cnode, cstart, clen);
  k_lstm3<<<256, 512, LDSZ, stream>>>(pre2, Whh, cnode, cstart, clen, nchains,
                                      slist, dlist, dcnt, ctr, emb);
  k_mlp<<<N_NODES/8, 256, 0, stream>>>(x, emb, fc1wT, fc1b, lng, lnb, outw, outb, out);
}

// Round 5
// 263.990 us; speedup vs baseline: 3.7258x; 1.3533x over previous
//
#include <hip/hip_runtime.h>
#include <math.h>

#define N_NODES 20000
#define N_EDGES 40000
#define SE 46
#define TE 82
#define NBLK 79   // ceil(N_NODES/256)
// D = 128, 4D = 512, F = 256, HID = 128

typedef short  s16x8 __attribute__((ext_vector_type(8)));
typedef short  s16x4 __attribute__((ext_vector_type(4)));
typedef float  f32x4 __attribute__((ext_vector_type(4)));

__device__ __forceinline__ float sigf(float x){ return 1.0f/(1.0f+__expf(-x)); }
__device__ __forceinline__ float tanh_f(float x){ return 1.0f - 2.0f/(__expf(2.0f*x)+1.0f); }
__device__ __forceinline__ int perm_out(int i){ return (i&3)*128 + (i>>2); }
__device__ __forceinline__ unsigned short f2bf(float f){
  unsigned u = __builtin_bit_cast(unsigned, f);
  unsigned r = (u + 0x7fff + ((u>>16)&1)) >> 16;
  return (unsigned short)r;
}
__device__ __forceinline__ float bf2f(short s){
  unsigned u = ((unsigned)(unsigned short)s) << 16;
  return __builtin_bit_cast(float, u);
}

// gate-interleaved transpose: out[k*512 + i] = in[perm(i)*128 + k]
__global__ void k_transperm(const float* __restrict__ in, float* __restrict__ out){
  int idx = blockIdx.x*blockDim.x + threadIdx.x;
  if (idx < 512*128){
    int k = idx >> 9, i = idx & 511;
    out[idx] = in[perm_out(i)*128 + k];
  }
}

// f32 -> bf16 convert
__global__ void k_prepw(const float* __restrict__ in, short* __restrict__ out, int n){
  int i = blockIdx.x*blockDim.x + threadIdx.x;
  if (i < n) out[i] = (short)f2bf(in[i]);
}

// ---------------- edge features + pre2 = permuted(scores @ Wih^T + bih + bhh) ----------------
__global__ void k_edge(const int* __restrict__ heads, const int* __restrict__ rels,
                       const int* __restrict__ tails, const float* __restrict__ weeks,
                       const float* __restrict__ ent, const float* __restrict__ rel_embs,
                       const float* __restrict__ wfreq, const float* __restrict__ wphi,
                       const float* __restrict__ wamp,
                       const float* __restrict__ WihT2, const float* __restrict__ bih,
                       const float* __restrict__ bhh, float* __restrict__ pre2){
  __shared__ float s2[128][16];   // s2[k][edge]
  int e0 = blockIdx.x * 16;
  int tid = threadIdx.x;
  #pragma unroll
  for (int q=0;q<8;q++){
    int idx = tid + 256*q;          // 0..2047
    int el = idx >> 7, d = idx & 127;
    int e = e0 + el;
    int hd = heads[e], tl = tails[e], rl = rels[e];
    float wk = weeks[e];
    float hv, tv;
    if (d < SE){
      hv = ent[(size_t)hd*SE + d];
      tv = ent[(size_t)tl*SE + d];
    } else {
      int dt = d - SE;
      hv = wamp[(size_t)hd*TE+dt] * __sinf(wfreq[(size_t)hd*TE+dt]*wk + wphi[(size_t)hd*TE+dt]);
      tv = wamp[(size_t)tl*TE+dt] * __sinf(wfreq[(size_t)tl*TE+dt]*wk + wphi[(size_t)tl*TE+dt]);
    }
    float rv = rel_embs[rl*128 + d];
    s2[d][el] = hv * rv * tv;
  }
  __syncthreads();
  float acc0[16], acc1[16];
  #pragma unroll
  for (int e=0;e<16;e++){ acc0[e]=0.f; acc1[e]=0.f; }
  for (int k=0;k<128;k++){
    float w0 = WihT2[k*512 + tid];
    float w1 = WihT2[k*512 + tid + 256];
    const float4* sp = (const float4*)&s2[k][0];
    float4 sa = sp[0], sb = sp[1], sc = sp[2], sd = sp[3];
    float sv[16] = {sa.x,sa.y,sa.z,sa.w, sb.x,sb.y,sb.z,sb.w,
                    sc.x,sc.y,sc.z,sc.w, sd.x,sd.y,sd.z,sd.w};
    #pragma unroll
    for (int e=0;e<16;e++){ acc0[e] += w0*sv[e]; acc1[e] += w1*sv[e]; }
  }
  float b0 = bih[perm_out(tid)]     + bhh[perm_out(tid)];
  float b1 = bih[perm_out(tid+256)] + bhh[perm_out(tid+256)];
  #pragma unroll
  for (int e=0;e<16;e++){
    pre2[(size_t)(e0+e)*512 + tid]       = acc0[e] + b0;
    pre2[(size_t)(e0+e)*512 + tid + 256] = acc1[e] + b1;
  }
}

// ---------------- grouping machinery ----------------
__global__ void k_hist(const int* __restrict__ src, const int* __restrict__ dst,
                       int* __restrict__ scnt, int* __restrict__ dcnt){
  int e = blockIdx.x*blockDim.x + threadIdx.x;
  if (e < N_EDGES){ atomicAdd(&scnt[src[e]],1); atomicAdd(&dcnt[dst[e]],1); }
}

// fast scan: 1024 threads, 20 elems each, shuffle-based
__global__ void k_scan(const int* __restrict__ scnt, const int* __restrict__ dcnt,
                       int* __restrict__ sstart, int* __restrict__ dstart){
  const int* cnt = blockIdx.x ? dcnt : scnt;
  int* start = blockIdx.x ? dstart : sstart;
  const int CH = 20;
  int tid = threadIdx.x;
  int base = tid*CH;
  int v[CH]; int tsum = 0;
  #pragma unroll
  for (int j=0;j<CH;j++){ int i = base+j; v[j] = (i<N_NODES)? cnt[i] : 0; tsum += v[j]; }
  int lane = tid & 63, wv = tid >> 6;
  int incl = tsum;
  #pragma unroll
  for (int m=1;m<64;m<<=1){ int u = __shfl_up(incl, m); if (lane >= m) incl += u; }
  __shared__ int wsum[16], woff[16];
  if (lane==63) wsum[wv] = incl;
  __syncthreads();
  if (tid < 16){ int s=0; for (int k=0;k<tid;k++) s += wsum[k]; woff[tid]=s; }
  __syncthreads();
  int run = woff[wv] + incl - tsum;
  #pragma unroll
  for (int j=0;j<CH;j++){ int i = base+j; if (i<N_NODES) start[i] = run; run += v[j]; }
  if (tid == 1023) start[N_NODES] = run;
}

__global__ void k_scatter(const int* __restrict__ src, const int* __restrict__ dst,
                          const int* __restrict__ sstart, const int* __restrict__ dstart,
                          int* __restrict__ sc2, int* __restrict__ dc2,
                          int* __restrict__ slist, int* __restrict__ dlist){
  int e = blockIdx.x*blockDim.x + threadIdx.x;
  if (e < N_EDGES){
    int s = src[e]; int p  = sstart[s] + atomicAdd(&sc2[s],1); slist[p]=e;
    int d = dst[e]; int p2 = dstart[d] + atomicAdd(&dc2[d],1); dlist[p2]=e;
  }
}

__global__ void k_sortlists(const int* __restrict__ sstart, const int* __restrict__ dstart,
                            int* __restrict__ slist, int* __restrict__ dlist){
  int n = blockIdx.x*blockDim.x + threadIdx.x;
  if (n < N_NODES){
    #pragma unroll
    for (int pass=0; pass<2; pass++){
      const int* st = pass ? dstart : sstart;
      int* ls = pass ? dlist : slist;
      int a = st[n], b = st[n+1];
      for (int i=a+1;i<b;i++){
        int v = ls[i]; int j=i-1;
        while (j>=a && ls[j]>v){ ls[j+1]=ls[j]; j--; }
        ls[j+1]=v;
      }
    }
  }
}

// ---------------- chain compaction: block-local counting sort ----------------
__global__ void k_cbin1(const int* __restrict__ sstart, const int* __restrict__ dstart,
                        int* __restrict__ bhist){
  __shared__ int h[128];
  int tid = threadIdx.x, blk = blockIdx.x;
  if (tid < 128) h[tid] = 0;
  __syncthreads();
  int n = blk*256 + tid;
  if (n < N_NODES){
    int c = sstart[n+1]-sstart[n];
    if (c>0) atomicAdd(&h[min(c,63)], 1);
    int c2 = dstart[n+1]-dstart[n];
    if (c2>0) atomicAdd(&h[64+min(c2,63)], 1);
  }
  __syncthreads();
  if (tid < 128) bhist[tid*NBLK + blk] = h[tid];
}

__global__ void k_cbin2(const int* __restrict__ bhist, int* __restrict__ boff,
                        int* __restrict__ nchains){
  const int S = 2*63*NBLK;   // 9954
  const int CH = 10;
  int tid = threadIdx.x;
  int v[CH]; int tsum = 0;
  int binidx[CH];
  #pragma unroll
  for (int j=0;j<CH;j++){
    int s = tid*CH + j;
    int val = 0, bi = -1;
    if (s < S){
      int p = s / (63*NBLK);
      int r = s - p*63*NBLK;
      int li = r / NBLK;
      int b  = r - li*NBLK;
      int l  = 63 - li;
      bi = (p*64 + l)*NBLK + b;
      val = bhist[bi];
    }
    binidx[j] = bi; v[j] = val; tsum += val;
  }
  int lane = tid & 63, wv = tid >> 6;
  int incl = tsum;
  #pragma unroll
  for (int m=1;m<64;m<<=1){ int u = __shfl_up(incl, m); if (lane >= m) incl += u; }
  __shared__ int wsum[16], woff[16];
  __shared__ int pend[2];
  if (lane==63) wsum[wv] = incl;
  __syncthreads();
  if (tid < 16){ int s=0; for (int k=0;k<tid;k++) s += wsum[k]; woff[tid]=s; }
  __syncthreads();
  int run = woff[wv] + incl - tsum;
  #pragma unroll
  for (int j=0;j<CH;j++){
    int s = tid*CH + j;
    if (s < S){
      boff[binidx[j]] = run;
      run += v[j];
      if (s == 63*NBLK - 1) pend[0] = run;
      if (s == S - 1)       pend[1] = run;
    }
  }
  __syncthreads();
  if (tid == 0){
    nchains[0] = pend[0];
    nchains[1] = pend[1] - pend[0];
  }
}

__global__ void k_cbin3(const int* __restrict__ sstart, const int* __restrict__ dstart,
                        const int* __restrict__ boff, const int* __restrict__ nchains,
                        int* __restrict__ cnode, int* __restrict__ cstart,
                        int* __restrict__ clen){
  __shared__ int h[128];
  int tid = threadIdx.x, blk = blockIdx.x;
  if (tid < 128) h[tid] = 0;
  __syncthreads();
  int n = blk*256 + tid;
  int bin0=-1, bin1=-1, r0=0, r1=0, a0=0, c0=0, a1=0, c1=0;
  if (n < N_NODES){
    a0 = sstart[n]; c0 = sstart[n+1]-a0;
    if (c0>0){ bin0 = min(c0,63);      r0 = atomicAdd(&h[bin0], 1); }
    a1 = dstart[n]; c1 = dstart[n+1]-a1;
    if (c1>0){ bin1 = 64+min(c1,63);   r1 = atomicAdd(&h[bin1], 1); }
  }
  __syncthreads();
  int nch0 = nchains[0];
  if (bin0 >= 0){
    int pos = boff[bin0*NBLK + blk] + r0;
    cnode[pos] = n; cstart[pos] = a0; clen[pos] = c0;
  }
  if (bin1 >= 0){
    int pos = boff[bin1*NBLK + blk] + r1 - nch0;
    cnode[N_NODES+pos] = n; cstart[N_NODES+pos] = a1; clen[N_NODES+pos] = c1;
  }
}

// ---------------- persistent MFMA LSTM: Whh bf16 in LDS, 16 chains/batch ----------------
#define LDS_G 131072
#define LDS_H 147456
#define LDS_META 151552
#define LDSZ 151936

__global__ __launch_bounds__(512, 1) void k_lstm3(
    const float* __restrict__ pre2, const float* __restrict__ Whh,
    const int* __restrict__ cnode, const int* __restrict__ cstart,
    const int* __restrict__ clen, const int* __restrict__ nchains,
    const int* __restrict__ slist, const int* __restrict__ dlist,
    const int* __restrict__ dcnt, int* __restrict__ ctr,
    float* __restrict__ emb){
  extern __shared__ char smem[];
  int tid = threadIdx.x;
  int lane = tid & 63, wv = tid >> 6;
  #pragma unroll 1
  for (int q=0;q<16;q++){
    int c = q*512 + tid;
    int n = c >> 4, k8 = c & 15;
    int orig = (n&3)*128 + (n>>2);
    const float* src = Whh + (size_t)orig*128 + k8*8;
    s16x8 v8;
    #pragma unroll
    for (int j=0;j<8;j++) v8[j] = (short)f2bf(src[j]);
    int byt = (n*256 + k8*16) ^ ((n&7)<<4);
    *(s16x8*)(smem + byt) = v8;
  }
  int nch0 = nchains[0], nch1 = nchains[1];
  int B0 = (nch0+15)>>4, B1 = (nch1+15)>>4;
  int* M = (int*)(smem + LDS_META);
  int d  = tid & 127, cg = tid >> 7;
  __syncthreads();
  while (true){
    if (tid==0) M[80] = atomicAdd(ctr, 1);
    __syncthreads();
    int nb = M[80];
    if (nb >= B0 + B1) break;
    int pass = (nb >= B0) ? 1 : 0;
    int batch = pass ? nb - B0 : nb;
    int b0 = batch << 4;
    int nch = pass ? nch1 : nch0;
    const int* list = pass ? dlist : slist;
    if (tid < 16){
      int j = b0 + tid;
      int valid = (j < nch);
      int ci = pass*N_NODES + j;
      int st = valid ? cstart[ci] : 0;
      int ln = valid ? clen[ci] : 0;
      M[tid] = ln; M[16+tid] = st; M[32+tid] = valid ? cnode[ci] : -1;
      M[48+tid] = (ln > 0) ? list[st] : 0;
    }
    *(unsigned long long*)(smem + LDS_H + tid*8) = 0ull;
    float cst[4]  = {0.f,0.f,0.f,0.f};
    float hreg[4] = {0.f,0.f,0.f,0.f};
    __syncthreads();
    int ml = 0;
    #pragma unroll 1
    for (int j=0;j<16;j++) ml = max(ml, M[j]);
    for (int t=0; t<ml; t++){
      f32x4 D[4];
      #pragma unroll
      for (int i=0;i<4;i++) D[i] = (f32x4){0.f,0.f,0.f,0.f};
      int row = lane & 15;
      int col = lane & 15;
      #pragma unroll
      for (int ks=0; ks<4; ks++){
        int kb = ks*64 + (lane>>4)*16;
        s16x8 a = *(const s16x8*)(smem + LDS_H + ((row*256 + kb) ^ ((row&7)<<4)));
        #pragma unroll
        for (int i=0;i<4;i++){
          int n = wv*64 + i*16 + col;
          s16x8 b = *(const s16x8*)(smem + ((n*256 + kb) ^ ((n&7)<<4)));
          D[i] = __builtin_amdgcn_mfma_f32_16x16x32_bf16(a, b, D[i], 0, 0, 0);
        }
      }
      int rb = (lane>>4)*4;
      #pragma unroll
      for (int i=0;i<4;i++){
        int n = wv*64 + i*16 + col;
        #pragma unroll
        for (int q=0;q<4;q++){
          int r = rb + q;
          *(short*)(smem + LDS_G + ((r*1024 + n*2) ^ ((r&7)<<4))) = (short)f2bf(D[i][q]);
        }
      }
      __syncthreads();
      const int* eid = M + 48 + ((t&1)<<4);
      #pragma unroll
      for (int jj=0;jj<4;jj++){
        int r = cg*4 + jj;
        if (t < M[r]){
          f32x4 pv = *(const f32x4*)(pre2 + (size_t)eid[r]*512 + d*4);
          s16x4 gs = *(const s16x4*)(smem + LDS_G + ((r*1024 + d*8) ^ ((r&7)<<4)));
          float g0 = bf2f(gs[0]) + pv[0];
          float g1 = bf2f(gs[1]) + pv[1];
          float g2 = bf2f(gs[2]) + pv[2];
          float g3 = bf2f(gs[3]) + pv[3];
          float iv = sigf(g0), fv = sigf(g1), gv = tanh_f(g2), ov = sigf(g3);
          cst[jj] = fv*cst[jj] + iv*gv;
          float h = ov * tanh_f(cst[jj]);
          hreg[jj] = h;
          *(short*)(smem + LDS_H + ((r*256 + d*2) ^ ((r&7)<<4))) = (short)f2bf(h);
        }
      }
      if (tid < 16){
        int ln = M[tid];
        M[48 + (((t+1)&1)<<4) + tid] = (t+1 < ln) ? list[M[16+tid] + t+1] : 0;
      }
      __syncthreads();
    }
    #pragma unroll
    for (int jj=0;jj<4;jj++){
      int r = cg*4 + jj;
      int n = M[32+r];
      if (M[r] > 0 && n >= 0 && !(pass==0 && dcnt[n] > 0)){
        emb[(size_t)n*128 + d] = hreg[jj];
      }
    }
    __syncthreads();
  }
}

// ---------------- MFMA MLP: 32 nodes/block, fc1 GEMM + LN + out ----------------
__global__ __launch_bounds__(512) void k_mlp2(
    const float* __restrict__ x, const float* __restrict__ emb,
    const short* __restrict__ fc1wbf, const float* __restrict__ fc1b,
    const float* __restrict__ lng, const float* __restrict__ lnb,
    const float* __restrict__ outw, const float* __restrict__ outb,
    float* __restrict__ out){
  __shared__ char As[32*768];          // bf16 [32][384], XOR-swizzled rows
  __shared__ float hbuf[32][132];
  int tid = threadIdx.x;
  int lane = tid & 63, w = tid >> 6;
  int base = blockIdx.x * 32;
  // stage concat(x, emb) -> LDS bf16
  #pragma unroll
  for (int q=0;q<3;q++){
    int i = tid + 512*q;              // 0..1535, 48 chunks of 8 per row
    int r = i / 48, c = i - r*48;
    const float* src = (c < 32) ? (x + (size_t)(base+r)*256 + c*8)
                                : (emb + (size_t)(base+r)*128 + (c-32)*8);
    float4 v0 = *(const float4*)src;
    float4 v1 = *(const float4*)(src+4);
    s16x8 v8;
    v8[0]=(short)f2bf(v0.x); v8[1]=(short)f2bf(v0.y); v8[2]=(short)f2bf(v0.z); v8[3]=(short)f2bf(v0.w);
    v8[4]=(short)f2bf(v1.x); v8[5]=(short)f2bf(v1.y); v8[6]=(short)f2bf(v1.z); v8[7]=(short)f2bf(v1.w);
    *(s16x8*)(As + ((r*768 + c*16) ^ ((r&7)<<4))) = v8;
  }
  __syncthreads();
  // GEMM [32x384]@[384x128]: wave w -> cols w*16..+15, row tiles {0,16}
  int cl = lane & 15, kq = lane >> 4;
  f32x4 D0 = {0.f,0.f,0.f,0.f}, D1 = {0.f,0.f,0.f,0.f};
  const short* bp = fc1wbf + (size_t)(w*16 + cl)*384 + kq*8;
  #pragma unroll
  for (int ks=0; ks<12; ks++){
    s16x8 b = *(const s16x8*)(bp + ks*32);
    int kb = ks*64 + kq*16;           // byte offset within A row
    s16x8 a0 = *(const s16x8*)(As + (((cl   )*768 + kb) ^ ((cl&7)<<4)));
    s16x8 a1 = *(const s16x8*)(As + (((cl+16)*768 + kb) ^ (((cl+16)&7)<<4)));
    D0 = __builtin_amdgcn_mfma_f32_16x16x32_bf16(a0, b, D0, 0, 0, 0);
    D1 = __builtin_amdgcn_mfma_f32_16x16x32_bf16(a1, b, D1, 0, 0, 0);
  }
  int col = w*16 + cl;
  float bb = fc1b[col];
  #pragma unroll
  for (int q=0;q<4;q++){
    hbuf[kq*4+q][col]    = D0[q] + bb;
    hbuf[16+kq*4+q][col] = D1[q] + bb;
  }
  __syncthreads();
  // LN + out: wave w -> nodes w*4..+3, 16 lanes/node
  int sub = lane >> 4, l16 = lane & 15;
  int nd = w*4 + sub;
  float v[8];
  float s = 0.f;
  #pragma unroll
  for (int j=0;j<8;j++){ v[j] = hbuf[nd][l16*8+j]; s += v[j]; }
  #pragma unroll
  for (int m=1;m<16;m<<=1) s += __shfl_xor(s, m);
  float mu = s * (1.f/128.f);
  float va = 0.f;
  #pragma unroll
  for (int j=0;j<8;j++){ float dm = v[j]-mu; va += dm*dm; }
  #pragma unroll
  for (int m=1;m<16;m<<=1) va += __shfl_xor(va, m);
  float rstd = rsqrtf(va*(1.f/128.f) + 1e-5f);
  float o0=0.f, o1=0.f;
  #pragma unroll
  for (int j=0;j<8;j++){
    int c = l16*8+j;
    float h1 = (v[j]-mu)*rstd*lng[c] + lnb[c];
    h1 = fmaxf(h1, 0.f);
    o0 += h1*outw[c]; o1 += h1*outw[128+c];
  }
  #pragma unroll
  for (int m=1;m<16;m<<=1){ o0 += __shfl_xor(o0,m); o1 += __shfl_xor(o1,m); }
  if (l16==0){
    out[(size_t)(base+nd)*2]   = o0 + outb[0];
    out[(size_t)(base+nd)*2+1] = o1 + outb[1];
  }
}

extern "C" void kernel_launch(void* const* d_in, const int* in_sizes, int n_in,
                              void* d_out, int out_size, void* d_ws, size_t ws_size,
                              hipStream_t stream){
  const float* x      = (const float*)d_in[0];
  const int*   heads  = (const int*)d_in[1];
  const int*   rels   = (const int*)d_in[2];
  const int*   tails  = (const int*)d_in[3];
  const float* weeks  = (const float*)d_in[4];
  const int*   esrc   = (const int*)d_in[5];
  const int*   edst   = (const int*)d_in[6];
  const float* ent    = (const float*)d_in[10];
  const float* rel_e  = (const float*)d_in[11];
  const float* wfreq  = (const float*)d_in[12];
  const float* wphi   = (const float*)d_in[13];
  const float* wamp   = (const float*)d_in[14];
  const float* Wih    = (const float*)d_in[15];
  const float* Whh    = (const float*)d_in[16];
  const float* bih    = (const float*)d_in[17];
  const float* bhh    = (const float*)d_in[18];
  const float* fc1w   = (const float*)d_in[19];
  const float* fc1b   = (const float*)d_in[20];
  const float* lng    = (const float*)d_in[21];
  const float* lnb    = (const float*)d_in[22];
  const float* outw   = (const float*)d_in[23];
  const float* outb   = (const float*)d_in[24];
  float* out = (float*)d_out;

  char* ws = (char*)d_ws;
  size_t off = 0;
  auto alloc = [&](size_t bytes){ void* p = ws + off; off += (bytes + 255) & ~(size_t)255; return p; };
  float* pre2   = (float*)alloc((size_t)N_EDGES*512*4);
  float* WihT2  = (float*)alloc(512*128*4);
  short* fc1wbf = (short*)alloc(128*384*2);
  float* emb    = (float*)alloc((size_t)N_NODES*128*4);
  int* sstart   = (int*)alloc((N_NODES+1)*4);
  int* dstart   = (int*)alloc((N_NODES+1)*4);
  int* zreg     = (int*)alloc((size_t)(4*N_NODES + 3)*4);
  int* scnt = zreg, *dcnt = zreg+N_NODES, *sc2 = zreg+2*N_NODES, *dc2 = zreg+3*N_NODES;
  int* nchains  = zreg + 4*N_NODES;
  int* ctr      = nchains + 2;
  int* bhist    = (int*)alloc((size_t)128*NBLK*4);
  int* boff     = (int*)alloc((size_t)128*NBLK*4);
  int* slist    = (int*)alloc(N_EDGES*4);
  int* dlist    = (int*)alloc(N_EDGES*4);
  int* cnode    = (int*)alloc((size_t)2*N_NODES*4);
  int* cstart   = (int*)alloc((size_t)2*N_NODES*4);
  int* clen     = (int*)alloc((size_t)2*N_NODES*4);

  hipMemsetAsync(zreg, 0, (size_t)(4*N_NODES + 3)*4, stream);
  hipMemsetAsync(emb, 0, (size_t)N_NODES*128*4, stream);

  hipFuncSetAttribute((const void*)k_lstm3, hipFuncAttributeMaxDynamicSharedMemorySize, LDSZ);

  k_transperm<<<(512*128+255)/256, 256, 0, stream>>>(Wih, WihT2);
  k_prepw<<<(128*384+255)/256, 256, 0, stream>>>(fc1w, fc1wbf, 128*384);

  k_edge<<<N_EDGES/16, 256, 0, stream>>>(heads, rels, tails, weeks, ent, rel_e,
                                         wfreq, wphi, wamp, WihT2, bih, bhh, pre2);
  k_hist<<<(N_EDGES+255)/256, 256, 0, stream>>>(esrc, edst, scnt, dcnt);
  k_scan<<<2, 1024, 0, stream>>>(scnt, dcnt, sstart, dstart);
  k_scatter<<<(N_EDGES+255)/256, 256, 0, stream>>>(esrc, edst, sstart, dstart, sc2, dc2, slist, dlist);
  k_sortlists<<<(N_NODES+255)/256, 256, 0, stream>>>(sstart, dstart, slist, dlist);
  k_cbin1<<<NBLK, 256, 0, stream>>>(sstart, dstart, bhist);
  k_cbin2<<<1, 1024, 0, stream>>>(bhist, boff, nchains);
  k_cbin3<<<NBLK, 256, 0, stream>>>(sstart, dstart, boff, nchains, cnode, cstart, clen);
  k_lstm3<<<256, 512, LDSZ, stream>>>(pre2, Whh, cnode, cstart, clen, nchains,
                                      slist, dlist, dcnt, ctr, emb);
  k_mlp2<<<N_NODES/32, 512, 0, stream>>>(x, emb, fc1wbf, fc1b, lng, lnb, outw, outb, out);
}

// Round 6
// 261.494 us; speedup vs baseline: 3.7613x; 1.0095x over previous
//
#include <hip/hip_runtime.h>
#include <math.h>

#define N_NODES 20000
#define N_EDGES 40000
#define SE 46
#define TE 82
#define NBLK 79   // ceil(N_NODES/256)
// D = 128, 4D = 512, F = 256, HID = 128

typedef short  s16x8 __attribute__((ext_vector_type(8)));
typedef short  s16x4 __attribute__((ext_vector_type(4)));
typedef float  f32x4 __attribute__((ext_vector_type(4)));

__device__ __forceinline__ float sigf(float x){ return 1.0f/(1.0f+__expf(-x)); }
__device__ __forceinline__ float tanh_f(float x){ return 1.0f - 2.0f/(__expf(2.0f*x)+1.0f); }
__device__ __forceinline__ int perm_out(int i){ return (i&3)*128 + (i>>2); }
__device__ __forceinline__ unsigned short f2bf(float f){
  unsigned u = __builtin_bit_cast(unsigned, f);
  unsigned r = (u + 0x7fff + ((u>>16)&1)) >> 16;
  return (unsigned short)r;
}
__device__ __forceinline__ float bf2f(short s){
  unsigned u = ((unsigned)(unsigned short)s) << 16;
  return __builtin_bit_cast(float, u);
}

// f32 -> bf16 convert
__global__ void k_prepw(const float* __restrict__ in, short* __restrict__ out, int n){
  int i = blockIdx.x*blockDim.x + threadIdx.x;
  if (i < n) out[i] = (short)f2bf(in[i]);
}

// Wih -> bf16, permuted rows: out[i*128+k] = bf16(Wih[perm_out(i)*128+k])
__global__ void k_prepwih(const float* __restrict__ in, short* __restrict__ out){
  int idx = blockIdx.x*blockDim.x + threadIdx.x;
  if (idx < 512*128){
    int i = idx >> 7, k = idx & 127;
    out[idx] = (short)f2bf(in[perm_out(i)*128 + k]);
  }
}

// ---------------- edge features + MFMA GEMM: pre2 = perm(scores @ Wih^T + bih + bhh) ----------------
__global__ __launch_bounds__(256) void k_edge2(
    const int* __restrict__ heads, const int* __restrict__ rels,
    const int* __restrict__ tails, const float* __restrict__ weeks,
    const float* __restrict__ ent, const float* __restrict__ rel_embs,
    const float* __restrict__ wfreq, const float* __restrict__ wphi,
    const float* __restrict__ wamp,
    const short* __restrict__ WihB, const float* __restrict__ bih,
    const float* __restrict__ bhh, float* __restrict__ pre2){
  __shared__ char As[32*256];   // bf16 [32 edges][128 k], XOR-swizzled rows
  int e0 = blockIdx.x * 32;
  int tid = threadIdx.x;
  #pragma unroll
  for (int q=0;q<16;q++){
    int idx = tid + 256*q;          // 0..4095
    int el = idx >> 7, d = idx & 127;
    int e = e0 + el;
    int hd = heads[e], tl = tails[e], rl = rels[e];
    float wk = weeks[e];
    float hv, tv;
    if (d < SE){
      hv = ent[(size_t)hd*SE + d];
      tv = ent[(size_t)tl*SE + d];
    } else {
      int dt = d - SE;
      hv = wamp[(size_t)hd*TE+dt] * __sinf(wfreq[(size_t)hd*TE+dt]*wk + wphi[(size_t)hd*TE+dt]);
      tv = wamp[(size_t)tl*TE+dt] * __sinf(wfreq[(size_t)tl*TE+dt]*wk + wphi[(size_t)tl*TE+dt]);
    }
    float rv = rel_embs[rl*128 + d];
    float sc = hv * rv * tv;
    *(short*)(As + ((el*256 + d*2) ^ ((el&7)<<4))) = (short)f2bf(sc);
  }
  __syncthreads();
  int lane = tid & 63, w = tid >> 6;
  int cl = lane & 15, kq = lane >> 4;
  // hoist A fragments: a[m][ks], rows cl (m=0) and cl+16 (m=1)
  s16x8 a[2][4];
  #pragma unroll
  for (int ks=0;ks<4;ks++){
    int kb = ks*64 + kq*16;
    a[0][ks] = *(const s16x8*)(As + (((cl   )*256 + kb) ^ ((cl&7)<<4)));
    a[1][ks] = *(const s16x8*)(As + (((cl+16)*256 + kb) ^ (((cl+16)&7)<<4)));
  }
  f32x4 D[2][8];
  #pragma unroll
  for (int m=0;m<2;m++)
    #pragma unroll
    for (int i=0;i<8;i++) D[m][i] = (f32x4){0.f,0.f,0.f,0.f};
  #pragma unroll
  for (int i=0;i<8;i++){
    int n = w*128 + i*16 + cl;
    const short* bp = WihB + (size_t)n*128 + kq*8;
    #pragma unroll
    for (int ks=0;ks<4;ks++){
      s16x8 b = *(const s16x8*)(bp + ks*32);
      D[0][i] = __builtin_amdgcn_mfma_f32_16x16x32_bf16(a[0][ks], b, D[0][i], 0, 0, 0);
      D[1][i] = __builtin_amdgcn_mfma_f32_16x16x32_bf16(a[1][ks], b, D[1][i], 0, 0, 0);
    }
  }
  // epilogue: D rows = edges, cols = n; add bias, store f32
  #pragma unroll
  for (int i=0;i<8;i++){
    int n = w*128 + i*16 + cl;
    int pn = perm_out(n);
    float bb = bih[pn] + bhh[pn];
    #pragma unroll
    for (int m=0;m<2;m++){
      #pragma unroll
      for (int q2=0;q2<4;q2++){
        int row = m*16 + kq*4 + q2;
        pre2[(size_t)(e0+row)*512 + n] = D[m][i][q2] + bb;
      }
    }
  }
}

// ---------------- grouping machinery ----------------
__global__ void k_hist(const int* __restrict__ src, const int* __restrict__ dst,
                       int* __restrict__ scnt, int* __restrict__ dcnt){
  int e = blockIdx.x*blockDim.x + threadIdx.x;
  if (e < N_EDGES){ atomicAdd(&scnt[src[e]],1); atomicAdd(&dcnt[dst[e]],1); }
}

// fast scan: 1024 threads, 20 elems each, shuffle-based
__global__ void k_scan(const int* __restrict__ scnt, const int* __restrict__ dcnt,
                       int* __restrict__ sstart, int* __restrict__ dstart){
  const int* cnt = blockIdx.x ? dcnt : scnt;
  int* start = blockIdx.x ? dstart : sstart;
  const int CH = 20;
  int tid = threadIdx.x;
  int base = tid*CH;
  int v[CH]; int tsum = 0;
  #pragma unroll
  for (int j=0;j<CH;j++){ int i = base+j; v[j] = (i<N_NODES)? cnt[i] : 0; tsum += v[j]; }
  int lane = tid & 63, wv = tid >> 6;
  int incl = tsum;
  #pragma unroll
  for (int m=1;m<64;m<<=1){ int u = __shfl_up(incl, m); if (lane >= m) incl += u; }
  __shared__ int wsum[16], woff[16];
  if (lane==63) wsum[wv] = incl;
  __syncthreads();
  if (tid < 16){ int s=0; for (int k=0;k<tid;k++) s += wsum[k]; woff[tid]=s; }
  __syncthreads();
  int run = woff[wv] + incl - tsum;
  #pragma unroll
  for (int j=0;j<CH;j++){ int i = base+j; if (i<N_NODES) start[i] = run; run += v[j]; }
  if (tid == 1023) start[N_NODES] = run;
}

__global__ void k_scatter(const int* __restrict__ src, const int* __restrict__ dst,
                          const int* __restrict__ sstart, const int* __restrict__ dstart,
                          int* __restrict__ sc2, int* __restrict__ dc2,
                          int* __restrict__ slist, int* __restrict__ dlist){
  int e = blockIdx.x*blockDim.x + threadIdx.x;
  if (e < N_EDGES){
    int s = src[e]; int p  = sstart[s] + atomicAdd(&sc2[s],1); slist[p]=e;
    int d = dst[e]; int p2 = dstart[d] + atomicAdd(&dc2[d],1); dlist[p2]=e;
  }
}

__global__ void k_sortlists(const int* __restrict__ sstart, const int* __restrict__ dstart,
                            int* __restrict__ slist, int* __restrict__ dlist){
  int n = blockIdx.x*blockDim.x + threadIdx.x;
  if (n < N_NODES){
    #pragma unroll
    for (int pass=0; pass<2; pass++){
      const int* st = pass ? dstart : sstart;
      int* ls = pass ? dlist : slist;
      int a = st[n], b = st[n+1];
      for (int i=a+1;i<b;i++){
        int v = ls[i]; int j=i-1;
        while (j>=a && ls[j]>v){ ls[j+1]=ls[j]; j--; }
        ls[j+1]=v;
      }
    }
  }
}

// ---------------- chain compaction: block-local counting sort ----------------
__global__ void k_cbin1(const int* __restrict__ sstart, const int* __restrict__ dstart,
                        int* __restrict__ bhist){
  __shared__ int h[128];
  int tid = threadIdx.x, blk = blockIdx.x;
  if (tid < 128) h[tid] = 0;
  __syncthreads();
  int n = blk*256 + tid;
  if (n < N_NODES){
    int c = sstart[n+1]-sstart[n];
    if (c>0) atomicAdd(&h[min(c,63)], 1);
    int c2 = dstart[n+1]-dstart[n];
    if (c2>0) atomicAdd(&h[64+min(c2,63)], 1);
  }
  __syncthreads();
  if (tid < 128) bhist[tid*NBLK + blk] = h[tid];
}

__global__ void k_cbin2(const int* __restrict__ bhist, int* __restrict__ boff,
                        int* __restrict__ nchains){
  const int S = 2*63*NBLK;   // 9954
  const int CH = 10;
  int tid = threadIdx.x;
  int v[CH]; int tsum = 0;
  int binidx[CH];
  #pragma unroll
  for (int j=0;j<CH;j++){
    int s = tid*CH + j;
    int val = 0, bi = -1;
    if (s < S){
      int p = s / (63*NBLK);
      int r = s - p*63*NBLK;
      int li = r / NBLK;
      int b  = r - li*NBLK;
      int l  = 63 - li;
      bi = (p*64 + l)*NBLK + b;
      val = bhist[bi];
    }
    binidx[j] = bi; v[j] = val; tsum += val;
  }
  int lane = tid & 63, wv = tid >> 6;
  int incl = tsum;
  #pragma unroll
  for (int m=1;m<64;m<<=1){ int u = __shfl_up(incl, m); if (lane >= m) incl += u; }
  __shared__ int wsum[16], woff[16];
  __shared__ int pend[2];
  if (lane==63) wsum[wv] = incl;
  __syncthreads();
  if (tid < 16){ int s=0; for (int k=0;k<tid;k++) s += wsum[k]; woff[tid]=s; }
  __syncthreads();
  int run = woff[wv] + incl - tsum;
  #pragma unroll
  for (int j=0;j<CH;j++){
    int s = tid*CH + j;
    if (s < S){
      boff[binidx[j]] = run;
      run += v[j];
      if (s == 63*NBLK - 1) pend[0] = run;
      if (s == S - 1)       pend[1] = run;
    }
  }
  __syncthreads();
  if (tid == 0){
    nchains[0] = pend[0];
    nchains[1] = pend[1] - pend[0];
  }
}

__global__ void k_cbin3(const int* __restrict__ sstart, const int* __restrict__ dstart,
                        const int* __restrict__ boff, const int* __restrict__ nchains,
                        int* __restrict__ cnode, int* __restrict__ cstart,
                        int* __restrict__ clen){
  __shared__ int h[128];
  int tid = threadIdx.x, blk = blockIdx.x;
  if (tid < 128) h[tid] = 0;
  __syncthreads();
  int n = blk*256 + tid;
  int bin0=-1, bin1=-1, r0=0, r1=0, a0=0, c0=0, a1=0, c1=0;
  if (n < N_NODES){
    a0 = sstart[n]; c0 = sstart[n+1]-a0;
    if (c0>0){ bin0 = min(c0,63);      r0 = atomicAdd(&h[bin0], 1); }
    a1 = dstart[n]; c1 = dstart[n+1]-a1;
    if (c1>0){ bin1 = 64+min(c1,63);   r1 = atomicAdd(&h[bin1], 1); }
  }
  __syncthreads();
  int nch0 = nchains[0];
  if (bin0 >= 0){
    int pos = boff[bin0*NBLK + blk] + r0;
    cnode[pos] = n; cstart[pos] = a0; clen[pos] = c0;
  }
  if (bin1 >= 0){
    int pos = boff[bin1*NBLK + blk] + r1 - nch0;
    cnode[N_NODES+pos] = n; cstart[N_NODES+pos] = a1; clen[N_NODES+pos] = c1;
  }
}

// ---------------- persistent MFMA LSTM: Whh bf16 in LDS, 16 chains/batch ----------------
#define LDS_G 131072
#define LDS_H 147456
#define LDS_META 151552
#define LDSZ 151936

__global__ __launch_bounds__(512, 1) void k_lstm3(
    const float* __restrict__ pre2, const float* __restrict__ Whh,
    const int* __restrict__ cnode, const int* __restrict__ cstart,
    const int* __restrict__ clen, const int* __restrict__ nchains,
    const int* __restrict__ slist, const int* __restrict__ dlist,
    const int* __restrict__ dcnt, int* __restrict__ ctr,
    float* __restrict__ emb){
  extern __shared__ char smem[];
  int tid = threadIdx.x;
  int lane = tid & 63, wv = tid >> 6;
  #pragma unroll 1
  for (int q=0;q<16;q++){
    int c = q*512 + tid;
    int n = c >> 4, k8 = c & 15;
    int orig = (n&3)*128 + (n>>2);
    const float* src = Whh + (size_t)orig*128 + k8*8;
    s16x8 v8;
    #pragma unroll
    for (int j=0;j<8;j++) v8[j] = (short)f2bf(src[j]);
    int byt = (n*256 + k8*16) ^ ((n&7)<<4);
    *(s16x8*)(smem + byt) = v8;
  }
  int nch0 = nchains[0], nch1 = nchains[1];
  int B0 = (nch0+15)>>4, B1 = (nch1+15)>>4;
  int* M = (int*)(smem + LDS_META);
  int d  = tid & 127, cg = tid >> 7;
  __syncthreads();
  while (true){
    if (tid==0) M[80] = atomicAdd(ctr, 1);
    __syncthreads();
    int nb = M[80];
    if (nb >= B0 + B1) break;
    int pass = (nb >= B0) ? 1 : 0;
    int batch = pass ? nb - B0 : nb;
    int b0 = batch << 4;
    int nch = pass ? nch1 : nch0;
    const int* list = pass ? dlist : slist;
    if (tid < 16){
      int j = b0 + tid;
      int valid = (j < nch);
      int ci = pass*N_NODES + j;
      int st = valid ? cstart[ci] : 0;
      int ln = valid ? clen[ci] : 0;
      M[tid] = ln; M[16+tid] = st; M[32+tid] = valid ? cnode[ci] : -1;
      M[48+tid] = (ln > 0) ? list[st] : 0;
    }
    *(unsigned long long*)(smem + LDS_H + tid*8) = 0ull;
    float cst[4]  = {0.f,0.f,0.f,0.f};
    float hreg[4] = {0.f,0.f,0.f,0.f};
    __syncthreads();
    int ml = 0;
    #pragma unroll 1
    for (int j=0;j<16;j++) ml = max(ml, M[j]);
    for (int t=0; t<ml; t++){
      f32x4 D[4];
      #pragma unroll
      for (int i=0;i<4;i++) D[i] = (f32x4){0.f,0.f,0.f,0.f};
      int row = lane & 15;
      int col = lane & 15;
      #pragma unroll
      for (int ks=0; ks<4; ks++){
        int kb = ks*64 + (lane>>4)*16;
        s16x8 a = *(const s16x8*)(smem + LDS_H + ((row*256 + kb) ^ ((row&7)<<4)));
        #pragma unroll
        for (int i=0;i<4;i++){
          int n = wv*64 + i*16 + col;
          s16x8 b = *(const s16x8*)(smem + ((n*256 + kb) ^ ((n&7)<<4)));
          D[i] = __builtin_amdgcn_mfma_f32_16x16x32_bf16(a, b, D[i], 0, 0, 0);
        }
      }
      int rb = (lane>>4)*4;
      #pragma unroll
      for (int i=0;i<4;i++){
        int n = wv*64 + i*16 + col;
        #pragma unroll
        for (int q=0;q<4;q++){
          int r = rb + q;
          *(short*)(smem + LDS_G + ((r*1024 + n*2) ^ ((r&7)<<4))) = (short)f2bf(D[i][q]);
        }
      }
      __syncthreads();
      const int* eid = M + 48 + ((t&1)<<4);
      #pragma unroll
      for (int jj=0;jj<4;jj++){
        int r = cg*4 + jj;
        if (t < M[r]){
          f32x4 pv = *(const f32x4*)(pre2 + (size_t)eid[r]*512 + d*4);
          s16x4 gs = *(const s16x4*)(smem + LDS_G + ((r*1024 + d*8) ^ ((r&7)<<4)));
          float g0 = bf2f(gs[0]) + pv[0];
          float g1 = bf2f(gs[1]) + pv[1];
          float g2 = bf2f(gs[2]) + pv[2];
          float g3 = bf2f(gs[3]) + pv[3];
          float iv = sigf(g0), fv = sigf(g1), gv = tanh_f(g2), ov = sigf(g3);
          cst[jj] = fv*cst[jj] + iv*gv;
          float h = ov * tanh_f(cst[jj]);
          hreg[jj] = h;
          *(short*)(smem + LDS_H + ((r*256 + d*2) ^ ((r&7)<<4))) = (short)f2bf(h);
        }
      }
      if (tid < 16){
        int ln = M[tid];
        M[48 + (((t+1)&1)<<4) + tid] = (t+1 < ln) ? list[M[16+tid] + t+1] : 0;
      }
      __syncthreads();
    }
    #pragma unroll
    for (int jj=0;jj<4;jj++){
      int r = cg*4 + jj;
      int n = M[32+r];
      if (M[r] > 0 && n >= 0 && !(pass==0 && dcnt[n] > 0)){
        emb[(size_t)n*128 + d] = hreg[jj];
      }
    }
    __syncthreads();
  }
}

// ---------------- MFMA MLP: 32 nodes/block, fc1 GEMM + LN + out ----------------
__global__ __launch_bounds__(512) void k_mlp2(
    const float* __restrict__ x, const float* __restrict__ emb,
    const short* __restrict__ fc1wbf, const float* __restrict__ fc1b,
    const float* __restrict__ lng, const float* __restrict__ lnb,
    const float* __restrict__ outw, const float* __restrict__ outb,
    float* __restrict__ out){
  __shared__ char As[32*768];          // bf16 [32][384], XOR-swizzled rows
  __shared__ float hbuf[32][132];
  int tid = threadIdx.x;
  int lane = tid & 63, w = tid >> 6;
  int base = blockIdx.x * 32;
  #pragma unroll
  for (int q=0;q<3;q++){
    int i = tid + 512*q;              // 0..1535, 48 chunks of 8 per row
    int r = i / 48, c = i - r*48;
    const float* src = (c < 32) ? (x + (size_t)(base+r)*256 + c*8)
                                : (emb + (size_t)(base+r)*128 + (c-32)*8);
    float4 v0 = *(const float4*)src;
    float4 v1 = *(const float4*)(src+4);
    s16x8 v8;
    v8[0]=(short)f2bf(v0.x); v8[1]=(short)f2bf(v0.y); v8[2]=(short)f2bf(v0.z); v8[3]=(short)f2bf(v0.w);
    v8[4]=(short)f2bf(v1.x); v8[5]=(short)f2bf(v1.y); v8[6]=(short)f2bf(v1.z); v8[7]=(short)f2bf(v1.w);
    *(s16x8*)(As + ((r*768 + c*16) ^ ((r&7)<<4))) = v8;
  }
  __syncthreads();
  int cl = lane & 15, kq = lane >> 4;
  f32x4 D0 = {0.f,0.f,0.f,0.f}, D1 = {0.f,0.f,0.f,0.f};
  const short* bp = fc1wbf + (size_t)(w*16 + cl)*384 + kq*8;
  #pragma unroll
  for (int ks=0; ks<12; ks++){
    s16x8 b = *(const s16x8*)(bp + ks*32);
    int kb = ks*64 + kq*16;
    s16x8 a0 = *(const s16x8*)(As + (((cl   )*768 + kb) ^ ((cl&7)<<4)));
    s16x8 a1 = *(const s16x8*)(As + (((cl+16)*768 + kb) ^ (((cl+16)&7)<<4)));
    D0 = __builtin_amdgcn_mfma_f32_16x16x32_bf16(a0, b, D0, 0, 0, 0);
    D1 = __builtin_amdgcn_mfma_f32_16x16x32_bf16(a1, b, D1, 0, 0, 0);
  }
  int col = w*16 + cl;
  float bb = fc1b[col];
  #pragma unroll
  for (int q=0;q<4;q++){
    hbuf[kq*4+q][col]    = D0[q] + bb;
    hbuf[16+kq*4+q][col] = D1[q] + bb;
  }
  __syncthreads();
  int sub = lane >> 4, l16 = lane & 15;
  int nd = w*4 + sub;
  float v[8];
  float s = 0.f;
  #pragma unroll
  for (int j=0;j<8;j++){ v[j] = hbuf[nd][l16*8+j]; s += v[j]; }
  #pragma unroll
  for (int m=1;m<16;m<<=1) s += __shfl_xor(s, m);
  float mu = s * (1.f/128.f);
  float va = 0.f;
  #pragma unroll
  for (int j=0;j<8;j++){ float dm = v[j]-mu; va += dm*dm; }
  #pragma unroll
  for (int m=1;m<16;m<<=1) va += __shfl_xor(va, m);
  float rstd = rsqrtf(va*(1.f/128.f) + 1e-5f);
  float o0=0.f, o1=0.f;
  #pragma unroll
  for (int j=0;j<8;j++){
    int c = l16*8+j;
    float h1 = (v[j]-mu)*rstd*lng[c] + lnb[c];
    h1 = fmaxf(h1, 0.f);
    o0 += h1*outw[c]; o1 += h1*outw[128+c];
  }
  #pragma unroll
  for (int m=1;m<16;m<<=1){ o0 += __shfl_xor(o0,m); o1 += __shfl_xor(o1,m); }
  if (l16==0){
    out[(size_t)(base+nd)*2]   = o0 + outb[0];
    out[(size_t)(base+nd)*2+1] = o1 + outb[1];
  }
}

extern "C" void kernel_launch(void* const* d_in, const int* in_sizes, int n_in,
                              void* d_out, int out_size, void* d_ws, size_t ws_size,
                              hipStream_t stream){
  const float* x      = (const float*)d_in[0];
  const int*   heads  = (const int*)d_in[1];
  const int*   rels   = (const int*)d_in[2];
  const int*   tails  = (const int*)d_in[3];
  const float* weeks  = (const float*)d_in[4];
  const int*   esrc   = (const int*)d_in[5];
  const int*   edst   = (const int*)d_in[6];
  const float* ent    = (const float*)d_in[10];
  const float* rel_e  = (const float*)d_in[11];
  const float* wfreq  = (const float*)d_in[12];
  const float* wphi   = (const float*)d_in[13];
  const float* wamp   = (const float*)d_in[14];
  const float* Wih    = (const float*)d_in[15];
  const float* Whh    = (const float*)d_in[16];
  const float* bih    = (const float*)d_in[17];
  const float* bhh    = (const float*)d_in[18];
  const float* fc1w   = (const float*)d_in[19];
  const float* fc1b   = (const float*)d_in[20];
  const float* lng    = (const float*)d_in[21];
  const float* lnb    = (const float*)d_in[22];
  const float* outw   = (const float*)d_in[23];
  const float* outb   = (const float*)d_in[24];
  float* out = (float*)d_out;

  char* ws = (char*)d_ws;
  size_t off = 0;
  auto alloc = [&](size_t bytes){ void* p = ws + off; off += (bytes + 255) & ~(size_t)255; return p; };
  float* pre2   = (float*)alloc((size_t)N_EDGES*512*4);
  short* WihB   = (short*)alloc(512*128*2);
  short* fc1wbf = (short*)alloc(128*384*2);
  float* emb    = (float*)alloc((size_t)N_NODES*128*4);
  int* sstart   = (int*)alloc((N_NODES+1)*4);
  int* dstart   = (int*)alloc((N_NODES+1)*4);
  int* zreg     = (int*)alloc((size_t)(4*N_NODES + 3)*4);
  int* scnt = zreg, *dcnt = zreg+N_NODES, *sc2 = zreg+2*N_NODES, *dc2 = zreg+3*N_NODES;
  int* nchains  = zreg + 4*N_NODES;
  int* ctr      = nchains + 2;
  int* bhist    = (int*)alloc((size_t)128*NBLK*4);
  int* boff     = (int*)alloc((size_t)128*NBLK*4);
  int* slist    = (int*)alloc(N_EDGES*4);
  int* dlist    = (int*)alloc(N_EDGES*4);
  int* cnode    = (int*)alloc((size_t)2*N_NODES*4);
  int* cstart   = (int*)alloc((size_t)2*N_NODES*4);
  int* clen     = (int*)alloc((size_t)2*N_NODES*4);

  hipMemsetAsync(zreg, 0, (size_t)(4*N_NODES + 3)*4, stream);
  hipMemsetAsync(emb, 0, (size_t)N_NODES*128*4, stream);

  hipFuncSetAttribute((const void*)k_lstm3, hipFuncAttributeMaxDynamicSharedMemorySize, LDSZ);

  k_prepwih<<<(512*128+255)/256, 256, 0, stream>>>(Wih, WihB);
  k_prepw<<<(128*384+255)/256, 256, 0, stream>>>(fc1w, fc1wbf, 128*384);

  k_edge2<<<N_EDGES/32, 256, 0, stream>>>(heads, rels, tails, weeks, ent, rel_e,
                                          wfreq, wphi, wamp, WihB, bih, bhh, pre2);
  k_hist<<<(N_EDGES+255)/256, 256, 0, stream>>>(esrc, edst, scnt, dcnt);
  k_scan<<<2, 1024, 0, stream>>>(scnt, dcnt, sstart, dstart);
  k_scatter<<<(N_EDGES+255)/256, 256, 0, stream>>>(esrc, edst, sstart, dstart, sc2, dc2, slist, dlist);
  k_sortlists<<<(N_NODES+255)/256, 256, 0, stream>>>(sstart, dstart, slist, dlist);
  k_cbin1<<<NBLK, 256, 0, stream>>>(sstart, dstart, bhist);
  k_cbin2<<<1, 1024, 0, stream>>>(bhist, boff, nchains);
  k_cbin3<<<NBLK, 256, 0, stream>>>(sstart, dstart, boff, nchains, cnode, cstart, clen);
  k_lstm3<<<256, 512, LDSZ, stream>>>(pre2, Whh, cnode, cstart, clen, nchains,
                                      slist, dlist, dcnt, ctr, emb);
  k_mlp2<<<N_NODES/32, 512, 0, stream>>>(x, emb, fc1wbf, fc1b, lng, lnb, outw, outb, out);
}

// Round 7
// 236.699 us; speedup vs baseline: 4.1553x; 1.1048x over previous
//
#include <hip/hip_runtime.h>
#include <math.h>

#define N_NODES 20000
#define N_EDGES 40000
#define SE 46
#define TE 82
#define NBLK 79   // ceil(N_NODES/256)
// D = 128, 4D = 512, F = 256, HID = 128

typedef short  s16x8 __attribute__((ext_vector_type(8)));
typedef short  s16x4 __attribute__((ext_vector_type(4)));
typedef float  f32x4 __attribute__((ext_vector_type(4)));

__device__ __forceinline__ float sigf(float x){ return 1.0f/(1.0f+__expf(-x)); }
__device__ __forceinline__ float tanh_f(float x){ return 1.0f - 2.0f/(__expf(2.0f*x)+1.0f); }
__device__ __forceinline__ int perm_out(int i){ return (i&3)*128 + (i>>2); }
__device__ __forceinline__ unsigned short f2bf(float f){
  unsigned u = __builtin_bit_cast(unsigned, f);
  unsigned r = (u + 0x7fff + ((u>>16)&1)) >> 16;
  return (unsigned short)r;
}
__device__ __forceinline__ float bf2f(short s){
  unsigned u = ((unsigned)(unsigned short)s) << 16;
  return __builtin_bit_cast(float, u);
}

// f32 -> bf16 convert
__global__ void k_prepw(const float* __restrict__ in, short* __restrict__ out, int n){
  int i = blockIdx.x*blockDim.x + threadIdx.x;
  if (i < n) out[i] = (short)f2bf(in[i]);
}

// Wih -> bf16, permuted rows: out[i*128+k] = bf16(Wih[perm_out(i)*128+k])
__global__ void k_prepwih(const float* __restrict__ in, short* __restrict__ out){
  int idx = blockIdx.x*blockDim.x + threadIdx.x;
  if (idx < 512*128){
    int i = idx >> 7, k = idx & 127;
    out[idx] = (short)f2bf(in[perm_out(i)*128 + k]);
  }
}

// ---------------- gather: scores[e][d] = h*r*t as bf16, 8 dims/thread ----------------
__global__ __launch_bounds__(256) void k_gather(
    const int* __restrict__ heads, const int* __restrict__ rels,
    const int* __restrict__ tails, const float* __restrict__ weeks,
    const float* __restrict__ ent, const float* __restrict__ rel_embs,
    const float* __restrict__ wfreq, const float* __restrict__ wphi,
    const float* __restrict__ wamp, short* __restrict__ scores){
  int c = blockIdx.x*256 + threadIdx.x;   // 640000 chunks
  int e = c >> 4, d0 = (c & 15) << 3;
  int hd = heads[e], tl = tails[e], rl = rels[e];
  float wk = weeks[e];
  float hv[8], tv[8];
  if (d0 + 8 <= SE){
    const float* hp = ent + (size_t)hd*SE + d0;
    const float* tp = ent + (size_t)tl*SE + d0;
    #pragma unroll
    for (int j=0;j<4;j++){
      float2 a = *(const float2*)(hp + j*2); hv[2*j]=a.x; hv[2*j+1]=a.y;
      float2 b = *(const float2*)(tp + j*2); tv[2*j]=b.x; tv[2*j+1]=b.y;
    }
  } else if (d0 >= 48){
    int dt = d0 - SE;
    const float *hf = wfreq + (size_t)hd*TE + dt, *hp2 = wphi + (size_t)hd*TE + dt, *ha = wamp + (size_t)hd*TE + dt;
    const float *tf = wfreq + (size_t)tl*TE + dt, *tp2 = wphi + (size_t)tl*TE + dt, *ta = wamp + (size_t)tl*TE + dt;
    #pragma unroll
    for (int j=0;j<4;j++){
      float2 f_h = *(const float2*)(hf + j*2);
      float2 p_h = *(const float2*)(hp2 + j*2);
      float2 a_h = *(const float2*)(ha + j*2);
      float2 f_t = *(const float2*)(tf + j*2);
      float2 p_t = *(const float2*)(tp2 + j*2);
      float2 a_t = *(const float2*)(ta + j*2);
      hv[2*j]   = a_h.x*__sinf(f_h.x*wk + p_h.x);
      hv[2*j+1] = a_h.y*__sinf(f_h.y*wk + p_h.y);
      tv[2*j]   = a_t.x*__sinf(f_t.x*wk + p_t.x);
      tv[2*j+1] = a_t.y*__sinf(f_t.y*wk + p_t.y);
    }
  } else {
    // d0 == 40: boundary chunk, scalar
    #pragma unroll
    for (int j=0;j<8;j++){
      int d = 40 + j;
      if (d < SE){
        hv[j] = ent[(size_t)hd*SE + d];
        tv[j] = ent[(size_t)tl*SE + d];
      } else {
        int dt = d - SE;
        hv[j] = wamp[(size_t)hd*TE+dt]*__sinf(wfreq[(size_t)hd*TE+dt]*wk + wphi[(size_t)hd*TE+dt]);
        tv[j] = wamp[(size_t)tl*TE+dt]*__sinf(wfreq[(size_t)tl*TE+dt]*wk + wphi[(size_t)tl*TE+dt]);
      }
    }
  }
  const float* rp = rel_embs + rl*128 + d0;
  float4 r0 = *(const float4*)rp, r1 = *(const float4*)(rp+4);
  float rv[8] = {r0.x,r0.y,r0.z,r0.w, r1.x,r1.y,r1.z,r1.w};
  s16x8 o;
  #pragma unroll
  for (int j=0;j<8;j++) o[j] = (short)f2bf(hv[j]*rv[j]*tv[j]);
  *(s16x8*)(scores + (size_t)e*128 + d0) = o;
}

// ---------------- MFMA GEMM: pre2b = bf16(perm(scores @ Wih^T + bih + bhh)) ----------------
__global__ __launch_bounds__(256) void k_pregemm(
    const short* __restrict__ scores, const short* __restrict__ WihB,
    const float* __restrict__ bih, const float* __restrict__ bhh,
    short* __restrict__ pre2b){
  __shared__ char As[32*256];   // bf16 [32 edges][128 k], XOR-swizzled rows
  int e0 = blockIdx.x * 32;
  int tid = threadIdx.x;
  #pragma unroll
  for (int q=0;q<2;q++){
    int c = tid + 256*q;            // 0..511
    int el = c >> 4, k8 = c & 15;
    s16x8 v = *(const s16x8*)(scores + (size_t)(e0+el)*128 + k8*8);
    *(s16x8*)(As + ((el*256 + k8*16) ^ ((el&7)<<4))) = v;
  }
  __syncthreads();
  int lane = tid & 63, w = tid >> 6;
  int cl = lane & 15, kq = lane >> 4;
  s16x8 a[2][4];
  #pragma unroll
  for (int ks=0;ks<4;ks++){
    int kb = ks*64 + kq*16;
    a[0][ks] = *(const s16x8*)(As + (((cl   )*256 + kb) ^ ((cl&7)<<4)));
    a[1][ks] = *(const s16x8*)(As + (((cl+16)*256 + kb) ^ (((cl+16)&7)<<4)));
  }
  f32x4 D[2][8];
  #pragma unroll
  for (int m=0;m<2;m++)
    #pragma unroll
    for (int i=0;i<8;i++) D[m][i] = (f32x4){0.f,0.f,0.f,0.f};
  #pragma unroll
  for (int i=0;i<8;i++){
    int n = w*128 + i*16 + cl;
    const short* bp = WihB + (size_t)n*128 + kq*8;
    #pragma unroll
    for (int ks=0;ks<4;ks++){
      s16x8 b = *(const s16x8*)(bp + ks*32);
      D[0][i] = __builtin_amdgcn_mfma_f32_16x16x32_bf16(a[0][ks], b, D[0][i], 0, 0, 0);
      D[1][i] = __builtin_amdgcn_mfma_f32_16x16x32_bf16(a[1][ks], b, D[1][i], 0, 0, 0);
    }
  }
  #pragma unroll
  for (int i=0;i<8;i++){
    int n = w*128 + i*16 + cl;
    int pn = perm_out(n);
    float bb = bih[pn] + bhh[pn];
    #pragma unroll
    for (int m=0;m<2;m++){
      #pragma unroll
      for (int q2=0;q2<4;q2++){
        int row = m*16 + kq*4 + q2;
        pre2b[(size_t)(e0+row)*512 + n] = (short)f2bf(D[m][i][q2] + bb);
      }
    }
  }
}

// ---------------- grouping machinery ----------------
__global__ void k_hist(const int* __restrict__ src, const int* __restrict__ dst,
                       int* __restrict__ scnt, int* __restrict__ dcnt){
  int e = blockIdx.x*blockDim.x + threadIdx.x;
  if (e < N_EDGES){ atomicAdd(&scnt[src[e]],1); atomicAdd(&dcnt[dst[e]],1); }
}

// fast scan: 1024 threads, 20 elems each, shuffle-based
__global__ void k_scan(const int* __restrict__ scnt, const int* __restrict__ dcnt,
                       int* __restrict__ sstart, int* __restrict__ dstart){
  const int* cnt = blockIdx.x ? dcnt : scnt;
  int* start = blockIdx.x ? dstart : sstart;
  const int CH = 20;
  int tid = threadIdx.x;
  int base = tid*CH;
  int v[CH]; int tsum = 0;
  #pragma unroll
  for (int j=0;j<CH;j++){ int i = base+j; v[j] = (i<N_NODES)? cnt[i] : 0; tsum += v[j]; }
  int lane = tid & 63, wv = tid >> 6;
  int incl = tsum;
  #pragma unroll
  for (int m=1;m<64;m<<=1){ int u = __shfl_up(incl, m); if (lane >= m) incl += u; }
  __shared__ int wsum[16], woff[16];
  if (lane==63) wsum[wv] = incl;
  __syncthreads();
  if (tid < 16){ int s=0; for (int k=0;k<tid;k++) s += wsum[k]; woff[tid]=s; }
  __syncthreads();
  int run = woff[wv] + incl - tsum;
  #pragma unroll
  for (int j=0;j<CH;j++){ int i = base+j; if (i<N_NODES) start[i] = run; run += v[j]; }
  if (tid == 1023) start[N_NODES] = run;
}

__global__ void k_scatter(const int* __restrict__ src, const int* __restrict__ dst,
                          const int* __restrict__ sstart, const int* __restrict__ dstart,
                          int* __restrict__ sc2, int* __restrict__ dc2,
                          int* __restrict__ slist, int* __restrict__ dlist){
  int e = blockIdx.x*blockDim.x + threadIdx.x;
  if (e < N_EDGES){
    int s = src[e]; int p  = sstart[s] + atomicAdd(&sc2[s],1); slist[p]=e;
    int d = dst[e]; int p2 = dstart[d] + atomicAdd(&dc2[d],1); dlist[p2]=e;
  }
}

__global__ void k_sortlists(const int* __restrict__ sstart, const int* __restrict__ dstart,
                            int* __restrict__ slist, int* __restrict__ dlist){
  int n = blockIdx.x*blockDim.x + threadIdx.x;
  if (n < N_NODES){
    #pragma unroll
    for (int pass=0; pass<2; pass++){
      const int* st = pass ? dstart : sstart;
      int* ls = pass ? dlist : slist;
      int a = st[n], b = st[n+1];
      for (int i=a+1;i<b;i++){
        int v = ls[i]; int j=i-1;
        while (j>=a && ls[j]>v){ ls[j+1]=ls[j]; j--; }
        ls[j+1]=v;
      }
    }
  }
}

// ---------------- chain compaction: block-local counting sort ----------------
__global__ void k_cbin1(const int* __restrict__ sstart, const int* __restrict__ dstart,
                        int* __restrict__ bhist){
  __shared__ int h[128];
  int tid = threadIdx.x, blk = blockIdx.x;
  if (tid < 128) h[tid] = 0;
  __syncthreads();
  int n = blk*256 + tid;
  if (n < N_NODES){
    int c = sstart[n+1]-sstart[n];
    if (c>0) atomicAdd(&h[min(c,63)], 1);
    int c2 = dstart[n+1]-dstart[n];
    if (c2>0) atomicAdd(&h[64+min(c2,63)], 1);
  }
  __syncthreads();
  if (tid < 128) bhist[tid*NBLK + blk] = h[tid];
}

__global__ void k_cbin2(const int* __restrict__ bhist, int* __restrict__ boff,
                        int* __restrict__ nchains){
  const int S = 2*63*NBLK;   // 9954
  const int CH = 10;
  int tid = threadIdx.x;
  int v[CH]; int tsum = 0;
  int binidx[CH];
  #pragma unroll
  for (int j=0;j<CH;j++){
    int s = tid*CH + j;
    int val = 0, bi = -1;
    if (s < S){
      int p = s / (63*NBLK);
      int r = s - p*63*NBLK;
      int li = r / NBLK;
      int b  = r - li*NBLK;
      int l  = 63 - li;
      bi = (p*64 + l)*NBLK + b;
      val = bhist[bi];
    }
    binidx[j] = bi; v[j] = val; tsum += val;
  }
  int lane = tid & 63, wv = tid >> 6;
  int incl = tsum;
  #pragma unroll
  for (int m=1;m<64;m<<=1){ int u = __shfl_up(incl, m); if (lane >= m) incl += u; }
  __shared__ int wsum[16], woff[16];
  __shared__ int pend[2];
  if (lane==63) wsum[wv] = incl;
  __syncthreads();
  if (tid < 16){ int s=0; for (int k=0;k<tid;k++) s += wsum[k]; woff[tid]=s; }
  __syncthreads();
  int run = woff[wv] + incl - tsum;
  #pragma unroll
  for (int j=0;j<CH;j++){
    int s = tid*CH + j;
    if (s < S){
      boff[binidx[j]] = run;
      run += v[j];
      if (s == 63*NBLK - 1) pend[0] = run;
      if (s == S - 1)       pend[1] = run;
    }
  }
  __syncthreads();
  if (tid == 0){
    nchains[0] = pend[0];
    nchains[1] = pend[1] - pend[0];
  }
}

__global__ void k_cbin3(const int* __restrict__ sstart, const int* __restrict__ dstart,
                        const int* __restrict__ boff, const int* __restrict__ nchains,
                        int* __restrict__ cnode, int* __restrict__ cstart,
                        int* __restrict__ clen){
  __shared__ int h[128];
  int tid = threadIdx.x, blk = blockIdx.x;
  if (tid < 128) h[tid] = 0;
  __syncthreads();
  int n = blk*256 + tid;
  int bin0=-1, bin1=-1, r0=0, r1=0, a0=0, c0=0, a1=0, c1=0;
  if (n < N_NODES){
    a0 = sstart[n]; c0 = sstart[n+1]-a0;
    if (c0>0){ bin0 = min(c0,63);      r0 = atomicAdd(&h[bin0], 1); }
    a1 = dstart[n]; c1 = dstart[n+1]-a1;
    if (c1>0){ bin1 = 64+min(c1,63);   r1 = atomicAdd(&h[bin1], 1); }
  }
  __syncthreads();
  int nch0 = nchains[0];
  if (bin0 >= 0){
    int pos = boff[bin0*NBLK + blk] + r0;
    cnode[pos] = n; cstart[pos] = a0; clen[pos] = c0;
  }
  if (bin1 >= 0){
    int pos = boff[bin1*NBLK + blk] + r1 - nch0;
    cnode[N_NODES+pos] = n; cstart[N_NODES+pos] = a1; clen[N_NODES+pos] = c1;
  }
}

// ---------------- persistent MFMA LSTM: Whh bf16 in LDS, 16 chains/batch ----------------
#define LDS_G 131072
#define LDS_H 147456
#define LDS_META 151552
#define LDSZ 151936

__global__ __launch_bounds__(512, 1) void k_lstm3(
    const short* __restrict__ pre2b, const float* __restrict__ Whh,
    const int* __restrict__ cnode, const int* __restrict__ cstart,
    const int* __restrict__ clen, const int* __restrict__ nchains,
    const int* __restrict__ slist, const int* __restrict__ dlist,
    const int* __restrict__ dcnt, int* __restrict__ ctr,
    float* __restrict__ emb){
  extern __shared__ char smem[];
  int tid = threadIdx.x;
  int lane = tid & 63, wv = tid >> 6;
  #pragma unroll 1
  for (int q=0;q<16;q++){
    int c = q*512 + tid;
    int n = c >> 4, k8 = c & 15;
    int orig = (n&3)*128 + (n>>2);
    const float* src = Whh + (size_t)orig*128 + k8*8;
    s16x8 v8;
    #pragma unroll
    for (int j=0;j<8;j++) v8[j] = (short)f2bf(src[j]);
    int byt = (n*256 + k8*16) ^ ((n&7)<<4);
    *(s16x8*)(smem + byt) = v8;
  }
  int nch0 = nchains[0], nch1 = nchains[1];
  int B0 = (nch0+15)>>4, B1 = (nch1+15)>>4;
  int* M = (int*)(smem + LDS_META);
  int d  = tid & 127, cg = tid >> 7;
  __syncthreads();
  while (true){
    if (tid==0) M[80] = atomicAdd(ctr, 1);
    __syncthreads();
    int nb = M[80];
    if (nb >= B0 + B1) break;
    int pass = (nb >= B0) ? 1 : 0;
    int batch = pass ? nb - B0 : nb;
    int b0 = batch << 4;
    int nch = pass ? nch1 : nch0;
    const int* list = pass ? dlist : slist;
    if (tid < 16){
      int j = b0 + tid;
      int valid = (j < nch);
      int ci = pass*N_NODES + j;
      int st = valid ? cstart[ci] : 0;
      int ln = valid ? clen[ci] : 0;
      M[tid] = ln; M[16+tid] = st; M[32+tid] = valid ? cnode[ci] : -1;
      M[48+tid] = (ln > 0) ? list[st] : 0;
    }
    *(unsigned long long*)(smem + LDS_H + tid*8) = 0ull;
    float cst[4]  = {0.f,0.f,0.f,0.f};
    float hreg[4] = {0.f,0.f,0.f,0.f};
    __syncthreads();
    int ml = 0;
    #pragma unroll 1
    for (int j=0;j<16;j++) ml = max(ml, M[j]);
    for (int t=0; t<ml; t++){
      f32x4 D[4];
      #pragma unroll
      for (int i=0;i<4;i++) D[i] = (f32x4){0.f,0.f,0.f,0.f};
      int row = lane & 15;
      int col = lane & 15;
      #pragma unroll
      for (int ks=0; ks<4; ks++){
        int kb = ks*64 + (lane>>4)*16;
        s16x8 a = *(const s16x8*)(smem + LDS_H + ((row*256 + kb) ^ ((row&7)<<4)));
        #pragma unroll
        for (int i=0;i<4;i++){
          int n = wv*64 + i*16 + col;
          s16x8 b = *(const s16x8*)(smem + ((n*256 + kb) ^ ((n&7)<<4)));
          D[i] = __builtin_amdgcn_mfma_f32_16x16x32_bf16(a, b, D[i], 0, 0, 0);
        }
      }
      int rb = (lane>>4)*4;
      #pragma unroll
      for (int i=0;i<4;i++){
        int n = wv*64 + i*16 + col;
        #pragma unroll
        for (int q=0;q<4;q++){
          int r = rb + q;
          *(short*)(smem + LDS_G + ((r*1024 + n*2) ^ ((r&7)<<4))) = (short)f2bf(D[i][q]);
        }
      }
      __syncthreads();
      const int* eid = M + 48 + ((t&1)<<4);
      #pragma unroll
      for (int jj=0;jj<4;jj++){
        int r = cg*4 + jj;
        if (t < M[r]){
          s16x4 pv = *(const s16x4*)(pre2b + (size_t)eid[r]*512 + d*4);
          s16x4 gs = *(const s16x4*)(smem + LDS_G + ((r*1024 + d*8) ^ ((r&7)<<4)));
          float g0 = bf2f(gs[0]) + bf2f(pv[0]);
          float g1 = bf2f(gs[1]) + bf2f(pv[1]);
          float g2 = bf2f(gs[2]) + bf2f(pv[2]);
          float g3 = bf2f(gs[3]) + bf2f(pv[3]);
          float iv = sigf(g0), fv = sigf(g1), gv = tanh_f(g2), ov = sigf(g3);
          cst[jj] = fv*cst[jj] + iv*gv;
          float h = ov * tanh_f(cst[jj]);
          hreg[jj] = h;
          *(short*)(smem + LDS_H + ((r*256 + d*2) ^ ((r&7)<<4))) = (short)f2bf(h);
        }
      }
      if (tid < 16){
        int ln = M[tid];
        M[48 + (((t+1)&1)<<4) + tid] = (t+1 < ln) ? list[M[16+tid] + t+1] : 0;
      }
      __syncthreads();
    }
    #pragma unroll
    for (int jj=0;jj<4;jj++){
      int r = cg*4 + jj;
      int n = M[32+r];
      if (M[r] > 0 && n >= 0 && !(pass==0 && dcnt[n] > 0)){
        emb[(size_t)n*128 + d] = hreg[jj];
      }
    }
    __syncthreads();
  }
}

// ---------------- MFMA MLP: 32 nodes/block, fc1 GEMM + LN + out ----------------
__global__ __launch_bounds__(512) void k_mlp2(
    const float* __restrict__ x, const float* __restrict__ emb,
    const short* __restrict__ fc1wbf, const float* __restrict__ fc1b,
    const float* __restrict__ lng, const float* __restrict__ lnb,
    const float* __restrict__ outw, const float* __restrict__ outb,
    float* __restrict__ out){
  __shared__ char As[32*768];          // bf16 [32][384], XOR-swizzled rows
  __shared__ float hbuf[32][132];
  int tid = threadIdx.x;
  int lane = tid & 63, w = tid >> 6;
  int base = blockIdx.x * 32;
  #pragma unroll
  for (int q=0;q<3;q++){
    int i = tid + 512*q;              // 0..1535, 48 chunks of 8 per row
    int r = i / 48, c = i - r*48;
    const float* src = (c < 32) ? (x + (size_t)(base+r)*256 + c*8)
                                : (emb + (size_t)(base+r)*128 + (c-32)*8);
    float4 v0 = *(const float4*)src;
    float4 v1 = *(const float4*)(src+4);
    s16x8 v8;
    v8[0]=(short)f2bf(v0.x); v8[1]=(short)f2bf(v0.y); v8[2]=(short)f2bf(v0.z); v8[3]=(short)f2bf(v0.w);
    v8[4]=(short)f2bf(v1.x); v8[5]=(short)f2bf(v1.y); v8[6]=(short)f2bf(v1.z); v8[7]=(short)f2bf(v1.w);
    *(s16x8*)(As + ((r*768 + c*16) ^ ((r&7)<<4))) = v8;
  }
  __syncthreads();
  int cl = lane & 15, kq = lane >> 4;
  f32x4 D0 = {0.f,0.f,0.f,0.f}, D1 = {0.f,0.f,0.f,0.f};
  const short* bp = fc1wbf + (size_t)(w*16 + cl)*384 + kq*8;
  #pragma unroll
  for (int ks=0; ks<12; ks++){
    s16x8 b = *(const s16x8*)(bp + ks*32);
    int kb = ks*64 + kq*16;
    s16x8 a0 = *(const s16x8*)(As + (((cl   )*768 + kb) ^ ((cl&7)<<4)));
    s16x8 a1 = *(const s16x8*)(As + (((cl+16)*768 + kb) ^ (((cl+16)&7)<<4)));
    D0 = __builtin_amdgcn_mfma_f32_16x16x32_bf16(a0, b, D0, 0, 0, 0);
    D1 = __builtin_amdgcn_mfma_f32_16x16x32_bf16(a1, b, D1, 0, 0, 0);
  }
  int col = w*16 + cl;
  float bb = fc1b[col];
  #pragma unroll
  for (int q=0;q<4;q++){
    hbuf[kq*4+q][col]    = D0[q] + bb;
    hbuf[16+kq*4+q][col] = D1[q] + bb;
  }
  __syncthreads();
  int sub = lane >> 4, l16 = lane & 15;
  int nd = w*4 + sub;
  float v[8];
  float s = 0.f;
  #pragma unroll
  for (int j=0;j<8;j++){ v[j] = hbuf[nd][l16*8+j]; s += v[j]; }
  #pragma unroll
  for (int m=1;m<16;m<<=1) s += __shfl_xor(s, m);
  float mu = s * (1.f/128.f);
  float va = 0.f;
  #pragma unroll
  for (int j=0;j<8;j++){ float dm = v[j]-mu; va += dm*dm; }
  #pragma unroll
  for (int m=1;m<16;m<<=1) va += __shfl_xor(va, m);
  float rstd = rsqrtf(va*(1.f/128.f) + 1e-5f);
  float o0=0.f, o1=0.f;
  #pragma unroll
  for (int j=0;j<8;j++){
    int c = l16*8+j;
    float h1 = (v[j]-mu)*rstd*lng[c] + lnb[c];
    h1 = fmaxf(h1, 0.f);
    o0 += h1*outw[c]; o1 += h1*outw[128+c];
  }
  #pragma unroll
  for (int m=1;m<16;m<<=1){ o0 += __shfl_xor(o0,m); o1 += __shfl_xor(o1,m); }
  if (l16==0){
    out[(size_t)(base+nd)*2]   = o0 + outb[0];
    out[(size_t)(base+nd)*2+1] = o1 + outb[1];
  }
}

extern "C" void kernel_launch(void* const* d_in, const int* in_sizes, int n_in,
                              void* d_out, int out_size, void* d_ws, size_t ws_size,
                              hipStream_t stream){
  const float* x      = (const float*)d_in[0];
  const int*   heads  = (const int*)d_in[1];
  const int*   rels   = (const int*)d_in[2];
  const int*   tails  = (const int*)d_in[3];
  const float* weeks  = (const float*)d_in[4];
  const int*   esrc   = (const int*)d_in[5];
  const int*   edst   = (const int*)d_in[6];
  const float* ent    = (const float*)d_in[10];
  const float* rel_e  = (const float*)d_in[11];
  const float* wfreq  = (const float*)d_in[12];
  const float* wphi   = (const float*)d_in[13];
  const float* wamp   = (const float*)d_in[14];
  const float* Wih    = (const float*)d_in[15];
  const float* Whh    = (const float*)d_in[16];
  const float* bih    = (const float*)d_in[17];
  const float* bhh    = (const float*)d_in[18];
  const float* fc1w   = (const float*)d_in[19];
  const float* fc1b   = (const float*)d_in[20];
  const float* lng    = (const float*)d_in[21];
  const float* lnb    = (const float*)d_in[22];
  const float* outw   = (const float*)d_in[23];
  const float* outb   = (const float*)d_in[24];
  float* out = (float*)d_out;

  char* ws = (char*)d_ws;
  size_t off = 0;
  auto alloc = [&](size_t bytes){ void* p = ws + off; off += (bytes + 255) & ~(size_t)255; return p; };
  short* pre2b  = (short*)alloc((size_t)N_EDGES*512*2);
  short* scores = (short*)alloc((size_t)N_EDGES*128*2);
  short* WihB   = (short*)alloc(512*128*2);
  short* fc1wbf = (short*)alloc(128*384*2);
  float* emb    = (float*)alloc((size_t)N_NODES*128*4);
  int* sstart   = (int*)alloc((N_NODES+1)*4);
  int* dstart   = (int*)alloc((N_NODES+1)*4);
  int* zreg     = (int*)alloc((size_t)(4*N_NODES + 3)*4);
  int* scnt = zreg, *dcnt = zreg+N_NODES, *sc2 = zreg+2*N_NODES, *dc2 = zreg+3*N_NODES;
  int* nchains  = zreg + 4*N_NODES;
  int* ctr      = nchains + 2;
  int* bhist    = (int*)alloc((size_t)128*NBLK*4);
  int* boff     = (int*)alloc((size_t)128*NBLK*4);
  int* slist    = (int*)alloc(N_EDGES*4);
  int* dlist    = (int*)alloc(N_EDGES*4);
  int* cnode    = (int*)alloc((size_t)2*N_NODES*4);
  int* cstart   = (int*)alloc((size_t)2*N_NODES*4);
  int* clen     = (int*)alloc((size_t)2*N_NODES*4);

  hipMemsetAsync(zreg, 0, (size_t)(4*N_NODES + 3)*4, stream);
  hipMemsetAsync(emb, 0, (size_t)N_NODES*128*4, stream);

  hipFuncSetAttribute((const void*)k_lstm3, hipFuncAttributeMaxDynamicSharedMemorySize, LDSZ);

  k_prepwih<<<(512*128+255)/256, 256, 0, stream>>>(Wih, WihB);
  k_prepw<<<(128*384+255)/256, 256, 0, stream>>>(fc1w, fc1wbf, 128*384);

  k_gather<<<N_EDGES*16/256, 256, 0, stream>>>(heads, rels, tails, weeks, ent, rel_e,
                                               wfreq, wphi, wamp, scores);
  k_pregemm<<<N_EDGES/32, 256, 0, stream>>>(scores, WihB, bih, bhh, pre2b);
  k_hist<<<(N_EDGES+255)/256, 256, 0, stream>>>(esrc, edst, scnt, dcnt);
  k_scan<<<2, 1024, 0, stream>>>(scnt, dcnt, sstart, dstart);
  k_scatter<<<(N_EDGES+255)/256, 256, 0, stream>>>(esrc, edst, sstart, dstart, sc2, dc2, slist, dlist);
  k_sortlists<<<(N_NODES+255)/256, 256, 0, stream>>>(sstart, dstart, slist, dlist);
  k_cbin1<<<NBLK, 256, 0, stream>>>(sstart, dstart, bhist);
  k_cbin2<<<1, 1024, 0, stream>>>(bhist, boff, nchains);
  k_cbin3<<<NBLK, 256, 0, stream>>>(sstart, dstart, boff, nchains, cnode, cstart, clen);
  k_lstm3<<<256, 512, LDSZ, stream>>>(pre2b, Whh, cnode, cstart, clen, nchains,
                                      slist, dlist, dcnt, ctr, emb);
  k_mlp2<<<N_NODES/32, 512, 0, stream>>>(x, emb, fc1wbf, fc1b, lng, lnb, outw, outb, out);
}

// Round 8
// 219.563 us; speedup vs baseline: 4.4797x; 1.0780x over previous
//
#include <hip/hip_runtime.h>
#include <math.h>

#define N_NODES 20000
#define N_EDGES 40000
#define SE 46
#define TE 82
#define NBLK 79   // ceil(N_NODES/256)
// D = 128, 4D = 512, F = 256, HID = 128

typedef short  s16x8 __attribute__((ext_vector_type(8)));
typedef short  s16x4 __attribute__((ext_vector_type(4)));
typedef float  f32x4 __attribute__((ext_vector_type(4)));

__device__ __forceinline__ float sigf(float x){ return 1.0f/(1.0f+__expf(-x)); }
__device__ __forceinline__ float tanh_f(float x){ return 1.0f - 2.0f/(__expf(2.0f*x)+1.0f); }
__device__ __forceinline__ int perm_out(int i){ return (i&3)*128 + (i>>2); }
__device__ __forceinline__ unsigned short f2bf(float f){
  unsigned u = __builtin_bit_cast(unsigned, f);
  unsigned r = (u + 0x7fff + ((u>>16)&1)) >> 16;
  return (unsigned short)r;
}
__device__ __forceinline__ float bf2f(short s){
  unsigned u = ((unsigned)(unsigned short)s) << 16;
  return __builtin_bit_cast(float, u);
}

// f32 -> bf16 convert
__global__ void k_prepw(const float* __restrict__ in, short* __restrict__ out, int n){
  int i = blockIdx.x*blockDim.x + threadIdx.x;
  if (i < n) out[i] = (short)f2bf(in[i]);
}

// Wih -> bf16, permuted rows: out[i*128+k] = bf16(Wih[perm_out(i)*128+k])
__global__ void k_prepwih(const float* __restrict__ in, short* __restrict__ out){
  int idx = blockIdx.x*blockDim.x + threadIdx.x;
  if (idx < 512*128){
    int i = idx >> 7, k = idx & 127;
    out[idx] = (short)f2bf(in[perm_out(i)*128 + k]);
  }
}

// ---------------- gather: scores[e][d] = h*r*t as bf16, 8 dims/thread ----------------
__global__ __launch_bounds__(256) void k_gather(
    const int* __restrict__ heads, const int* __restrict__ rels,
    const int* __restrict__ tails, const float* __restrict__ weeks,
    const float* __restrict__ ent, const float* __restrict__ rel_embs,
    const float* __restrict__ wfreq, const float* __restrict__ wphi,
    const float* __restrict__ wamp, short* __restrict__ scores){
  int c = blockIdx.x*256 + threadIdx.x;   // 640000 chunks
  int e = c >> 4, d0 = (c & 15) << 3;
  int hd = heads[e], tl = tails[e], rl = rels[e];
  float wk = weeks[e];
  float hv[8], tv[8];
  if (d0 + 8 <= SE){
    const float* hp = ent + (size_t)hd*SE + d0;
    const float* tp = ent + (size_t)tl*SE + d0;
    #pragma unroll
    for (int j=0;j<4;j++){
      float2 a = *(const float2*)(hp + j*2); hv[2*j]=a.x; hv[2*j+1]=a.y;
      float2 b = *(const float2*)(tp + j*2); tv[2*j]=b.x; tv[2*j+1]=b.y;
    }
  } else if (d0 >= 48){
    int dt = d0 - SE;
    const float *hf = wfreq + (size_t)hd*TE + dt, *hp2 = wphi + (size_t)hd*TE + dt, *ha = wamp + (size_t)hd*TE + dt;
    const float *tf = wfreq + (size_t)tl*TE + dt, *tp2 = wphi + (size_t)tl*TE + dt, *ta = wamp + (size_t)tl*TE + dt;
    #pragma unroll
    for (int j=0;j<4;j++){
      float2 f_h = *(const float2*)(hf + j*2);
      float2 p_h = *(const float2*)(hp2 + j*2);
      float2 a_h = *(const float2*)(ha + j*2);
      float2 f_t = *(const float2*)(tf + j*2);
      float2 p_t = *(const float2*)(tp2 + j*2);
      float2 a_t = *(const float2*)(ta + j*2);
      hv[2*j]   = a_h.x*__sinf(f_h.x*wk + p_h.x);
      hv[2*j+1] = a_h.y*__sinf(f_h.y*wk + p_h.y);
      tv[2*j]   = a_t.x*__sinf(f_t.x*wk + p_t.x);
      tv[2*j+1] = a_t.y*__sinf(f_t.y*wk + p_t.y);
    }
  } else {
    #pragma unroll
    for (int j=0;j<8;j++){
      int d = 40 + j;
      if (d < SE){
        hv[j] = ent[(size_t)hd*SE + d];
        tv[j] = ent[(size_t)tl*SE + d];
      } else {
        int dt = d - SE;
        hv[j] = wamp[(size_t)hd*TE+dt]*__sinf(wfreq[(size_t)hd*TE+dt]*wk + wphi[(size_t)hd*TE+dt]);
        tv[j] = wamp[(size_t)tl*TE+dt]*__sinf(wfreq[(size_t)tl*TE+dt]*wk + wphi[(size_t)tl*TE+dt]);
      }
    }
  }
  const float* rp = rel_embs + rl*128 + d0;
  float4 r0 = *(const float4*)rp, r1 = *(const float4*)(rp+4);
  float rv[8] = {r0.x,r0.y,r0.z,r0.w, r1.x,r1.y,r1.z,r1.w};
  s16x8 o;
  #pragma unroll
  for (int j=0;j<8;j++) o[j] = (short)f2bf(hv[j]*rv[j]*tv[j]);
  *(s16x8*)(scores + (size_t)e*128 + d0) = o;
}

// ---------------- MFMA GEMM: pre2b = bf16(perm(scores @ Wih^T + bih + bhh)) ----------------
__global__ __launch_bounds__(256) void k_pregemm(
    const short* __restrict__ scores, const short* __restrict__ WihB,
    const float* __restrict__ bih, const float* __restrict__ bhh,
    short* __restrict__ pre2b){
  __shared__ char As[32*256];   // bf16 [32 edges][128 k], XOR-swizzled rows
  int e0 = blockIdx.x * 32;
  int tid = threadIdx.x;
  #pragma unroll
  for (int q=0;q<2;q++){
    int c = tid + 256*q;            // 0..511
    int el = c >> 4, k8 = c & 15;
    s16x8 v = *(const s16x8*)(scores + (size_t)(e0+el)*128 + k8*8);
    *(s16x8*)(As + ((el*256 + k8*16) ^ ((el&7)<<4))) = v;
  }
  __syncthreads();
  int lane = tid & 63, w = tid >> 6;
  int cl = lane & 15, kq = lane >> 4;
  s16x8 a[2][4];
  #pragma unroll
  for (int ks=0;ks<4;ks++){
    int kb = ks*64 + kq*16;
    a[0][ks] = *(const s16x8*)(As + (((cl   )*256 + kb) ^ ((cl&7)<<4)));
    a[1][ks] = *(const s16x8*)(As + (((cl+16)*256 + kb) ^ (((cl+16)&7)<<4)));
  }
  f32x4 D[2][8];
  #pragma unroll
  for (int m=0;m<2;m++)
    #pragma unroll
    for (int i=0;i<8;i++) D[m][i] = (f32x4){0.f,0.f,0.f,0.f};
  #pragma unroll
  for (int i=0;i<8;i++){
    int n = w*128 + i*16 + cl;
    const short* bp = WihB + (size_t)n*128 + kq*8;
    #pragma unroll
    for (int ks=0;ks<4;ks++){
      s16x8 b = *(const s16x8*)(bp + ks*32);
      D[0][i] = __builtin_amdgcn_mfma_f32_16x16x32_bf16(a[0][ks], b, D[0][i], 0, 0, 0);
      D[1][i] = __builtin_amdgcn_mfma_f32_16x16x32_bf16(a[1][ks], b, D[1][i], 0, 0, 0);
    }
  }
  #pragma unroll
  for (int i=0;i<8;i++){
    int n = w*128 + i*16 + cl;
    int pn = perm_out(n);
    float bb = bih[pn] + bhh[pn];
    #pragma unroll
    for (int m=0;m<2;m++){
      #pragma unroll
      for (int q2=0;q2<4;q2++){
        int row = m*16 + kq*4 + q2;
        pre2b[(size_t)(e0+row)*512 + n] = (short)f2bf(D[m][i][q2] + bb);
      }
    }
  }
}

// ---------------- grouping machinery ----------------
__global__ void k_hist(const int* __restrict__ src, const int* __restrict__ dst,
                       int* __restrict__ scnt, int* __restrict__ dcnt){
  int e = blockIdx.x*blockDim.x + threadIdx.x;
  if (e < N_EDGES){ atomicAdd(&scnt[src[e]],1); atomicAdd(&dcnt[dst[e]],1); }
}

__global__ void k_scan(const int* __restrict__ scnt, const int* __restrict__ dcnt,
                       int* __restrict__ sstart, int* __restrict__ dstart){
  const int* cnt = blockIdx.x ? dcnt : scnt;
  int* start = blockIdx.x ? dstart : sstart;
  const int CH = 20;
  int tid = threadIdx.x;
  int base = tid*CH;
  int v[CH]; int tsum = 0;
  #pragma unroll
  for (int j=0;j<CH;j++){ int i = base+j; v[j] = (i<N_NODES)? cnt[i] : 0; tsum += v[j]; }
  int lane = tid & 63, wv = tid >> 6;
  int incl = tsum;
  #pragma unroll
  for (int m=1;m<64;m<<=1){ int u = __shfl_up(incl, m); if (lane >= m) incl += u; }
  __shared__ int wsum[16], woff[16];
  if (lane==63) wsum[wv] = incl;
  __syncthreads();
  if (tid < 16){ int s=0; for (int k=0;k<tid;k++) s += wsum[k]; woff[tid]=s; }
  __syncthreads();
  int run = woff[wv] + incl - tsum;
  #pragma unroll
  for (int j=0;j<CH;j++){ int i = base+j; if (i<N_NODES) start[i] = run; run += v[j]; }
  if (tid == 1023) start[N_NODES] = run;
}

__global__ void k_scatter(const int* __restrict__ src, const int* __restrict__ dst,
                          const int* __restrict__ sstart, const int* __restrict__ dstart,
                          int* __restrict__ sc2, int* __restrict__ dc2,
                          int* __restrict__ slist, int* __restrict__ dlist){
  int e = blockIdx.x*blockDim.x + threadIdx.x;
  if (e < N_EDGES){
    int s = src[e]; int p  = sstart[s] + atomicAdd(&sc2[s],1); slist[p]=e;
    int d = dst[e]; int p2 = dstart[d] + atomicAdd(&dc2[d],1); dlist[p2]=e;
  }
}

__global__ void k_sortlists(const int* __restrict__ sstart, const int* __restrict__ dstart,
                            int* __restrict__ slist, int* __restrict__ dlist){
  int n = blockIdx.x*blockDim.x + threadIdx.x;
  if (n < N_NODES){
    #pragma unroll
    for (int pass=0; pass<2; pass++){
      const int* st = pass ? dstart : sstart;
      int* ls = pass ? dlist : slist;
      int a = st[n], b = st[n+1];
      for (int i=a+1;i<b;i++){
        int v = ls[i]; int j=i-1;
        while (j>=a && ls[j]>v){ ls[j+1]=ls[j]; j--; }
        ls[j+1]=v;
      }
    }
  }
}

// ---------------- chain compaction: block-local counting sort ----------------
__global__ void k_cbin1(const int* __restrict__ sstart, const int* __restrict__ dstart,
                        int* __restrict__ bhist){
  __shared__ int h[128];
  int tid = threadIdx.x, blk = blockIdx.x;
  if (tid < 128) h[tid] = 0;
  __syncthreads();
  int n = blk*256 + tid;
  if (n < N_NODES){
    int c = sstart[n+1]-sstart[n];
    if (c>0) atomicAdd(&h[min(c,63)], 1);
    int c2 = dstart[n+1]-dstart[n];
    if (c2>0) atomicAdd(&h[64+min(c2,63)], 1);
  }
  __syncthreads();
  if (tid < 128) bhist[tid*NBLK + blk] = h[tid];
}

__global__ void k_cbin2(const int* __restrict__ bhist, int* __restrict__ boff,
                        int* __restrict__ nchains){
  const int S = 2*63*NBLK;   // 9954
  const int CH = 10;
  int tid = threadIdx.x;
  int v[CH]; int tsum = 0;
  int binidx[CH];
  #pragma unroll
  for (int j=0;j<CH;j++){
    int s = tid*CH + j;
    int val = 0, bi = -1;
    if (s < S){
      int p = s / (63*NBLK);
      int r = s - p*63*NBLK;
      int li = r / NBLK;
      int b  = r - li*NBLK;
      int l  = 63 - li;
      bi = (p*64 + l)*NBLK + b;
      val = bhist[bi];
    }
    binidx[j] = bi; v[j] = val; tsum += val;
  }
  int lane = tid & 63, wv = tid >> 6;
  int incl = tsum;
  #pragma unroll
  for (int m=1;m<64;m<<=1){ int u = __shfl_up(incl, m); if (lane >= m) incl += u; }
  __shared__ int wsum[16], woff[16];
  __shared__ int pend[2];
  if (lane==63) wsum[wv] = incl;
  __syncthreads();
  if (tid < 16){ int s=0; for (int k=0;k<tid;k++) s += wsum[k]; woff[tid]=s; }
  __syncthreads();
  int run = woff[wv] + incl - tsum;
  #pragma unroll
  for (int j=0;j<CH;j++){
    int s = tid*CH + j;
    if (s < S){
      boff[binidx[j]] = run;
      run += v[j];
      if (s == 63*NBLK - 1) pend[0] = run;
      if (s == S - 1)       pend[1] = run;
    }
  }
  __syncthreads();
  if (tid == 0){
    nchains[0] = pend[0];
    nchains[1] = pend[1] - pend[0];
  }
}

__global__ void k_cbin3(const int* __restrict__ sstart, const int* __restrict__ dstart,
                        const int* __restrict__ boff, const int* __restrict__ nchains,
                        int* __restrict__ cnode, int* __restrict__ cstart,
                        int* __restrict__ clen){
  __shared__ int h[128];
  int tid = threadIdx.x, blk = blockIdx.x;
  if (tid < 128) h[tid] = 0;
  __syncthreads();
  int n = blk*256 + tid;
  int bin0=-1, bin1=-1, r0=0, r1=0, a0=0, c0=0, a1=0, c1=0;
  if (n < N_NODES){
    a0 = sstart[n]; c0 = sstart[n+1]-a0;
    if (c0>0){ bin0 = min(c0,63);      r0 = atomicAdd(&h[bin0], 1); }
    a1 = dstart[n]; c1 = dstart[n+1]-a1;
    if (c1>0){ bin1 = 64+min(c1,63);   r1 = atomicAdd(&h[bin1], 1); }
  }
  __syncthreads();
  int nch0 = nchains[0];
  if (bin0 >= 0){
    int pos = boff[bin0*NBLK + blk] + r0;
    cnode[pos] = n; cstart[pos] = a0; clen[pos] = c0;
  }
  if (bin1 >= 0){
    int pos = boff[bin1*NBLK + blk] + r1 - nch0;
    cnode[N_NODES+pos] = n; cstart[N_NODES+pos] = a1; clen[N_NODES+pos] = c1;
  }
}

// ---------------- persistent MFMA LSTM v4: gate-direct mapping, 32 chains/batch ----------------
// LDS: W (512 rows x 256B bf16, swz) | H x2 (32 x 256B bf16, swz) | meta
// Wave wv owns Whh rows n = i*128 + wv*16 + cl  =>  D[m][i][q] = gate i, dim d_own=wv*16+cl,
// chain m*16+kq*4+q  -- gate combine entirely in registers, no G buffer.
#define LDS_H4 131072
#define LDS_META4 147456
#define LDSZ4 148480

__global__ __launch_bounds__(512, 1) void k_lstm4(
    const short* __restrict__ pre2b, const float* __restrict__ Whh,
    const int* __restrict__ cnode, const int* __restrict__ cstart,
    const int* __restrict__ clen, const int* __restrict__ nchains,
    const int* __restrict__ slist, const int* __restrict__ dlist,
    const int* __restrict__ dcnt, int* __restrict__ ctr,
    float* __restrict__ emb){
  extern __shared__ char smem[];
  int tid = threadIdx.x;
  int lane = tid & 63, wv = tid >> 6;
  int cl = lane & 15, kq = lane >> 4;
  int d_own = wv*16 + cl;
  // load Whh (ORIGINAL row order) -> LDS bf16 swizzled
  #pragma unroll 1
  for (int q=0;q<16;q++){
    int c = q*512 + tid;
    int n = c >> 4, k8 = c & 15;
    const float* src = Whh + (size_t)n*128 + k8*8;
    s16x8 v8;
    #pragma unroll
    for (int j=0;j<8;j++) v8[j] = (short)f2bf(src[j]);
    int byt = (n*256 + k8*16) ^ ((n&7)<<4);
    *(s16x8*)(smem + byt) = v8;
  }
  int nch0 = nchains[0], nch1 = nchains[1];
  int B0 = (nch0+31)>>5, B1 = (nch1+31)>>5;
  // M: [0..31] len | [32..63] start | [64..127] eid[2][32] | [128..159] node | [160] nb
  int* M = (int*)(smem + LDS_META4);
  __syncthreads();
  while (true){
    if (tid==0) M[160] = atomicAdd(ctr, 1);
    __syncthreads();
    int nb = M[160];
    if (nb >= B0 + B1) break;
    int pass = (nb >= B0) ? 1 : 0;
    int batch = pass ? nb - B0 : nb;
    int b0 = batch << 5;
    int nch = pass ? nch1 : nch0;
    const int* list = pass ? dlist : slist;
    if (tid < 32){
      int j = b0 + tid;
      int valid = (j < nch);
      int ci = pass*N_NODES + j;
      int st = valid ? cstart[ci] : 0;
      int ln = valid ? clen[ci] : 0;
      M[tid] = ln; M[32+tid] = st; M[128+tid] = valid ? cnode[ci] : -1;
      M[64+tid] = (ln > 0) ? list[st] : 0;
    }
    // zero H buffer 0 (8KB)
    {
      unsigned long long* hz = (unsigned long long*)(smem + LDS_H4 + tid*16);
      hz[0] = 0ull; hz[1] = 0ull;
    }
    float cst[8]  = {0.f,0.f,0.f,0.f,0.f,0.f,0.f,0.f};
    float hreg[8] = {0.f,0.f,0.f,0.f,0.f,0.f,0.f,0.f};
    __syncthreads();
    int ml = 0;
    #pragma unroll 1
    for (int j=0;j<32;j++) ml = max(ml, M[j]);
    int cur = 0;
    for (int t=0; t<ml; t++){
      // issue pv loads for step t (eids prefetched into slot t&1)
      const int* eid = M + 64 + ((t&1)<<5);
      s16x4 pv[8];
      #pragma unroll
      for (int m=0;m<2;m++)
        #pragma unroll
        for (int q=0;q<4;q++){
          int r = m*16 + kq*4 + q;
          pv[m*4+q] = *(const s16x4*)(pre2b + (size_t)eid[r]*512 + d_own*4);
        }
      // MFMA: gates_raw[chains][n=i*128+d_own] from H[cur]
      f32x4 D[2][4];
      #pragma unroll
      for (int m=0;m<2;m++)
        #pragma unroll
        for (int i=0;i<4;i++) D[m][i] = (f32x4){0.f,0.f,0.f,0.f};
      char* Hc = smem + LDS_H4 + cur*8192;
      #pragma unroll
      for (int ks=0; ks<4; ks++){
        int kb = ks*64 + kq*16;
        s16x8 a0 = *(const s16x8*)(Hc + (((cl   )*256 + kb) ^ ((cl&7)<<4)));
        s16x8 a1 = *(const s16x8*)(Hc + (((cl+16)*256 + kb) ^ (((cl+16)&7)<<4)));
        #pragma unroll
        for (int i=0;i<4;i++){
          int n = i*128 + d_own;
          s16x8 b = *(const s16x8*)(smem + ((n*256 + kb) ^ ((n&7)<<4)));
          D[0][i] = __builtin_amdgcn_mfma_f32_16x16x32_bf16(a0, b, D[0][i], 0, 0, 0);
          D[1][i] = __builtin_amdgcn_mfma_f32_16x16x32_bf16(a1, b, D[1][i], 0, 0, 0);
        }
      }
      // gate combine in registers; write h to H[cur^1]
      char* Hn = smem + LDS_H4 + (cur^1)*8192;
      #pragma unroll
      for (int m=0;m<2;m++)
        #pragma unroll
        for (int q=0;q<4;q++){
          int r = m*16 + kq*4 + q;
          if (t < M[r]){
            s16x4 p = pv[m*4+q];
            float gi = D[m][0][q] + bf2f(p[0]);
            float gf = D[m][1][q] + bf2f(p[1]);
            float gg = D[m][2][q] + bf2f(p[2]);
            float go = D[m][3][q] + bf2f(p[3]);
            int idx = m*4+q;
            cst[idx] = sigf(gf)*cst[idx] + sigf(gi)*tanh_f(gg);
            float h = sigf(go)*tanh_f(cst[idx]);
            hreg[idx] = h;
            *(short*)(Hn + ((r*256 + d_own*2) ^ ((r&7)<<4))) = (short)f2bf(h);
          }
        }
      // prefetch eids for t+1
      if (tid < 32){
        int ln = M[tid];
        M[64 + (((t+1)&1)<<5) + tid] = (t+1 < ln) ? list[M[32+tid] + t+1] : 0;
      }
      __syncthreads();
      cur ^= 1;
    }
    // emb writes
    #pragma unroll
    for (int m=0;m<2;m++)
      #pragma unroll
      for (int q=0;q<4;q++){
        int r = m*16 + kq*4 + q;
        int n = M[128+r];
        if (M[r] > 0 && n >= 0 && !(pass==0 && dcnt[n] > 0)){
          emb[(size_t)n*128 + d_own] = hreg[m*4+q];
        }
      }
    __syncthreads();
  }
}

// ---------------- MFMA MLP: 32 nodes/block, fc1 GEMM + LN + out ----------------
__global__ __launch_bounds__(512) void k_mlp2(
    const float* __restrict__ x, const float* __restrict__ emb,
    const short* __restrict__ fc1wbf, const float* __restrict__ fc1b,
    const float* __restrict__ lng, const float* __restrict__ lnb,
    const float* __restrict__ outw, const float* __restrict__ outb,
    float* __restrict__ out){
  __shared__ char As[32*768];          // bf16 [32][384], XOR-swizzled rows
  __shared__ float hbuf[32][132];
  int tid = threadIdx.x;
  int lane = tid & 63, w = tid >> 6;
  int base = blockIdx.x * 32;
  #pragma unroll
  for (int q=0;q<3;q++){
    int i = tid + 512*q;              // 0..1535, 48 chunks of 8 per row
    int r = i / 48, c = i - r*48;
    const float* src = (c < 32) ? (x + (size_t)(base+r)*256 + c*8)
                                : (emb + (size_t)(base+r)*128 + (c-32)*8);
    float4 v0 = *(const float4*)src;
    float4 v1 = *(const float4*)(src+4);
    s16x8 v8;
    v8[0]=(short)f2bf(v0.x); v8[1]=(short)f2bf(v0.y); v8[2]=(short)f2bf(v0.z); v8[3]=(short)f2bf(v0.w);
    v8[4]=(short)f2bf(v1.x); v8[5]=(short)f2bf(v1.y); v8[6]=(short)f2bf(v1.z); v8[7]=(short)f2bf(v1.w);
    *(s16x8*)(As + ((r*768 + c*16) ^ ((r&7)<<4))) = v8;
  }
  __syncthreads();
  int cl = lane & 15, kq = lane >> 4;
  f32x4 D0 = {0.f,0.f,0.f,0.f}, D1 = {0.f,0.f,0.f,0.f};
  const short* bp = fc1wbf + (size_t)(w*16 + cl)*384 + kq*8;
  #pragma unroll
  for (int ks=0; ks<12; ks++){
    s16x8 b = *(const s16x8*)(bp + ks*32);
    int kb = ks*64 + kq*16;
    s16x8 a0 = *(const s16x8*)(As + (((cl   )*768 + kb) ^ ((cl&7)<<4)));
    s16x8 a1 = *(const s16x8*)(As + (((cl+16)*768 + kb) ^ (((cl+16)&7)<<4)));
    D0 = __builtin_amdgcn_mfma_f32_16x16x32_bf16(a0, b, D0, 0, 0, 0);
    D1 = __builtin_amdgcn_mfma_f32_16x16x32_bf16(a1, b, D1, 0, 0, 0);
  }
  int col = w*16 + cl;
  float bb = fc1b[col];
  #pragma unroll
  for (int q=0;q<4;q++){
    hbuf[kq*4+q][col]    = D0[q] + bb;
    hbuf[16+kq*4+q][col] = D1[q] + bb;
  }
  __syncthreads();
  int sub = lane >> 4, l16 = lane & 15;
  int nd = w*4 + sub;
  float v[8];
  float s = 0.f;
  #pragma unroll
  for (int j=0;j<8;j++){ v[j] = hbuf[nd][l16*8+j]; s += v[j]; }
  #pragma unroll
  for (int m=1;m<16;m<<=1) s += __shfl_xor(s, m);
  float mu = s * (1.f/128.f);
  float va = 0.f;
  #pragma unroll
  for (int j=0;j<8;j++){ float dm = v[j]-mu; va += dm*dm; }
  #pragma unroll
  for (int m=1;m<16;m<<=1) va += __shfl_xor(va, m);
  float rstd = rsqrtf(va*(1.f/128.f) + 1e-5f);
  float o0=0.f, o1=0.f;
  #pragma unroll
  for (int j=0;j<8;j++){
    int c = l16*8+j;
    float h1 = (v[j]-mu)*rstd*lng[c] + lnb[c];
    h1 = fmaxf(h1, 0.f);
    o0 += h1*outw[c]; o1 += h1*outw[128+c];
  }
  #pragma unroll
  for (int m=1;m<16;m<<=1){ o0 += __shfl_xor(o0,m); o1 += __shfl_xor(o1,m); }
  if (l16==0){
    out[(size_t)(base+nd)*2]   = o0 + outb[0];
    out[(size_t)(base+nd)*2+1] = o1 + outb[1];
  }
}

extern "C" void kernel_launch(void* const* d_in, const int* in_sizes, int n_in,
                              void* d_out, int out_size, void* d_ws, size_t ws_size,
                              hipStream_t stream){
  const float* x      = (const float*)d_in[0];
  const int*   heads  = (const int*)d_in[1];
  const int*   rels   = (const int*)d_in[2];
  const int*   tails  = (const int*)d_in[3];
  const float* weeks  = (const float*)d_in[4];
  const int*   esrc   = (const int*)d_in[5];
  const int*   edst   = (const int*)d_in[6];
  const float* ent    = (const float*)d_in[10];
  const float* rel_e  = (const float*)d_in[11];
  const float* wfreq  = (const float*)d_in[12];
  const float* wphi   = (const float*)d_in[13];
  const float* wamp   = (const float*)d_in[14];
  const float* Wih    = (const float*)d_in[15];
  const float* Whh    = (const float*)d_in[16];
  const float* bih    = (const float*)d_in[17];
  const float* bhh    = (const float*)d_in[18];
  const float* fc1w   = (const float*)d_in[19];
  const float* fc1b   = (const float*)d_in[20];
  const float* lng    = (const float*)d_in[21];
  const float* lnb    = (const float*)d_in[22];
  const float* outw   = (const float*)d_in[23];
  const float* outb   = (const float*)d_in[24];
  float* out = (float*)d_out;

  char* ws = (char*)d_ws;
  size_t off = 0;
  auto alloc = [&](size_t bytes){ void* p = ws + off; off += (bytes + 255) & ~(size_t)255; return p; };
  short* pre2b  = (short*)alloc((size_t)N_EDGES*512*2);
  short* scores = (short*)alloc((size_t)N_EDGES*128*2);
  short* WihB   = (short*)alloc(512*128*2);
  short* fc1wbf = (short*)alloc(128*384*2);
  float* emb    = (float*)alloc((size_t)N_NODES*128*4);
  int* sstart   = (int*)alloc((N_NODES+1)*4);
  int* dstart   = (int*)alloc((N_NODES+1)*4);
  int* zreg     = (int*)alloc((size_t)(4*N_NODES + 3)*4);
  int* scnt = zreg, *dcnt = zreg+N_NODES, *sc2 = zreg+2*N_NODES, *dc2 = zreg+3*N_NODES;
  int* nchains  = zreg + 4*N_NODES;
  int* ctr      = nchains + 2;
  int* bhist    = (int*)alloc((size_t)128*NBLK*4);
  int* boff     = (int*)alloc((size_t)128*NBLK*4);
  int* slist    = (int*)alloc(N_EDGES*4);
  int* dlist    = (int*)alloc(N_EDGES*4);
  int* cnode    = (int*)alloc((size_t)2*N_NODES*4);
  int* cstart   = (int*)alloc((size_t)2*N_NODES*4);
  int* clen     = (int*)alloc((size_t)2*N_NODES*4);

  hipMemsetAsync(zreg, 0, (size_t)(4*N_NODES + 3)*4, stream);
  hipMemsetAsync(emb, 0, (size_t)N_NODES*128*4, stream);

  hipFuncSetAttribute((const void*)k_lstm4, hipFuncAttributeMaxDynamicSharedMemorySize, LDSZ4);

  k_prepwih<<<(512*128+255)/256, 256, 0, stream>>>(Wih, WihB);
  k_prepw<<<(128*384+255)/256, 256, 0, stream>>>(fc1w, fc1wbf, 128*384);

  k_gather<<<N_EDGES*16/256, 256, 0, stream>>>(heads, rels, tails, weeks, ent, rel_e,
                                               wfreq, wphi, wamp, scores);
  k_pregemm<<<N_EDGES/32, 256, 0, stream>>>(scores, WihB, bih, bhh, pre2b);
  k_hist<<<(N_EDGES+255)/256, 256, 0, stream>>>(esrc, edst, scnt, dcnt);
  k_scan<<<2, 1024, 0, stream>>>(scnt, dcnt, sstart, dstart);
  k_scatter<<<(N_EDGES+255)/256, 256, 0, stream>>>(esrc, edst, sstart, dstart, sc2, dc2, slist, dlist);
  k_sortlists<<<(N_NODES+255)/256, 256, 0, stream>>>(sstart, dstart, slist, dlist);
  k_cbin1<<<NBLK, 256, 0, stream>>>(sstart, dstart, bhist);
  k_cbin2<<<1, 1024, 0, stream>>>(bhist, boff, nchains);
  k_cbin3<<<NBLK, 256, 0, stream>>>(sstart, dstart, boff, nchains, cnode, cstart, clen);
  k_lstm4<<<256, 512, LDSZ4, stream>>>(pre2b, Whh, cnode, cstart, clen, nchains,
                                       slist, dlist, dcnt, ctr, emb);
  k_mlp2<<<N_NODES/32, 512, 0, stream>>>(x, emb, fc1wbf, fc1b, lng, lnb, outw, outb, out);
}

// Round 9
// 188.565 us; speedup vs baseline: 5.2161x; 1.1644x over previous
//
#include <hip/hip_runtime.h>
#include <math.h>

#define N_NODES 20000
#define N_EDGES 40000
#define SE 46
#define TE 82
#define NBLK 79   // ceil(N_NODES/256)
// D = 128, 4D = 512, F = 256, HID = 128

typedef short  s16x8 __attribute__((ext_vector_type(8)));
typedef short  s16x4 __attribute__((ext_vector_type(4)));
typedef float  f32x4 __attribute__((ext_vector_type(4)));

__device__ __forceinline__ float sigf(float x){ return 1.0f/(1.0f+__expf(-x)); }
__device__ __forceinline__ float tanh_f(float x){ return 1.0f - 2.0f/(__expf(2.0f*x)+1.0f); }
__device__ __forceinline__ int perm_out(int i){ return (i&3)*128 + (i>>2); }
__device__ __forceinline__ unsigned short f2bf(float f){
  unsigned u = __builtin_bit_cast(unsigned, f);
  unsigned r = (u + 0x7fff + ((u>>16)&1)) >> 16;
  return (unsigned short)r;
}
__device__ __forceinline__ float bf2f(short s){
  unsigned u = ((unsigned)(unsigned short)s) << 16;
  return __builtin_bit_cast(float, u);
}

// f32 -> bf16 convert
__global__ void k_prepw(const float* __restrict__ in, short* __restrict__ out, int n){
  int i = blockIdx.x*blockDim.x + threadIdx.x;
  if (i < n) out[i] = (short)f2bf(in[i]);
}

// Wih -> bf16, permuted rows: out[i*128+k] = bf16(Wih[perm_out(i)*128+k])
__global__ void k_prepwih(const float* __restrict__ in, short* __restrict__ out){
  int idx = blockIdx.x*blockDim.x + threadIdx.x;
  if (idx < 512*128){
    int i = idx >> 7, k = idx & 127;
    out[idx] = (short)f2bf(in[perm_out(i)*128 + k]);
  }
}

// ---------------- gather: scores[e][d] = h*r*t as bf16, 8 dims/thread ----------------
__global__ __launch_bounds__(256) void k_gather(
    const int* __restrict__ heads, const int* __restrict__ rels,
    const int* __restrict__ tails, const float* __restrict__ weeks,
    const float* __restrict__ ent, const float* __restrict__ rel_embs,
    const float* __restrict__ wfreq, const float* __restrict__ wphi,
    const float* __restrict__ wamp, short* __restrict__ scores){
  int c = blockIdx.x*256 + threadIdx.x;   // 640000 chunks
  int e = c >> 4, d0 = (c & 15) << 3;
  int hd = heads[e], tl = tails[e], rl = rels[e];
  float wk = weeks[e];
  float hv[8], tv[8];
  if (d0 + 8 <= SE){
    const float* hp = ent + (size_t)hd*SE + d0;
    const float* tp = ent + (size_t)tl*SE + d0;
    #pragma unroll
    for (int j=0;j<4;j++){
      float2 a = *(const float2*)(hp + j*2); hv[2*j]=a.x; hv[2*j+1]=a.y;
      float2 b = *(const float2*)(tp + j*2); tv[2*j]=b.x; tv[2*j+1]=b.y;
    }
  } else if (d0 >= 48){
    int dt = d0 - SE;
    const float *hf = wfreq + (size_t)hd*TE + dt, *hp2 = wphi + (size_t)hd*TE + dt, *ha = wamp + (size_t)hd*TE + dt;
    const float *tf = wfreq + (size_t)tl*TE + dt, *tp2 = wphi + (size_t)tl*TE + dt, *ta = wamp + (size_t)tl*TE + dt;
    #pragma unroll
    for (int j=0;j<4;j++){
      float2 f_h = *(const float2*)(hf + j*2);
      float2 p_h = *(const float2*)(hp2 + j*2);
      float2 a_h = *(const float2*)(ha + j*2);
      float2 f_t = *(const float2*)(tf + j*2);
      float2 p_t = *(const float2*)(tp2 + j*2);
      float2 a_t = *(const float2*)(ta + j*2);
      hv[2*j]   = a_h.x*__sinf(f_h.x*wk + p_h.x);
      hv[2*j+1] = a_h.y*__sinf(f_h.y*wk + p_h.y);
      tv[2*j]   = a_t.x*__sinf(f_t.x*wk + p_t.x);
      tv[2*j+1] = a_t.y*__sinf(f_t.y*wk + p_t.y);
    }
  } else {
    #pragma unroll
    for (int j=0;j<8;j++){
      int d = 40 + j;
      if (d < SE){
        hv[j] = ent[(size_t)hd*SE + d];
        tv[j] = ent[(size_t)tl*SE + d];
      } else {
        int dt = d - SE;
        hv[j] = wamp[(size_t)hd*TE+dt]*__sinf(wfreq[(size_t)hd*TE+dt]*wk + wphi[(size_t)hd*TE+dt]);
        tv[j] = wamp[(size_t)tl*TE+dt]*__sinf(wfreq[(size_t)tl*TE+dt]*wk + wphi[(size_t)tl*TE+dt]);
      }
    }
  }
  const float* rp = rel_embs + rl*128 + d0;
  float4 r0 = *(const float4*)rp, r1 = *(const float4*)(rp+4);
  float rv[8] = {r0.x,r0.y,r0.z,r0.w, r1.x,r1.y,r1.z,r1.w};
  s16x8 o;
  #pragma unroll
  for (int j=0;j<8;j++) o[j] = (short)f2bf(hv[j]*rv[j]*tv[j]);
  *(s16x8*)(scores + (size_t)e*128 + d0) = o;
}

// ---------------- MFMA GEMM: pre2b = bf16(perm(scores @ Wih^T + bih + bhh)) ----------------
__global__ __launch_bounds__(256) void k_pregemm(
    const short* __restrict__ scores, const short* __restrict__ WihB,
    const float* __restrict__ bih, const float* __restrict__ bhh,
    short* __restrict__ pre2b){
  __shared__ char As[32*256];   // bf16 [32 edges][128 k], XOR-swizzled rows
  int e0 = blockIdx.x * 32;
  int tid = threadIdx.x;
  #pragma unroll
  for (int q=0;q<2;q++){
    int c = tid + 256*q;            // 0..511
    int el = c >> 4, k8 = c & 15;
    s16x8 v = *(const s16x8*)(scores + (size_t)(e0+el)*128 + k8*8);
    *(s16x8*)(As + ((el*256 + k8*16) ^ ((el&7)<<4))) = v;
  }
  __syncthreads();
  int lane = tid & 63, w = tid >> 6;
  int cl = lane & 15, kq = lane >> 4;
  s16x8 a[2][4];
  #pragma unroll
  for (int ks=0;ks<4;ks++){
    int kb = ks*64 + kq*16;
    a[0][ks] = *(const s16x8*)(As + (((cl   )*256 + kb) ^ ((cl&7)<<4)));
    a[1][ks] = *(const s16x8*)(As + (((cl+16)*256 + kb) ^ (((cl+16)&7)<<4)));
  }
  f32x4 D[2][8];
  #pragma unroll
  for (int m=0;m<2;m++)
    #pragma unroll
    for (int i=0;i<8;i++) D[m][i] = (f32x4){0.f,0.f,0.f,0.f};
  #pragma unroll
  for (int i=0;i<8;i++){
    int n = w*128 + i*16 + cl;
    const short* bp = WihB + (size_t)n*128 + kq*8;
    #pragma unroll
    for (int ks=0;ks<4;ks++){
      s16x8 b = *(const s16x8*)(bp + ks*32);
      D[0][i] = __builtin_amdgcn_mfma_f32_16x16x32_bf16(a[0][ks], b, D[0][i], 0, 0, 0);
      D[1][i] = __builtin_amdgcn_mfma_f32_16x16x32_bf16(a[1][ks], b, D[1][i], 0, 0, 0);
    }
  }
  #pragma unroll
  for (int i=0;i<8;i++){
    int n = w*128 + i*16 + cl;
    int pn = perm_out(n);
    float bb = bih[pn] + bhh[pn];
    #pragma unroll
    for (int m=0;m<2;m++){
      #pragma unroll
      for (int q2=0;q2<4;q2++){
        int row = m*16 + kq*4 + q2;
        pre2b[(size_t)(e0+row)*512 + n] = (short)f2bf(D[m][i][q2] + bb);
      }
    }
  }
}

// ---------------- grouping machinery ----------------
__global__ void k_hist(const int* __restrict__ src, const int* __restrict__ dst,
                       int* __restrict__ scnt, int* __restrict__ dcnt){
  int e = blockIdx.x*blockDim.x + threadIdx.x;
  if (e < N_EDGES){ atomicAdd(&scnt[src[e]],1); atomicAdd(&dcnt[dst[e]],1); }
}

__global__ void k_scan(const int* __restrict__ scnt, const int* __restrict__ dcnt,
                       int* __restrict__ sstart, int* __restrict__ dstart){
  const int* cnt = blockIdx.x ? dcnt : scnt;
  int* start = blockIdx.x ? dstart : sstart;
  const int CH = 20;
  int tid = threadIdx.x;
  int base = tid*CH;
  int v[CH]; int tsum = 0;
  #pragma unroll
  for (int j=0;j<CH;j++){ int i = base+j; v[j] = (i<N_NODES)? cnt[i] : 0; tsum += v[j]; }
  int lane = tid & 63, wv = tid >> 6;
  int incl = tsum;
  #pragma unroll
  for (int m=1;m<64;m<<=1){ int u = __shfl_up(incl, m); if (lane >= m) incl += u; }
  __shared__ int wsum[16], woff[16];
  if (lane==63) wsum[wv] = incl;
  __syncthreads();
  if (tid < 16){ int s=0; for (int k=0;k<tid;k++) s += wsum[k]; woff[tid]=s; }
  __syncthreads();
  int run = woff[wv] + incl - tsum;
  #pragma unroll
  for (int j=0;j<CH;j++){ int i = base+j; if (i<N_NODES) start[i] = run; run += v[j]; }
  if (tid == 1023) start[N_NODES] = run;
}

__global__ void k_scatter(const int* __restrict__ src, const int* __restrict__ dst,
                          const int* __restrict__ sstart, const int* __restrict__ dstart,
                          int* __restrict__ sc2, int* __restrict__ dc2,
                          int* __restrict__ slist, int* __restrict__ dlist){
  int e = blockIdx.x*blockDim.x + threadIdx.x;
  if (e < N_EDGES){
    int s = src[e]; int p  = sstart[s] + atomicAdd(&sc2[s],1); slist[p]=e;
    int d = dst[e]; int p2 = dstart[d] + atomicAdd(&dc2[d],1); dlist[p2]=e;
  }
}

__global__ void k_sortlists(const int* __restrict__ sstart, const int* __restrict__ dstart,
                            int* __restrict__ slist, int* __restrict__ dlist){
  int n = blockIdx.x*blockDim.x + threadIdx.x;
  if (n < N_NODES){
    #pragma unroll
    for (int pass=0; pass<2; pass++){
      const int* st = pass ? dstart : sstart;
      int* ls = pass ? dlist : slist;
      int a = st[n], b = st[n+1];
      for (int i=a+1;i<b;i++){
        int v = ls[i]; int j=i-1;
        while (j>=a && ls[j]>v){ ls[j+1]=ls[j]; j--; }
        ls[j+1]=v;
      }
    }
  }
}

// ---------------- chain compaction: block-local counting sort ----------------
// Src-pass chains whose node ALSO has dst edges are dead work (dst pass overwrites) -> skip.
__global__ void k_cbin1(const int* __restrict__ sstart, const int* __restrict__ dstart,
                        int* __restrict__ bhist){
  __shared__ int h[128];
  int tid = threadIdx.x, blk = blockIdx.x;
  if (tid < 128) h[tid] = 0;
  __syncthreads();
  int n = blk*256 + tid;
  if (n < N_NODES){
    int c  = sstart[n+1]-sstart[n];
    int c2 = dstart[n+1]-dstart[n];
    if (c>0 && c2==0) atomicAdd(&h[min(c,63)], 1);
    if (c2>0) atomicAdd(&h[64+min(c2,63)], 1);
  }
  __syncthreads();
  if (tid < 128) bhist[tid*NBLK + blk] = h[tid];
}

__global__ void k_cbin2(const int* __restrict__ bhist, int* __restrict__ boff,
                        int* __restrict__ nchains){
  const int S = 2*63*NBLK;   // 9954
  const int CH = 10;
  int tid = threadIdx.x;
  int v[CH]; int tsum = 0;
  int binidx[CH];
  #pragma unroll
  for (int j=0;j<CH;j++){
    int s = tid*CH + j;
    int val = 0, bi = -1;
    if (s < S){
      int p = s / (63*NBLK);
      int r = s - p*63*NBLK;
      int li = r / NBLK;
      int b  = r - li*NBLK;
      int l  = 63 - li;
      bi = (p*64 + l)*NBLK + b;
      val = bhist[bi];
    }
    binidx[j] = bi; v[j] = val; tsum += val;
  }
  int lane = tid & 63, wv = tid >> 6;
  int incl = tsum;
  #pragma unroll
  for (int m=1;m<64;m<<=1){ int u = __shfl_up(incl, m); if (lane >= m) incl += u; }
  __shared__ int wsum[16], woff[16];
  __shared__ int pend[2];
  if (lane==63) wsum[wv] = incl;
  __syncthreads();
  if (tid < 16){ int s=0; for (int k=0;k<tid;k++) s += wsum[k]; woff[tid]=s; }
  __syncthreads();
  int run = woff[wv] + incl - tsum;
  #pragma unroll
  for (int j=0;j<CH;j++){
    int s = tid*CH + j;
    if (s < S){
      boff[binidx[j]] = run;
      run += v[j];
      if (s == 63*NBLK - 1) pend[0] = run;
      if (s == S - 1)       pend[1] = run;
    }
  }
  __syncthreads();
  if (tid == 0){
    nchains[0] = pend[0];
    nchains[1] = pend[1] - pend[0];
  }
}

__global__ void k_cbin3(const int* __restrict__ sstart, const int* __restrict__ dstart,
                        const int* __restrict__ boff, const int* __restrict__ nchains,
                        int* __restrict__ cnode, int* __restrict__ cstart,
                        int* __restrict__ clen){
  __shared__ int h[128];
  int tid = threadIdx.x, blk = blockIdx.x;
  if (tid < 128) h[tid] = 0;
  __syncthreads();
  int n = blk*256 + tid;
  int bin0=-1, bin1=-1, r0=0, r1=0, a0=0, c0=0, a1=0, c1=0;
  if (n < N_NODES){
    a0 = sstart[n]; c0 = sstart[n+1]-a0;
    a1 = dstart[n]; c1 = dstart[n+1]-a1;
    if (c0>0 && c1==0){ bin0 = min(c0,63);    r0 = atomicAdd(&h[bin0], 1); }
    if (c1>0)         { bin1 = 64+min(c1,63); r1 = atomicAdd(&h[bin1], 1); }
  }
  __syncthreads();
  int nch0 = nchains[0];
  if (bin0 >= 0){
    int pos = boff[bin0*NBLK + blk] + r0;
    cnode[pos] = n; cstart[pos] = a0; clen[pos] = c0;
  }
  if (bin1 >= 0){
    int pos = boff[bin1*NBLK + blk] + r1 - nch0;
    cnode[N_NODES+pos] = n; cstart[N_NODES+pos] = a1; clen[N_NODES+pos] = c1;
  }
}

// ---------------- persistent MFMA LSTM v5: gate-direct + pv prefetch pipeline ----------------
// LDS: W (512 rows x 256B bf16, swz) | H x2 (32 x 256B bf16, swz) | meta
#define LDS_H4 131072
#define LDS_META4 147456
#define LDSZ4 148480

__global__ __launch_bounds__(512, 1) void k_lstm5(
    const short* __restrict__ pre2b, const float* __restrict__ Whh,
    const int* __restrict__ cnode, const int* __restrict__ cstart,
    const int* __restrict__ clen, const int* __restrict__ nchains,
    const int* __restrict__ slist, const int* __restrict__ dlist,
    int* __restrict__ ctr, float* __restrict__ emb){
  extern __shared__ char smem[];
  int tid = threadIdx.x;
  int lane = tid & 63, wv = tid >> 6;
  int cl = lane & 15, kq = lane >> 4;
  int d_own = wv*16 + cl;
  // load Whh (original row order) -> LDS bf16 swizzled
  #pragma unroll 1
  for (int q=0;q<16;q++){
    int c = q*512 + tid;
    int n = c >> 4, k8 = c & 15;
    const float* src = Whh + (size_t)n*128 + k8*8;
    s16x8 v8;
    #pragma unroll
    for (int j=0;j<8;j++) v8[j] = (short)f2bf(src[j]);
    int byt = (n*256 + k8*16) ^ ((n&7)<<4);
    *(s16x8*)(smem + byt) = v8;
  }
  int nch0 = nchains[0], nch1 = nchains[1];
  int B0 = (nch0+31)>>5, B1 = (nch1+31)>>5;
  // M: [0..31] len | [32..63] start | [64..127] eid slots 2x32 | [128..159] node | [160] nb
  int* M = (int*)(smem + LDS_META4);
  __syncthreads();
  while (true){
    if (tid==0) M[160] = atomicAdd(ctr, 1);
    __syncthreads();
    int nb = M[160];
    if (nb >= B0 + B1) break;
    int pass = (nb >= B0) ? 1 : 0;
    int batch = pass ? nb - B0 : nb;
    int b0 = batch << 5;
    int nch = pass ? nch1 : nch0;
    const int* list = pass ? dlist : slist;
    if (tid < 32){
      int j = b0 + tid;
      int valid = (j < nch);
      int ci = pass*N_NODES + j;
      int st = valid ? cstart[ci] : 0;
      int ln = valid ? clen[ci] : 0;
      M[tid] = ln; M[32+tid] = st; M[128+tid] = valid ? cnode[ci] : -1;
      M[64+tid] = (ln > 0) ? list[st]   : 0;   // eid[0] -> slot 0
      M[96+tid] = (ln > 1) ? list[st+1] : 0;   // eid[1] -> slot 1
    }
    // zero H buffer 0 (8KB)
    {
      unsigned long long* hz = (unsigned long long*)(smem + LDS_H4 + tid*16);
      hz[0] = 0ull; hz[1] = 0ull;
    }
    float cst[8]  = {0.f,0.f,0.f,0.f,0.f,0.f,0.f,0.f};
    float hreg[8] = {0.f,0.f,0.f,0.f,0.f,0.f,0.f,0.f};
    __syncthreads();
    int mylen[8];
    #pragma unroll
    for (int m=0;m<2;m++)
      #pragma unroll
      for (int q=0;q<4;q++) mylen[m*4+q] = M[m*16 + kq*4 + q];
    int ml = 0;
    #pragma unroll 1
    for (int j=0;j<32;j++) ml = max(ml, M[j]);
    // issue pv for t=0 (slot 0)
    s16x4 pvc[8];
    #pragma unroll
    for (int m=0;m<2;m++)
      #pragma unroll
      for (int q=0;q<4;q++){
        int r = m*16 + kq*4 + q;
        pvc[m*4+q] = *(const s16x4*)(pre2b + (size_t)M[64+r]*512 + d_own*4);
      }
    int cur = 0;
    for (int t=0; t<ml; t++){
      // issue pv loads for t+1 from slot ((t+1)&1)
      s16x4 pvn[8];
      const int* eidN = M + 64 + (((t+1)&1)<<5);
      #pragma unroll
      for (int m=0;m<2;m++)
        #pragma unroll
        for (int q=0;q<4;q++){
          int r = m*16 + kq*4 + q;
          pvn[m*4+q] = *(const s16x4*)(pre2b + (size_t)eidN[r]*512 + d_own*4);
        }
      // MFMA: gates_raw from H[cur]
      f32x4 D[2][4];
      #pragma unroll
      for (int m=0;m<2;m++)
        #pragma unroll
        for (int i=0;i<4;i++) D[m][i] = (f32x4){0.f,0.f,0.f,0.f};
      char* Hc = smem + LDS_H4 + cur*8192;
      #pragma unroll
      for (int ks=0; ks<4; ks++){
        int kb = ks*64 + kq*16;
        s16x8 a0 = *(const s16x8*)(Hc + (((cl   )*256 + kb) ^ ((cl&7)<<4)));
        s16x8 a1 = *(const s16x8*)(Hc + (((cl+16)*256 + kb) ^ (((cl+16)&7)<<4)));
        #pragma unroll
        for (int i=0;i<4;i++){
          int n = i*128 + d_own;
          s16x8 b = *(const s16x8*)(smem + ((n*256 + kb) ^ ((n&7)<<4)));
          D[0][i] = __builtin_amdgcn_mfma_f32_16x16x32_bf16(a0, b, D[0][i], 0, 0, 0);
          D[1][i] = __builtin_amdgcn_mfma_f32_16x16x32_bf16(a1, b, D[1][i], 0, 0, 0);
        }
      }
      // gate combine in registers with pvc (issued one step ago); write h to H[cur^1]
      char* Hn = smem + LDS_H4 + (cur^1)*8192;
      #pragma unroll
      for (int m=0;m<2;m++)
        #pragma unroll
        for (int q=0;q<4;q++){
          int r = m*16 + kq*4 + q;
          if (t < mylen[m*4+q]){
            s16x4 p = pvc[m*4+q];
            float gi = D[m][0][q] + bf2f(p[0]);
            float gf = D[m][1][q] + bf2f(p[1]);
            float gg = D[m][2][q] + bf2f(p[2]);
            float go = D[m][3][q] + bf2f(p[3]);
            int idx = m*4+q;
            cst[idx] = sigf(gf)*cst[idx] + sigf(gi)*tanh_f(gg);
            float h = sigf(go)*tanh_f(cst[idx]);
            hreg[idx] = h;
            *(short*)(Hn + ((r*256 + d_own*2) ^ ((r&7)<<4))) = (short)f2bf(h);
          }
        }
      // prefetch eid[t+2] into slot (t&1) (its old contents already consumed)
      if (tid < 32){
        int ln = M[tid];
        M[64 + ((t&1)<<5) + tid] = (t+2 < ln) ? list[M[32+tid] + t+2] : 0;
      }
      __syncthreads();
      #pragma unroll
      for (int i=0;i<8;i++) pvc[i] = pvn[i];
      cur ^= 1;
    }
    // emb writes (binning already excluded overwritten src chains)
    #pragma unroll
    for (int m=0;m<2;m++)
      #pragma unroll
      for (int q=0;q<4;q++){
        int r = m*16 + kq*4 + q;
        int n = M[128+r];
        if (mylen[m*4+q] > 0 && n >= 0){
          emb[(size_t)n*128 + d_own] = hreg[m*4+q];
        }
      }
    __syncthreads();
  }
}

// ---------------- MFMA MLP: 32 nodes/block, fc1 GEMM + LN + out ----------------
__global__ __launch_bounds__(512) void k_mlp2(
    const float* __restrict__ x, const float* __restrict__ emb,
    const short* __restrict__ fc1wbf, const float* __restrict__ fc1b,
    const float* __restrict__ lng, const float* __restrict__ lnb,
    const float* __restrict__ outw, const float* __restrict__ outb,
    float* __restrict__ out){
  __shared__ char As[32*768];          // bf16 [32][384], XOR-swizzled rows
  __shared__ float hbuf[32][132];
  int tid = threadIdx.x;
  int lane = tid & 63, w = tid >> 6;
  int base = blockIdx.x * 32;
  #pragma unroll
  for (int q=0;q<3;q++){
    int i = tid + 512*q;              // 0..1535, 48 chunks of 8 per row
    int r = i / 48, c = i - r*48;
    const float* src = (c < 32) ? (x + (size_t)(base+r)*256 + c*8)
                                : (emb + (size_t)(base+r)*128 + (c-32)*8);
    float4 v0 = *(const float4*)src;
    float4 v1 = *(const float4*)(src+4);
    s16x8 v8;
    v8[0]=(short)f2bf(v0.x); v8[1]=(short)f2bf(v0.y); v8[2]=(short)f2bf(v0.z); v8[3]=(short)f2bf(v0.w);
    v8[4]=(short)f2bf(v1.x); v8[5]=(short)f2bf(v1.y); v8[6]=(short)f2bf(v1.z); v8[7]=(short)f2bf(v1.w);
    *(s16x8*)(As + ((r*768 + c*16) ^ ((r&7)<<4))) = v8;
  }
  __syncthreads();
  int cl = lane & 15, kq = lane >> 4;
  f32x4 D0 = {0.f,0.f,0.f,0.f}, D1 = {0.f,0.f,0.f,0.f};
  const short* bp = fc1wbf + (size_t)(w*16 + cl)*384 + kq*8;
  #pragma unroll
  for (int ks=0; ks<12; ks++){
    s16x8 b = *(const s16x8*)(bp + ks*32);
    int kb = ks*64 + kq*16;
    s16x8 a0 = *(const s16x8*)(As + (((cl   )*768 + kb) ^ ((cl&7)<<4)));
    s16x8 a1 = *(const s16x8*)(As + (((cl+16)*768 + kb) ^ (((cl+16)&7)<<4)));
    D0 = __builtin_amdgcn_mfma_f32_16x16x32_bf16(a0, b, D0, 0, 0, 0);
    D1 = __builtin_amdgcn_mfma_f32_16x16x32_bf16(a1, b, D1, 0, 0, 0);
  }
  int col = w*16 + cl;
  float bb = fc1b[col];
  #pragma unroll
  for (int q=0;q<4;q++){
    hbuf[kq*4+q][col]    = D0[q] + bb;
    hbuf[16+kq*4+q][col] = D1[q] + bb;
  }
  __syncthreads();
  int sub = lane >> 4, l16 = lane & 15;
  int nd = w*4 + sub;
  float v[8];
  float s = 0.f;
  #pragma unroll
  for (int j=0;j<8;j++){ v[j] = hbuf[nd][l16*8+j]; s += v[j]; }
  #pragma unroll
  for (int m=1;m<16;m<<=1) s += __shfl_xor(s, m);
  float mu = s * (1.f/128.f);
  float va = 0.f;
  #pragma unroll
  for (int j=0;j<8;j++){ float dm = v[j]-mu; va += dm*dm; }
  #pragma unroll
  for (int m=1;m<16;m<<=1) va += __shfl_xor(va, m);
  float rstd = rsqrtf(va*(1.f/128.f) + 1e-5f);
  float o0=0.f, o1=0.f;
  #pragma unroll
  for (int j=0;j<8;j++){
    int c = l16*8+j;
    float h1 = (v[j]-mu)*rstd*lng[c] + lnb[c];
    h1 = fmaxf(h1, 0.f);
    o0 += h1*outw[c]; o1 += h1*outw[128+c];
  }
  #pragma unroll
  for (int m=1;m<16;m<<=1){ o0 += __shfl_xor(o0,m); o1 += __shfl_xor(o1,m); }
  if (l16==0){
    out[(size_t)(base+nd)*2]   = o0 + outb[0];
    out[(size_t)(base+nd)*2+1] = o1 + outb[1];
  }
}

extern "C" void kernel_launch(void* const* d_in, const int* in_sizes, int n_in,
                              void* d_out, int out_size, void* d_ws, size_t ws_size,
                              hipStream_t stream){
  const float* x      = (const float*)d_in[0];
  const int*   heads  = (const int*)d_in[1];
  const int*   rels   = (const int*)d_in[2];
  const int*   tails  = (const int*)d_in[3];
  const float* weeks  = (const float*)d_in[4];
  const int*   esrc   = (const int*)d_in[5];
  const int*   edst   = (const int*)d_in[6];
  const float* ent    = (const float*)d_in[10];
  const float* rel_e  = (const float*)d_in[11];
  const float* wfreq  = (const float*)d_in[12];
  const float* wphi   = (const float*)d_in[13];
  const float* wamp   = (const float*)d_in[14];
  const float* Wih    = (const float*)d_in[15];
  const float* Whh    = (const float*)d_in[16];
  const float* bih    = (const float*)d_in[17];
  const float* bhh    = (const float*)d_in[18];
  const float* fc1w   = (const float*)d_in[19];
  const float* fc1b   = (const float*)d_in[20];
  const float* lng    = (const float*)d_in[21];
  const float* lnb    = (const float*)d_in[22];
  const float* outw   = (const float*)d_in[23];
  const float* outb   = (const float*)d_in[24];
  float* out = (float*)d_out;

  char* ws = (char*)d_ws;
  size_t off = 0;
  auto alloc = [&](size_t bytes){ void* p = ws + off; off += (bytes + 255) & ~(size_t)255; return p; };
  short* pre2b  = (short*)alloc((size_t)N_EDGES*512*2);
  short* scores = (short*)alloc((size_t)N_EDGES*128*2);
  short* WihB   = (short*)alloc(512*128*2);
  short* fc1wbf = (short*)alloc(128*384*2);
  float* emb    = (float*)alloc((size_t)N_NODES*128*4);
  int* sstart   = (int*)alloc((N_NODES+1)*4);
  int* dstart   = (int*)alloc((N_NODES+1)*4);
  int* zreg     = (int*)alloc((size_t)(4*N_NODES + 3)*4);
  int* scnt = zreg, *dcnt = zreg+N_NODES, *sc2 = zreg+2*N_NODES, *dc2 = zreg+3*N_NODES;
  int* nchains  = zreg + 4*N_NODES;
  int* ctr      = nchains + 2;
  int* bhist    = (int*)alloc((size_t)128*NBLK*4);
  int* boff     = (int*)alloc((size_t)128*NBLK*4);
  int* slist    = (int*)alloc(N_EDGES*4);
  int* dlist    = (int*)alloc(N_EDGES*4);
  int* cnode    = (int*)alloc((size_t)2*N_NODES*4);
  int* cstart   = (int*)alloc((size_t)2*N_NODES*4);
  int* clen     = (int*)alloc((size_t)2*N_NODES*4);

  hipMemsetAsync(zreg, 0, (size_t)(4*N_NODES + 3)*4, stream);
  hipMemsetAsync(emb, 0, (size_t)N_NODES*128*4, stream);

  hipFuncSetAttribute((const void*)k_lstm5, hipFuncAttributeMaxDynamicSharedMemorySize, LDSZ4);

  k_prepwih<<<(512*128+255)/256, 256, 0, stream>>>(Wih, WihB);
  k_prepw<<<(128*384+255)/256, 256, 0, stream>>>(fc1w, fc1wbf, 128*384);

  k_gather<<<N_EDGES*16/256, 256, 0, stream>>>(heads, rels, tails, weeks, ent, rel_e,
                                               wfreq, wphi, wamp, scores);
  k_pregemm<<<N_EDGES/32, 256, 0, stream>>>(scores, WihB, bih, bhh, pre2b);
  k_hist<<<(N_EDGES+255)/256, 256, 0, stream>>>(esrc, edst, scnt, dcnt);
  k_scan<<<2, 1024, 0, stream>>>(scnt, dcnt, sstart, dstart);
  k_scatter<<<(N_EDGES+255)/256, 256, 0, stream>>>(esrc, edst, sstart, dstart, sc2, dc2, slist, dlist);
  k_sortlists<<<(N_NODES+255)/256, 256, 0, stream>>>(sstart, dstart, slist, dlist);
  k_cbin1<<<NBLK, 256, 0, stream>>>(sstart, dstart, bhist);
  k_cbin2<<<1, 1024, 0, stream>>>(bhist, boff, nchains);
  k_cbin3<<<NBLK, 256, 0, stream>>>(sstart, dstart, boff, nchains, cnode, cstart, clen);
  k_lstm5<<<256, 512, LDSZ4, stream>>>(pre2b, Whh, cnode, cstart, clen, nchains,
                                       slist, dlist, ctr, emb);
  k_mlp2<<<N_NODES/32, 512, 0, stream>>>(x, emb, fc1wbf, fc1b, lng, lnb, outw, outb, out);
}

// Round 10
// 181.128 us; speedup vs baseline: 5.4302x; 1.0411x over previous
//
#include <hip/hip_runtime.h>
#include <math.h>

#define N_NODES 20000
#define N_EDGES 40000
#define SE 46
#define TE 82
#define NBLK 79   // ceil(N_NODES/256)
// D = 128, 4D = 512, F = 256, HID = 128

typedef short  s16x8 __attribute__((ext_vector_type(8)));
typedef short  s16x4 __attribute__((ext_vector_type(4)));
typedef float  f32x4 __attribute__((ext_vector_type(4)));

__device__ __forceinline__ float sigf(float x){ return 1.0f/(1.0f+__expf(-x)); }
__device__ __forceinline__ float tanh_f(float x){ return 1.0f - 2.0f/(__expf(2.0f*x)+1.0f); }
__device__ __forceinline__ int perm_out(int i){ return (i&3)*128 + (i>>2); }
__device__ __forceinline__ unsigned short f2bf(float f){
  unsigned u = __builtin_bit_cast(unsigned, f);
  unsigned r = (u + 0x7fff + ((u>>16)&1)) >> 16;
  return (unsigned short)r;
}
__device__ __forceinline__ float bf2f(short s){
  unsigned u = ((unsigned)(unsigned short)s) << 16;
  return __builtin_bit_cast(float, u);
}

// ---------------- fused weight prep: WihB (perm) | WhhB2 (plain) | fc1wbf ----------------
__global__ void k_prep(const float* __restrict__ Wih, const float* __restrict__ Whh,
                       const float* __restrict__ fc1w,
                       short* __restrict__ WihB, short* __restrict__ WhhB2,
                       short* __restrict__ fc1wbf){
  int idx = blockIdx.x*blockDim.x + threadIdx.x;
  if (idx < 65536){
    int i = idx >> 7, k = idx & 127;
    WihB[idx] = (short)f2bf(Wih[perm_out(i)*128 + k]);
  } else if (idx < 131072){
    int j = idx - 65536;
    WhhB2[j] = (short)f2bf(Whh[j]);
  } else if (idx < 180224){
    int j = idx - 131072;
    fc1wbf[j] = (short)f2bf(fc1w[j]);
  }
}

// ---------------- gather: scores[e][d] = h*r*t as bf16, 8 dims/thread ----------------
__global__ __launch_bounds__(256) void k_gather(
    const int* __restrict__ heads, const int* __restrict__ rels,
    const int* __restrict__ tails, const float* __restrict__ weeks,
    const float* __restrict__ ent, const float* __restrict__ rel_embs,
    const float* __restrict__ wfreq, const float* __restrict__ wphi,
    const float* __restrict__ wamp, short* __restrict__ scores){
  int c = blockIdx.x*256 + threadIdx.x;   // 640000 chunks
  int e = c >> 4, d0 = (c & 15) << 3;
  int hd = heads[e], tl = tails[e], rl = rels[e];
  float wk = weeks[e];
  float hv[8], tv[8];
  if (d0 + 8 <= SE){
    const float* hp = ent + (size_t)hd*SE + d0;
    const float* tp = ent + (size_t)tl*SE + d0;
    #pragma unroll
    for (int j=0;j<4;j++){
      float2 a = *(const float2*)(hp + j*2); hv[2*j]=a.x; hv[2*j+1]=a.y;
      float2 b = *(const float2*)(tp + j*2); tv[2*j]=b.x; tv[2*j+1]=b.y;
    }
  } else if (d0 >= 48){
    int dt = d0 - SE;
    const float *hf = wfreq + (size_t)hd*TE + dt, *hp2 = wphi + (size_t)hd*TE + dt, *ha = wamp + (size_t)hd*TE + dt;
    const float *tf = wfreq + (size_t)tl*TE + dt, *tp2 = wphi + (size_t)tl*TE + dt, *ta = wamp + (size_t)tl*TE + dt;
    #pragma unroll
    for (int j=0;j<4;j++){
      float2 f_h = *(const float2*)(hf + j*2);
      float2 p_h = *(const float2*)(hp2 + j*2);
      float2 a_h = *(const float2*)(ha + j*2);
      float2 f_t = *(const float2*)(tf + j*2);
      float2 p_t = *(const float2*)(tp2 + j*2);
      float2 a_t = *(const float2*)(ta + j*2);
      hv[2*j]   = a_h.x*__sinf(f_h.x*wk + p_h.x);
      hv[2*j+1] = a_h.y*__sinf(f_h.y*wk + p_h.y);
      tv[2*j]   = a_t.x*__sinf(f_t.x*wk + p_t.x);
      tv[2*j+1] = a_t.y*__sinf(f_t.y*wk + p_t.y);
    }
  } else {
    #pragma unroll
    for (int j=0;j<8;j++){
      int d = 40 + j;
      if (d < SE){
        hv[j] = ent[(size_t)hd*SE + d];
        tv[j] = ent[(size_t)tl*SE + d];
      } else {
        int dt = d - SE;
        hv[j] = wamp[(size_t)hd*TE+dt]*__sinf(wfreq[(size_t)hd*TE+dt]*wk + wphi[(size_t)hd*TE+dt]);
        tv[j] = wamp[(size_t)tl*TE+dt]*__sinf(wfreq[(size_t)tl*TE+dt]*wk + wphi[(size_t)tl*TE+dt]);
      }
    }
  }
  const float* rp = rel_embs + rl*128 + d0;
  float4 r0 = *(const float4*)rp, r1 = *(const float4*)(rp+4);
  float rv[8] = {r0.x,r0.y,r0.z,r0.w, r1.x,r1.y,r1.z,r1.w};
  s16x8 o;
  #pragma unroll
  for (int j=0;j<8;j++) o[j] = (short)f2bf(hv[j]*rv[j]*tv[j]);
  *(s16x8*)(scores + (size_t)e*128 + d0) = o;
}

// ---------------- MFMA GEMM: pre2b = bf16(perm(scores @ Wih^T + bih + bhh)) ----------------
__global__ __launch_bounds__(256) void k_pregemm(
    const short* __restrict__ scores, const short* __restrict__ WihB,
    const float* __restrict__ bih, const float* __restrict__ bhh,
    short* __restrict__ pre2b){
  __shared__ char As[32*256];   // bf16 [32 edges][128 k], XOR-swizzled rows
  int e0 = blockIdx.x * 32;
  int tid = threadIdx.x;
  #pragma unroll
  for (int q=0;q<2;q++){
    int c = tid + 256*q;            // 0..511
    int el = c >> 4, k8 = c & 15;
    s16x8 v = *(const s16x8*)(scores + (size_t)(e0+el)*128 + k8*8);
    *(s16x8*)(As + ((el*256 + k8*16) ^ ((el&7)<<4))) = v;
  }
  __syncthreads();
  int lane = tid & 63, w = tid >> 6;
  int cl = lane & 15, kq = lane >> 4;
  s16x8 a[2][4];
  #pragma unroll
  for (int ks=0;ks<4;ks++){
    int kb = ks*64 + kq*16;
    a[0][ks] = *(const s16x8*)(As + (((cl   )*256 + kb) ^ ((cl&7)<<4)));
    a[1][ks] = *(const s16x8*)(As + (((cl+16)*256 + kb) ^ (((cl+16)&7)<<4)));
  }
  f32x4 D[2][8];
  #pragma unroll
  for (int m=0;m<2;m++)
    #pragma unroll
    for (int i=0;i<8;i++) D[m][i] = (f32x4){0.f,0.f,0.f,0.f};
  #pragma unroll
  for (int i=0;i<8;i++){
    int n = w*128 + i*16 + cl;
    const short* bp = WihB + (size_t)n*128 + kq*8;
    #pragma unroll
    for (int ks=0;ks<4;ks++){
      s16x8 b = *(const s16x8*)(bp + ks*32);
      D[0][i] = __builtin_amdgcn_mfma_f32_16x16x32_bf16(a[0][ks], b, D[0][i], 0, 0, 0);
      D[1][i] = __builtin_amdgcn_mfma_f32_16x16x32_bf16(a[1][ks], b, D[1][i], 0, 0, 0);
    }
  }
  #pragma unroll
  for (int i=0;i<8;i++){
    int n = w*128 + i*16 + cl;
    int pn = perm_out(n);
    float bb = bih[pn] + bhh[pn];
    #pragma unroll
    for (int m=0;m<2;m++){
      #pragma unroll
      for (int q2=0;q2<4;q2++){
        int row = m*16 + kq*4 + q2;
        pre2b[(size_t)(e0+row)*512 + n] = (short)f2bf(D[m][i][q2] + bb);
      }
    }
  }
}

// ---------------- grouping machinery ----------------
__global__ void k_hist(const int* __restrict__ src, const int* __restrict__ dst,
                       int* __restrict__ scnt, int* __restrict__ dcnt){
  int e = blockIdx.x*blockDim.x + threadIdx.x;
  if (e < N_EDGES){ atomicAdd(&scnt[src[e]],1); atomicAdd(&dcnt[dst[e]],1); }
}

__global__ void k_scan(const int* __restrict__ scnt, const int* __restrict__ dcnt,
                       int* __restrict__ sstart, int* __restrict__ dstart){
  const int* cnt = blockIdx.x ? dcnt : scnt;
  int* start = blockIdx.x ? dstart : sstart;
  const int CH = 20;
  int tid = threadIdx.x;
  int base = tid*CH;
  int v[CH]; int tsum = 0;
  #pragma unroll
  for (int j=0;j<CH;j++){ int i = base+j; v[j] = (i<N_NODES)? cnt[i] : 0; tsum += v[j]; }
  int lane = tid & 63, wv = tid >> 6;
  int incl = tsum;
  #pragma unroll
  for (int m=1;m<64;m<<=1){ int u = __shfl_up(incl, m); if (lane >= m) incl += u; }
  __shared__ int wsum[16], woff[16];
  if (lane==63) wsum[wv] = incl;
  __syncthreads();
  if (tid < 16){ int s=0; for (int k=0;k<tid;k++) s += wsum[k]; woff[tid]=s; }
  __syncthreads();
  int run = woff[wv] + incl - tsum;
  #pragma unroll
  for (int j=0;j<CH;j++){ int i = base+j; if (i<N_NODES) start[i] = run; run += v[j]; }
  if (tid == 1023) start[N_NODES] = run;
}

__global__ void k_scatter(const int* __restrict__ src, const int* __restrict__ dst,
                          const int* __restrict__ sstart, const int* __restrict__ dstart,
                          int* __restrict__ sc2, int* __restrict__ dc2,
                          int* __restrict__ slist, int* __restrict__ dlist){
  int e = blockIdx.x*blockDim.x + threadIdx.x;
  if (e < N_EDGES){
    int s = src[e]; int p  = sstart[s] + atomicAdd(&sc2[s],1); slist[p]=e;
    int d = dst[e]; int p2 = dstart[d] + atomicAdd(&dc2[d],1); dlist[p2]=e;
  }
}

__global__ void k_sortlists(const int* __restrict__ sstart, const int* __restrict__ dstart,
                            int* __restrict__ slist, int* __restrict__ dlist){
  int n = blockIdx.x*blockDim.x + threadIdx.x;
  if (n < N_NODES){
    #pragma unroll
    for (int pass=0; pass<2; pass++){
      const int* st = pass ? dstart : sstart;
      int* ls = pass ? dlist : slist;
      int a = st[n], b = st[n+1];
      for (int i=a+1;i<b;i++){
        int v = ls[i]; int j=i-1;
        while (j>=a && ls[j]>v){ ls[j+1]=ls[j]; j--; }
        ls[j+1]=v;
      }
    }
  }
}

// ---------------- chain compaction: block-local counting sort ----------------
// Src-pass chains whose node ALSO has dst edges are dead work (dst pass overwrites) -> skip.
__global__ void k_cbin1(const int* __restrict__ sstart, const int* __restrict__ dstart,
                        int* __restrict__ bhist){
  __shared__ int h[128];
  int tid = threadIdx.x, blk = blockIdx.x;
  if (tid < 128) h[tid] = 0;
  __syncthreads();
  int n = blk*256 + tid;
  if (n < N_NODES){
    int c  = sstart[n+1]-sstart[n];
    int c2 = dstart[n+1]-dstart[n];
    if (c>0 && c2==0) atomicAdd(&h[min(c,63)], 1);
    if (c2>0) atomicAdd(&h[64+min(c2,63)], 1);
  }
  __syncthreads();
  if (tid < 128) bhist[tid*NBLK + blk] = h[tid];
}

__global__ void k_cbin2(const int* __restrict__ bhist, int* __restrict__ boff,
                        int* __restrict__ nchains){
  const int S = 2*63*NBLK;   // 9954
  const int CH = 10;
  int tid = threadIdx.x;
  int v[CH]; int tsum = 0;
  int binidx[CH];
  #pragma unroll
  for (int j=0;j<CH;j++){
    int s = tid*CH + j;
    int val = 0, bi = -1;
    if (s < S){
      int p = s / (63*NBLK);
      int r = s - p*63*NBLK;
      int li = r / NBLK;
      int b  = r - li*NBLK;
      int l  = 63 - li;
      bi = (p*64 + l)*NBLK + b;
      val = bhist[bi];
    }
    binidx[j] = bi; v[j] = val; tsum += val;
  }
  int lane = tid & 63, wv = tid >> 6;
  int incl = tsum;
  #pragma unroll
  for (int m=1;m<64;m<<=1){ int u = __shfl_up(incl, m); if (lane >= m) incl += u; }
  __shared__ int wsum[16], woff[16];
  __shared__ int pend[2];
  if (lane==63) wsum[wv] = incl;
  __syncthreads();
  if (tid < 16){ int s=0; for (int k=0;k<tid;k++) s += wsum[k]; woff[tid]=s; }
  __syncthreads();
  int run = woff[wv] + incl - tsum;
  #pragma unroll
  for (int j=0;j<CH;j++){
    int s = tid*CH + j;
    if (s < S){
      boff[binidx[j]] = run;
      run += v[j];
      if (s == 63*NBLK - 1) pend[0] = run;
      if (s == S - 1)       pend[1] = run;
    }
  }
  __syncthreads();
  if (tid == 0){
    nchains[0] = pend[0];
    nchains[1] = pend[1] - pend[0];
  }
}

__global__ void k_cbin3(const int* __restrict__ sstart, const int* __restrict__ dstart,
                        const int* __restrict__ boff, const int* __restrict__ nchains,
                        int* __restrict__ cnode, int* __restrict__ cstart,
                        int* __restrict__ clen){
  __shared__ int h[128];
  int tid = threadIdx.x, blk = blockIdx.x;
  if (tid < 128) h[tid] = 0;
  __syncthreads();
  int n = blk*256 + tid;
  int bin0=-1, bin1=-1, r0=0, r1=0, a0=0, c0=0, a1=0, c1=0;
  if (n < N_NODES){
    a0 = sstart[n]; c0 = sstart[n+1]-a0;
    a1 = dstart[n]; c1 = dstart[n+1]-a1;
    if (c0>0 && c1==0){ bin0 = min(c0,63);    r0 = atomicAdd(&h[bin0], 1); }
    if (c1>0)         { bin1 = 64+min(c1,63); r1 = atomicAdd(&h[bin1], 1); }
  }
  __syncthreads();
  int nch0 = nchains[0];
  if (bin0 >= 0){
    int pos = boff[bin0*NBLK + blk] + r0;
    cnode[pos] = n; cstart[pos] = a0; clen[pos] = c0;
  }
  if (bin1 >= 0){
    int pos = boff[bin1*NBLK + blk] + r1 - nch0;
    cnode[N_NODES+pos] = n; cstart[N_NODES+pos] = a1; clen[N_NODES+pos] = c1;
  }
}

// ---------------- persistent MFMA LSTM v6: Whh fragments in REGISTERS ----------------
// Wave wv owns dims d_own = wv*16+cl; thread holds wf[i][ks] = Whh B-fragment for
// gate i, k-chunk ks -- invariant across steps and batches (64 VGPRs).
// LDS: H double-buffer 2 x 8KB (32 chains x 256B bf16, XOR-swizzled) + meta.
__global__ __launch_bounds__(512, 1) void k_lstm6(
    const short* __restrict__ pre2b, const short* __restrict__ WhhB2,
    const int* __restrict__ cnode, const int* __restrict__ cstart,
    const int* __restrict__ clen, const int* __restrict__ nchains,
    const int* __restrict__ slist, const int* __restrict__ dlist,
    int* __restrict__ ctr, float* __restrict__ emb){
  __shared__ char Hb[2][8192];
  __shared__ int M[161];
  int tid = threadIdx.x;
  int lane = tid & 63, wv = tid >> 6;
  int cl = lane & 15, kq = lane >> 4;
  int d_own = wv*16 + cl;
  // load Whh B-fragments -> registers (once)
  s16x8 wf[4][4];
  #pragma unroll
  for (int i=0;i<4;i++)
    #pragma unroll
    for (int ks=0;ks<4;ks++)
      wf[i][ks] = *(const s16x8*)(WhhB2 + (size_t)(i*128 + d_own)*128 + ks*32 + kq*8);
  int nch0 = nchains[0], nch1 = nchains[1];
  int B0 = (nch0+31)>>5, B1 = (nch1+31)>>5;
  while (true){
    if (tid==0) M[160] = atomicAdd(ctr, 1);
    __syncthreads();
    int nb = M[160];
    if (nb >= B0 + B1) break;
    int pass = (nb >= B0) ? 1 : 0;
    int batch = pass ? nb - B0 : nb;
    int b0 = batch << 5;
    int nch = pass ? nch1 : nch0;
    const int* list = pass ? dlist : slist;
    if (tid < 32){
      int j = b0 + tid;
      int valid = (j < nch);
      int ci = pass*N_NODES + j;
      int st = valid ? cstart[ci] : 0;
      int ln = valid ? clen[ci] : 0;
      M[tid] = ln; M[32+tid] = st; M[128+tid] = valid ? cnode[ci] : -1;
      M[64+tid] = (ln > 0) ? list[st]   : 0;   // eid[0] -> slot 0
      M[96+tid] = (ln > 1) ? list[st+1] : 0;   // eid[1] -> slot 1
    }
    *(unsigned long long*)(&Hb[0][tid*16])   = 0ull;   // zero H buffer 0
    *(unsigned long long*)(&Hb[0][tid*16+8]) = 0ull;
    float cst[8]  = {0.f,0.f,0.f,0.f,0.f,0.f,0.f,0.f};
    float hreg[8] = {0.f,0.f,0.f,0.f,0.f,0.f,0.f,0.f};
    __syncthreads();
    int mylen[8];
    #pragma unroll
    for (int m=0;m<2;m++)
      #pragma unroll
      for (int q=0;q<4;q++) mylen[m*4+q] = M[m*16 + kq*4 + q];
    int ml = 0;
    #pragma unroll 1
    for (int j=0;j<32;j++) ml = max(ml, M[j]);
    // issue pv for t=0 (slot 0)
    s16x4 pvc[8];
    #pragma unroll
    for (int m=0;m<2;m++)
      #pragma unroll
      for (int q=0;q<4;q++){
        int r = m*16 + kq*4 + q;
        pvc[m*4+q] = *(const s16x4*)(pre2b + (size_t)M[64+r]*512 + d_own*4);
      }
    int cur = 0;
    for (int t=0; t<ml; t++){
      // issue pv loads for t+1 from slot ((t+1)&1)
      s16x4 pvn[8];
      const int* eidN = M + 64 + (((t+1)&1)<<5);
      #pragma unroll
      for (int m=0;m<2;m++)
        #pragma unroll
        for (int q=0;q<4;q++){
          int r = m*16 + kq*4 + q;
          pvn[m*4+q] = *(const s16x4*)(pre2b + (size_t)eidN[r]*512 + d_own*4);
        }
      // MFMA: gates_raw from H[cur] x wf (registers)
      f32x4 D[2][4];
      #pragma unroll
      for (int m=0;m<2;m++)
        #pragma unroll
        for (int i=0;i<4;i++) D[m][i] = (f32x4){0.f,0.f,0.f,0.f};
      char* Hc = Hb[cur];
      #pragma unroll
      for (int ks=0; ks<4; ks++){
        int kb = ks*64 + kq*16;
        s16x8 a0 = *(const s16x8*)(Hc + (((cl   )*256 + kb) ^ ((cl&7)<<4)));
        s16x8 a1 = *(const s16x8*)(Hc + (((cl+16)*256 + kb) ^ (((cl+16)&7)<<4)));
        #pragma unroll
        for (int i=0;i<4;i++){
          D[0][i] = __builtin_amdgcn_mfma_f32_16x16x32_bf16(a0, wf[i][ks], D[0][i], 0, 0, 0);
          D[1][i] = __builtin_amdgcn_mfma_f32_16x16x32_bf16(a1, wf[i][ks], D[1][i], 0, 0, 0);
        }
      }
      // gate combine in registers with pvc; write h to H[cur^1]
      char* Hn = Hb[cur^1];
      #pragma unroll
      for (int m=0;m<2;m++)
        #pragma unroll
        for (int q=0;q<4;q++){
          int r = m*16 + kq*4 + q;
          if (t < mylen[m*4+q]){
            s16x4 p = pvc[m*4+q];
            float gi = D[m][0][q] + bf2f(p[0]);
            float gf = D[m][1][q] + bf2f(p[1]);
            float gg = D[m][2][q] + bf2f(p[2]);
            float go = D[m][3][q] + bf2f(p[3]);
            int idx = m*4+q;
            cst[idx] = sigf(gf)*cst[idx] + sigf(gi)*tanh_f(gg);
            float h = sigf(go)*tanh_f(cst[idx]);
            hreg[idx] = h;
            *(short*)(Hn + ((r*256 + d_own*2) ^ ((r&7)<<4))) = (short)f2bf(h);
          }
        }
      // prefetch eid[t+2] into slot (t&1)
      if (tid < 32){
        int ln = M[tid];
        M[64 + ((t&1)<<5) + tid] = (t+2 < ln) ? list[M[32+tid] + t+2] : 0;
      }
      __syncthreads();
      #pragma unroll
      for (int i=0;i<8;i++) pvc[i] = pvn[i];
      cur ^= 1;
    }
    // emb writes (binning already excluded overwritten src chains)
    #pragma unroll
    for (int m=0;m<2;m++)
      #pragma unroll
      for (int q=0;q<4;q++){
        int r = m*16 + kq*4 + q;
        int n = M[128+r];
        if (mylen[m*4+q] > 0 && n >= 0){
          emb[(size_t)n*128 + d_own] = hreg[m*4+q];
        }
      }
    __syncthreads();
  }
}

// ---------------- MFMA MLP: 32 nodes/block, fc1 GEMM + LN + out ----------------
__global__ __launch_bounds__(512) void k_mlp2(
    const float* __restrict__ x, const float* __restrict__ emb,
    const short* __restrict__ fc1wbf, const float* __restrict__ fc1b,
    const float* __restrict__ lng, const float* __restrict__ lnb,
    const float* __restrict__ outw, const float* __restrict__ outb,
    float* __restrict__ out){
  __shared__ char As[32*768];          // bf16 [32][384], XOR-swizzled rows
  __shared__ float hbuf[32][132];
  int tid = threadIdx.x;
  int lane = tid & 63, w = tid >> 6;
  int base = blockIdx.x * 32;
  #pragma unroll
  for (int q=0;q<3;q++){
    int i = tid + 512*q;              // 0..1535, 48 chunks of 8 per row
    int r = i / 48, c = i - r*48;
    const float* src = (c < 32) ? (x + (size_t)(base+r)*256 + c*8)
                                : (emb + (size_t)(base+r)*128 + (c-32)*8);
    float4 v0 = *(const float4*)src;
    float4 v1 = *(const float4*)(src+4);
    s16x8 v8;
    v8[0]=(short)f2bf(v0.x); v8[1]=(short)f2bf(v0.y); v8[2]=(short)f2bf(v0.z); v8[3]=(short)f2bf(v0.w);
    v8[4]=(short)f2bf(v1.x); v8[5]=(short)f2bf(v1.y); v8[6]=(short)f2bf(v1.z); v8[7]=(short)f2bf(v1.w);
    *(s16x8*)(As + ((r*768 + c*16) ^ ((r&7)<<4))) = v8;
  }
  __syncthreads();
  int cl = lane & 15, kq = lane >> 4;
  f32x4 D0 = {0.f,0.f,0.f,0.f}, D1 = {0.f,0.f,0.f,0.f};
  const short* bp = fc1wbf + (size_t)(w*16 + cl)*384 + kq*8;
  #pragma unroll
  for (int ks=0; ks<12; ks++){
    s16x8 b = *(const s16x8*)(bp + ks*32);
    int kb = ks*64 + kq*16;
    s16x8 a0 = *(const s16x8*)(As + (((cl   )*768 + kb) ^ ((cl&7)<<4)));
    s16x8 a1 = *(const s16x8*)(As + (((cl+16)*768 + kb) ^ (((cl+16)&7)<<4)));
    D0 = __builtin_amdgcn_mfma_f32_16x16x32_bf16(a0, b, D0, 0, 0, 0);
    D1 = __builtin_amdgcn_mfma_f32_16x16x32_bf16(a1, b, D1, 0, 0, 0);
  }
  int col = w*16 + cl;
  float bb = fc1b[col];
  #pragma unroll
  for (int q=0;q<4;q++){
    hbuf[kq*4+q][col]    = D0[q] + bb;
    hbuf[16+kq*4+q][col] = D1[q] + bb;
  }
  __syncthreads();
  int sub = lane >> 4, l16 = lane & 15;
  int nd = w*4 + sub;
  float v[8];
  float s = 0.f;
  #pragma unroll
  for (int j=0;j<8;j++){ v[j] = hbuf[nd][l16*8+j]; s += v[j]; }
  #pragma unroll
  for (int m=1;m<16;m<<=1) s += __shfl_xor(s, m);
  float mu = s * (1.f/128.f);
  float va = 0.f;
  #pragma unroll
  for (int j=0;j<8;j++){ float dm = v[j]-mu; va += dm*dm; }
  #pragma unroll
  for (int m=1;m<16;m<<=1) va += __shfl_xor(va, m);
  float rstd = rsqrtf(va*(1.f/128.f) + 1e-5f);
  float o0=0.f, o1=0.f;
  #pragma unroll
  for (int j=0;j<8;j++){
    int c = l16*8+j;
    float h1 = (v[j]-mu)*rstd*lng[c] + lnb[c];
    h1 = fmaxf(h1, 0.f);
    o0 += h1*outw[c]; o1 += h1*outw[128+c];
  }
  #pragma unroll
  for (int m=1;m<16;m<<=1){ o0 += __shfl_xor(o0,m); o1 += __shfl_xor(o1,m); }
  if (l16==0){
    out[(size_t)(base+nd)*2]   = o0 + outb[0];
    out[(size_t)(base+nd)*2+1] = o1 + outb[1];
  }
}

extern "C" void kernel_launch(void* const* d_in, const int* in_sizes, int n_in,
                              void* d_out, int out_size, void* d_ws, size_t ws_size,
                              hipStream_t stream){
  const float* x      = (const float*)d_in[0];
  const int*   heads  = (const int*)d_in[1];
  const int*   rels   = (const int*)d_in[2];
  const int*   tails  = (const int*)d_in[3];
  const float* weeks  = (const float*)d_in[4];
  const int*   esrc   = (const int*)d_in[5];
  const int*   edst   = (const int*)d_in[6];
  const float* ent    = (const float*)d_in[10];
  const float* rel_e  = (const float*)d_in[11];
  const float* wfreq  = (const float*)d_in[12];
  const float* wphi   = (const float*)d_in[13];
  const float* wamp   = (const float*)d_in[14];
  const float* Wih    = (const float*)d_in[15];
  const float* Whh    = (const float*)d_in[16];
  const float* bih    = (const float*)d_in[17];
  const float* bhh    = (const float*)d_in[18];
  const float* fc1w   = (const float*)d_in[19];
  const float* fc1b   = (const float*)d_in[20];
  const float* lng    = (const float*)d_in[21];
  const float* lnb    = (const float*)d_in[22];
  const float* outw   = (const float*)d_in[23];
  const float* outb   = (const float*)d_in[24];
  float* out = (float*)d_out;

  char* ws = (char*)d_ws;
  size_t off = 0;
  auto alloc = [&](size_t bytes){ void* p = ws + off; off += (bytes + 255) & ~(size_t)255; return p; };
  short* pre2b  = (short*)alloc((size_t)N_EDGES*512*2);
  short* scores = (short*)alloc((size_t)N_EDGES*128*2);
  short* WihB   = (short*)alloc(512*128*2);
  short* WhhB2  = (short*)alloc(512*128*2);
  short* fc1wbf = (short*)alloc(128*384*2);
  float* emb    = (float*)alloc((size_t)N_NODES*128*4);
  int* sstart   = (int*)alloc((N_NODES+1)*4);
  int* dstart   = (int*)alloc((N_NODES+1)*4);
  int* zreg     = (int*)alloc((size_t)(4*N_NODES + 3)*4);
  int* scnt = zreg, *dcnt = zreg+N_NODES, *sc2 = zreg+2*N_NODES, *dc2 = zreg+3*N_NODES;
  int* nchains  = zreg + 4*N_NODES;
  int* ctr      = nchains + 2;
  int* bhist    = (int*)alloc((size_t)128*NBLK*4);
  int* boff     = (int*)alloc((size_t)128*NBLK*4);
  int* slist    = (int*)alloc(N_EDGES*4);
  int* dlist    = (int*)alloc(N_EDGES*4);
  int* cnode    = (int*)alloc((size_t)2*N_NODES*4);
  int* cstart   = (int*)alloc((size_t)2*N_NODES*4);
  int* clen     = (int*)alloc((size_t)2*N_NODES*4);

  hipMemsetAsync(zreg, 0, (size_t)(4*N_NODES + 3)*4, stream);
  hipMemsetAsync(emb, 0, (size_t)N_NODES*128*4, stream);

  k_prep<<<(180224+255)/256, 256, 0, stream>>>(Wih, Whh, fc1w, WihB, WhhB2, fc1wbf);

  k_gather<<<N_EDGES*16/256, 256, 0, stream>>>(heads, rels, tails, weeks, ent, rel_e,
                                               wfreq, wphi, wamp, scores);
  k_pregemm<<<N_EDGES/32, 256, 0, stream>>>(scores, WihB, bih, bhh, pre2b);
  k_hist<<<(N_EDGES+255)/256, 256, 0, stream>>>(esrc, edst, scnt, dcnt);
  k_scan<<<2, 1024, 0, stream>>>(scnt, dcnt, sstart, dstart);
  k_scatter<<<(N_EDGES+255)/256, 256, 0, stream>>>(esrc, edst, sstart, dstart, sc2, dc2, slist, dlist);
  k_sortlists<<<(N_NODES+255)/256, 256, 0, stream>>>(sstart, dstart, slist, dlist);
  k_cbin1<<<NBLK, 256, 0, stream>>>(sstart, dstart, bhist);
  k_cbin2<<<1, 1024, 0, stream>>>(bhist, boff, nchains);
  k_cbin3<<<NBLK, 256, 0, stream>>>(sstart, dstart, boff, nchains, cnode, cstart, clen);
  k_lstm6<<<256, 512, 0, stream>>>(pre2b, WhhB2, cnode, cstart, clen, nchains,
                                   slist, dlist, ctr, emb);
  k_mlp2<<<N_NODES/32, 512, 0, stream>>>(x, emb, fc1wbf, fc1b, lng, lnb, outw, outb, out);
}

// Round 11
// 170.441 us; speedup vs baseline: 5.7707x; 1.0627x over previous
//
#include <hip/hip_runtime.h>
#include <math.h>

#define N_NODES 20000
#define N_EDGES 40000
#define SE 46
#define TE 82
#define NBLK 79   // ceil(N_NODES/256)
// D = 128, 4D = 512, F = 256, HID = 128

typedef short  s16x8 __attribute__((ext_vector_type(8)));
typedef short  s16x4 __attribute__((ext_vector_type(4)));
typedef float  f32x4 __attribute__((ext_vector_type(4)));

__device__ __forceinline__ float sigf(float x){ return 1.0f/(1.0f+__expf(-x)); }
__device__ __forceinline__ float tanh_f(float x){ return 1.0f - 2.0f/(__expf(2.0f*x)+1.0f); }
__device__ __forceinline__ int perm_out(int i){ return (i&3)*128 + (i>>2); }
__device__ __forceinline__ unsigned short f2bf(float f){
  unsigned u = __builtin_bit_cast(unsigned, f);
  unsigned r = (u + 0x7fff + ((u>>16)&1)) >> 16;
  return (unsigned short)r;
}
__device__ __forceinline__ float bf2f(short s){
  unsigned u = ((unsigned)(unsigned short)s) << 16;
  return __builtin_bit_cast(float, u);
}

#define GATHER_BLKS 2500
#define PREP_BLKS   704
#define HIST_BLKS   157
#define FRONT_BLKS  (GATHER_BLKS + PREP_BLKS + HIST_BLKS)

// ---------------- fused front: gather | weight-prep | hist ----------------
__global__ __launch_bounds__(256) void k_front(
    const int* __restrict__ heads, const int* __restrict__ rels,
    const int* __restrict__ tails, const float* __restrict__ weeks,
    const float* __restrict__ ent, const float* __restrict__ rel_embs,
    const float* __restrict__ wfreq, const float* __restrict__ wphi,
    const float* __restrict__ wamp, short* __restrict__ scores,
    const float* __restrict__ Wih, const float* __restrict__ Whh,
    const float* __restrict__ fc1w,
    short* __restrict__ WihB, short* __restrict__ WhhB2, short* __restrict__ fc1wbf,
    const int* __restrict__ esrc, const int* __restrict__ edst,
    int* __restrict__ scnt, int* __restrict__ dcnt){
  int blk = blockIdx.x, tid = threadIdx.x;
  if (blk < GATHER_BLKS){
    int c = blk*256 + tid;            // 640000 chunks
    int e = c >> 4, d0 = (c & 15) << 3;
    int hd = heads[e], tl = tails[e], rl = rels[e];
    float wk = weeks[e];
    float hv[8], tv[8];
    if (d0 + 8 <= SE){
      const float* hp = ent + (size_t)hd*SE + d0;
      const float* tp = ent + (size_t)tl*SE + d0;
      #pragma unroll
      for (int j=0;j<4;j++){
        float2 a = *(const float2*)(hp + j*2); hv[2*j]=a.x; hv[2*j+1]=a.y;
        float2 b = *(const float2*)(tp + j*2); tv[2*j]=b.x; tv[2*j+1]=b.y;
      }
    } else if (d0 >= 48){
      int dt = d0 - SE;
      const float *hf = wfreq + (size_t)hd*TE + dt, *hp2 = wphi + (size_t)hd*TE + dt, *ha = wamp + (size_t)hd*TE + dt;
      const float *tf = wfreq + (size_t)tl*TE + dt, *tp2 = wphi + (size_t)tl*TE + dt, *ta = wamp + (size_t)tl*TE + dt;
      #pragma unroll
      for (int j=0;j<4;j++){
        float2 f_h = *(const float2*)(hf + j*2);
        float2 p_h = *(const float2*)(hp2 + j*2);
        float2 a_h = *(const float2*)(ha + j*2);
        float2 f_t = *(const float2*)(tf + j*2);
        float2 p_t = *(const float2*)(tp2 + j*2);
        float2 a_t = *(const float2*)(ta + j*2);
        hv[2*j]   = a_h.x*__sinf(f_h.x*wk + p_h.x);
        hv[2*j+1] = a_h.y*__sinf(f_h.y*wk + p_h.y);
        tv[2*j]   = a_t.x*__sinf(f_t.x*wk + p_t.x);
        tv[2*j+1] = a_t.y*__sinf(f_t.y*wk + p_t.y);
      }
    } else {
      #pragma unroll
      for (int j=0;j<8;j++){
        int d = 40 + j;
        if (d < SE){
          hv[j] = ent[(size_t)hd*SE + d];
          tv[j] = ent[(size_t)tl*SE + d];
        } else {
          int dt = d - SE;
          hv[j] = wamp[(size_t)hd*TE+dt]*__sinf(wfreq[(size_t)hd*TE+dt]*wk + wphi[(size_t)hd*TE+dt]);
          tv[j] = wamp[(size_t)tl*TE+dt]*__sinf(wfreq[(size_t)tl*TE+dt]*wk + wphi[(size_t)tl*TE+dt]);
        }
      }
    }
    const float* rp = rel_embs + rl*128 + d0;
    float4 r0 = *(const float4*)rp, r1 = *(const float4*)(rp+4);
    float rv[8] = {r0.x,r0.y,r0.z,r0.w, r1.x,r1.y,r1.z,r1.w};
    s16x8 o;
    #pragma unroll
    for (int j=0;j<8;j++) o[j] = (short)f2bf(hv[j]*rv[j]*tv[j]);
    *(s16x8*)(scores + (size_t)e*128 + d0) = o;
  } else if (blk < GATHER_BLKS + PREP_BLKS){
    int idx = (blk - GATHER_BLKS)*256 + tid;
    if (idx < 65536){
      int i = idx >> 7, k = idx & 127;
      WihB[idx] = (short)f2bf(Wih[perm_out(i)*128 + k]);
    } else if (idx < 131072){
      int j = idx - 65536;
      WhhB2[j] = (short)f2bf(Whh[j]);
    } else if (idx < 180224){
      int j = idx - 131072;
      fc1wbf[j] = (short)f2bf(fc1w[j]);
    }
  } else {
    int e = (blk - GATHER_BLKS - PREP_BLKS)*256 + tid;
    if (e < N_EDGES){ atomicAdd(&scnt[esrc[e]],1); atomicAdd(&dcnt[edst[e]],1); }
  }
}

// ---------------- MFMA GEMM: pre2b = bf16(perm(scores @ Wih^T + bih + bhh)) ----------------
__global__ __launch_bounds__(256) void k_pregemm(
    const short* __restrict__ scores, const short* __restrict__ WihB,
    const float* __restrict__ bih, const float* __restrict__ bhh,
    short* __restrict__ pre2b){
  __shared__ char As[32*256];   // bf16 [32 edges][128 k], XOR-swizzled rows
  int e0 = blockIdx.x * 32;
  int tid = threadIdx.x;
  #pragma unroll
  for (int q=0;q<2;q++){
    int c = tid + 256*q;            // 0..511
    int el = c >> 4, k8 = c & 15;
    s16x8 v = *(const s16x8*)(scores + (size_t)(e0+el)*128 + k8*8);
    *(s16x8*)(As + ((el*256 + k8*16) ^ ((el&7)<<4))) = v;
  }
  __syncthreads();
  int lane = tid & 63, w = tid >> 6;
  int cl = lane & 15, kq = lane >> 4;
  s16x8 a[2][4];
  #pragma unroll
  for (int ks=0;ks<4;ks++){
    int kb = ks*64 + kq*16;
    a[0][ks] = *(const s16x8*)(As + (((cl   )*256 + kb) ^ ((cl&7)<<4)));
    a[1][ks] = *(const s16x8*)(As + (((cl+16)*256 + kb) ^ (((cl+16)&7)<<4)));
  }
  f32x4 D[2][8];
  #pragma unroll
  for (int m=0;m<2;m++)
    #pragma unroll
    for (int i=0;i<8;i++) D[m][i] = (f32x4){0.f,0.f,0.f,0.f};
  #pragma unroll
  for (int i=0;i<8;i++){
    int n = w*128 + i*16 + cl;
    const short* bp = WihB + (size_t)n*128 + kq*8;
    #pragma unroll
    for (int ks=0;ks<4;ks++){
      s16x8 b = *(const s16x8*)(bp + ks*32);
      D[0][i] = __builtin_amdgcn_mfma_f32_16x16x32_bf16(a[0][ks], b, D[0][i], 0, 0, 0);
      D[1][i] = __builtin_amdgcn_mfma_f32_16x16x32_bf16(a[1][ks], b, D[1][i], 0, 0, 0);
    }
  }
  #pragma unroll
  for (int i=0;i<8;i++){
    int n = w*128 + i*16 + cl;
    int pn = perm_out(n);
    float bb = bih[pn] + bhh[pn];
    #pragma unroll
    for (int m=0;m<2;m++){
      #pragma unroll
      for (int q2=0;q2<4;q2++){
        int row = m*16 + kq*4 + q2;
        pre2b[(size_t)(e0+row)*512 + n] = (short)f2bf(D[m][i][q2] + bb);
      }
    }
  }
}

// ---------------- scan (2 blocks x 1024) ----------------
__global__ void k_scan(const int* __restrict__ scnt, const int* __restrict__ dcnt,
                       int* __restrict__ sstart, int* __restrict__ dstart){
  const int* cnt = blockIdx.x ? dcnt : scnt;
  int* start = blockIdx.x ? dstart : sstart;
  const int CH = 20;
  int tid = threadIdx.x;
  int base = tid*CH;
  int v[CH]; int tsum = 0;
  #pragma unroll
  for (int j=0;j<CH;j++){ int i = base+j; v[j] = (i<N_NODES)? cnt[i] : 0; tsum += v[j]; }
  int lane = tid & 63, wv = tid >> 6;
  int incl = tsum;
  #pragma unroll
  for (int m=1;m<64;m<<=1){ int u = __shfl_up(incl, m); if (lane >= m) incl += u; }
  __shared__ int wsum[16], woff[16];
  if (lane==63) wsum[wv] = incl;
  __syncthreads();
  if (tid < 16){ int s=0; for (int k=0;k<tid;k++) s += wsum[k]; woff[tid]=s; }
  __syncthreads();
  int run = woff[wv] + incl - tsum;
  #pragma unroll
  for (int j=0;j<CH;j++){ int i = base+j; if (i<N_NODES) start[i] = run; run += v[j]; }
  if (tid == 1023) start[N_NODES] = run;
}

// ---------------- scatter (dst only; src list is identity) + cbin1 ----------------
__global__ __launch_bounds__(256) void k_scatcb1(
    const int* __restrict__ edst, const int* __restrict__ dstart,
    int* __restrict__ dc2, int* __restrict__ dlist,
    const int* __restrict__ sstart, int* __restrict__ bhist){
  int blk = blockIdx.x, tid = threadIdx.x;
  if (blk < HIST_BLKS){
    int e = blk*256 + tid;
    if (e < N_EDGES){
      int d = edst[e]; int p2 = dstart[d] + atomicAdd(&dc2[d],1); dlist[p2]=e;
    }
  } else {
    __shared__ int h[128];
    int b2 = blk - HIST_BLKS;
    if (tid < 128) h[tid] = 0;
    __syncthreads();
    int n = b2*256 + tid;
    if (n < N_NODES){
      int c  = sstart[n+1]-sstart[n];
      int c2 = dstart[n+1]-dstart[n];
      if (c>0 && c2==0) atomicAdd(&h[min(c,63)], 1);
      if (c2>0) atomicAdd(&h[64+min(c2,63)], 1);
    }
    __syncthreads();
    if (tid < 128) bhist[tid*NBLK + b2] = h[tid];
  }
}

__device__ __forceinline__ int mapbin(int s){
  int p = s / (63*NBLK);
  int r = s - p*63*NBLK;
  int li = r / NBLK;
  int b  = r - li*NBLK;
  int l  = 63 - li;
  return (p*64 + l)*NBLK + b;
}

// ---------------- sort dlist groups + cbin2 (256-thread two-pass scan) ----------------
__global__ __launch_bounds__(256) void k_sortcb2(
    const int* __restrict__ dstart, int* __restrict__ dlist,
    const int* __restrict__ bhist, int* __restrict__ boff,
    int* __restrict__ nchains){
  int blk = blockIdx.x, tid = threadIdx.x;
  __shared__ int wsum[4];
  __shared__ int pend[2];
  if (blk < NBLK){
    int n = blk*256 + tid;
    if (n < N_NODES){
      int a = dstart[n], b = dstart[n+1];
      for (int i=a+1;i<b;i++){
        int v = dlist[i]; int j=i-1;
        while (j>=a && dlist[j]>v){ dlist[j+1]=dlist[j]; j--; }
        dlist[j+1]=v;
      }
    }
  } else {
    const int S = 2*63*NBLK;   // 9954
    const int CH2 = 39;        // 256*39 = 9984
    int tsum = 0;
    for (int j=0;j<CH2;j++){
      int s = tid*CH2 + j;
      if (s < S) tsum += bhist[mapbin(s)];
    }
    int lane = tid & 63, wv = tid >> 6;
    int incl = tsum;
    #pragma unroll
    for (int m=1;m<64;m<<=1){ int u = __shfl_up(incl, m); if (lane >= m) incl += u; }
    if (lane==63) wsum[wv] = incl;
    __syncthreads();
    int woff = 0;
    for (int k=0;k<wv;k++) woff += wsum[k];
    int run = woff + incl - tsum;
    for (int j=0;j<CH2;j++){
      int s = tid*CH2 + j;
      if (s < S){
        int bi = mapbin(s);
        int val = bhist[bi];
        boff[bi] = run;
        run += val;
        if (s == 63*NBLK - 1) pend[0] = run;
        if (s == S - 1)       pend[1] = run;
      }
    }
    __syncthreads();
    if (tid == 0){
      nchains[0] = pend[0];
      nchains[1] = pend[1] - pend[0];
    }
  }
}

// ---------------- cbin3: chain compaction + emb-valid flags ----------------
__global__ void k_cbin3(const int* __restrict__ sstart, const int* __restrict__ dstart,
                        const int* __restrict__ boff, const int* __restrict__ nchains,
                        int* __restrict__ cnode, int* __restrict__ cstart,
                        int* __restrict__ clen, int* __restrict__ degf){
  __shared__ int h[128];
  int tid = threadIdx.x, blk = blockIdx.x;
  if (tid < 128) h[tid] = 0;
  __syncthreads();
  int n = blk*256 + tid;
  int bin0=-1, bin1=-1, r0=0, r1=0, a0=0, c0=0, a1=0, c1=0;
  if (n < N_NODES){
    a0 = sstart[n]; c0 = sstart[n+1]-a0;
    a1 = dstart[n]; c1 = dstart[n+1]-a1;
    degf[n] = (c0+c1 > 0) ? 1 : 0;
    if (c0>0 && c1==0){ bin0 = min(c0,63);    r0 = atomicAdd(&h[bin0], 1); }
    if (c1>0)         { bin1 = 64+min(c1,63); r1 = atomicAdd(&h[bin1], 1); }
  }
  __syncthreads();
  int nch0 = nchains[0];
  if (bin0 >= 0){
    int pos = boff[bin0*NBLK + blk] + r0;
    cnode[pos] = n; cstart[pos] = a0; clen[pos] = c0;
  }
  if (bin1 >= 0){
    int pos = boff[bin1*NBLK + blk] + r1 - nch0;
    cnode[N_NODES+pos] = n; cstart[N_NODES+pos] = a1; clen[N_NODES+pos] = c1;
  }
}

// ---------------- persistent MFMA LSTM v7: Whh in registers, early eid prefetch ----------------
__global__ __launch_bounds__(512, 1) void k_lstm7(
    const short* __restrict__ pre2b, const short* __restrict__ WhhB2,
    const int* __restrict__ cnode, const int* __restrict__ cstart,
    const int* __restrict__ clen, const int* __restrict__ nchains,
    const int* __restrict__ dlist, int* __restrict__ ctr,
    float* __restrict__ emb){
  __shared__ char Hb[2][8192];
  __shared__ int M[161];
  int tid = threadIdx.x;
  int lane = tid & 63, wv = tid >> 6;
  int cl = lane & 15, kq = lane >> 4;
  int d_own = wv*16 + cl;
  s16x8 wf[4][4];
  #pragma unroll
  for (int i=0;i<4;i++)
    #pragma unroll
    for (int ks=0;ks<4;ks++)
      wf[i][ks] = *(const s16x8*)(WhhB2 + (size_t)(i*128 + d_own)*128 + ks*32 + kq*8);
  int nch0 = nchains[0], nch1 = nchains[1];
  int B0 = (nch0+31)>>5, B1 = (nch1+31)>>5;
  while (true){
    if (tid==0) M[160] = atomicAdd(ctr, 1);
    __syncthreads();
    int nb = M[160];
    if (nb >= B0 + B1) break;
    int pass = (nb >= B0) ? 1 : 0;
    int batch = pass ? nb - B0 : nb;
    int b0 = batch << 5;
    int nch = pass ? nch1 : nch0;
    if (tid < 32){
      int j = b0 + tid;
      int valid = (j < nch);
      int ci = pass*N_NODES + j;
      int st = valid ? cstart[ci] : 0;
      int ln = valid ? clen[ci] : 0;
      M[tid] = ln; M[32+tid] = st; M[128+tid] = valid ? cnode[ci] : -1;
      M[64+tid] = (ln > 0) ? (pass ? dlist[st]   : st  ) : 0;
      M[96+tid] = (ln > 1) ? (pass ? dlist[st+1] : st+1) : 0;
    }
    *(unsigned long long*)(&Hb[0][tid*16])   = 0ull;
    *(unsigned long long*)(&Hb[0][tid*16+8]) = 0ull;
    float cst[8]  = {0.f,0.f,0.f,0.f,0.f,0.f,0.f,0.f};
    float hreg[8] = {0.f,0.f,0.f,0.f,0.f,0.f,0.f,0.f};
    __syncthreads();
    int mylen[8];
    #pragma unroll
    for (int m=0;m<2;m++)
      #pragma unroll
      for (int q=0;q<4;q++) mylen[m*4+q] = M[m*16 + kq*4 + q];
    int ml = 0;
    #pragma unroll 1
    for (int j=0;j<32;j++) ml = max(ml, M[j]);
    // preload pv for t=0 (slot 0)
    s16x4 pvc[8];
    #pragma unroll
    for (int m=0;m<2;m++)
      #pragma unroll
      for (int q=0;q<4;q++){
        int r = m*16 + kq*4 + q;
        pvc[m*4+q] = *(const s16x4*)(pre2b + (size_t)M[64+r]*512 + d_own*4);
      }
    __syncthreads();   // protect slot 0 from t=0's early prefetch write
    int cur = 0;
    for (int t=0; t<ml; t++){
      // early eid prefetch for t+2 into slot (t&1) (overlaps MFMA below)
      if (tid < 32){
        int ln = M[tid];
        int nxt = M[32+tid] + t + 2;
        M[64 + ((t&1)<<5) + tid] = (t+2 < ln) ? (pass ? dlist[nxt] : nxt) : 0;
      }
      // issue pv loads for t+1 from slot ((t+1)&1)
      s16x4 pvn[8];
      const int* eidN = M + 64 + (((t+1)&1)<<5);
      #pragma unroll
      for (int m=0;m<2;m++)
        #pragma unroll
        for (int q=0;q<4;q++){
          int r = m*16 + kq*4 + q;
          pvn[m*4+q] = *(const s16x4*)(pre2b + (size_t)eidN[r]*512 + d_own*4);
        }
      // MFMA from H[cur] x wf (registers)
      f32x4 D[2][4];
      #pragma unroll
      for (int m=0;m<2;m++)
        #pragma unroll
        for (int i=0;i<4;i++) D[m][i] = (f32x4){0.f,0.f,0.f,0.f};
      char* Hc = Hb[cur];
      #pragma unroll
      for (int ks=0; ks<4; ks++){
        int kb = ks*64 + kq*16;
        s16x8 a0 = *(const s16x8*)(Hc + (((cl   )*256 + kb) ^ ((cl&7)<<4)));
        s16x8 a1 = *(const s16x8*)(Hc + (((cl+16)*256 + kb) ^ (((cl+16)&7)<<4)));
        #pragma unroll
        for (int i=0;i<4;i++){
          D[0][i] = __builtin_amdgcn_mfma_f32_16x16x32_bf16(a0, wf[i][ks], D[0][i], 0, 0, 0);
          D[1][i] = __builtin_amdgcn_mfma_f32_16x16x32_bf16(a1, wf[i][ks], D[1][i], 0, 0, 0);
        }
      }
      // gate combine with pvc; write h to H[cur^1]
      char* Hn = Hb[cur^1];
      #pragma unroll
      for (int m=0;m<2;m++)
        #pragma unroll
        for (int q=0;q<4;q++){
          int r = m*16 + kq*4 + q;
          if (t < mylen[m*4+q]){
            s16x4 p = pvc[m*4+q];
            float gi = D[m][0][q] + bf2f(p[0]);
            float gf = D[m][1][q] + bf2f(p[1]);
            float gg = D[m][2][q] + bf2f(p[2]);
            float go = D[m][3][q] + bf2f(p[3]);
            int idx = m*4+q;
            cst[idx] = sigf(gf)*cst[idx] + sigf(gi)*tanh_f(gg);
            float h = sigf(go)*tanh_f(cst[idx]);
            hreg[idx] = h;
            *(short*)(Hn + ((r*256 + d_own*2) ^ ((r&7)<<4))) = (short)f2bf(h);
          }
        }
      __syncthreads();
      #pragma unroll
      for (int i=0;i<8;i++) pvc[i] = pvn[i];
      cur ^= 1;
    }
    #pragma unroll
    for (int m=0;m<2;m++)
      #pragma unroll
      for (int q=0;q<4;q++){
        int r = m*16 + kq*4 + q;
        int n = M[128+r];
        if (mylen[m*4+q] > 0 && n >= 0){
          emb[(size_t)n*128 + d_own] = hreg[m*4+q];
        }
      }
    __syncthreads();
  }
}

// ---------------- MFMA MLP: 32 nodes/block, degf-gated emb read ----------------
__global__ __launch_bounds__(512) void k_mlp2(
    const float* __restrict__ x, const float* __restrict__ emb,
    const int* __restrict__ degf,
    const short* __restrict__ fc1wbf, const float* __restrict__ fc1b,
    const float* __restrict__ lng, const float* __restrict__ lnb,
    const float* __restrict__ outw, const float* __restrict__ outb,
    float* __restrict__ out){
  __shared__ char As[32*768];          // bf16 [32][384], XOR-swizzled rows
  __shared__ float hbuf[32][132];
  int tid = threadIdx.x;
  int lane = tid & 63, w = tid >> 6;
  int base = blockIdx.x * 32;
  #pragma unroll
  for (int q=0;q<3;q++){
    int i = tid + 512*q;              // 0..1535, 48 chunks of 8 per row
    int r = i / 48, c = i - r*48;
    s16x8 v8 = {0,0,0,0,0,0,0,0};
    if (c < 32){
      const float* src = x + (size_t)(base+r)*256 + c*8;
      float4 v0 = *(const float4*)src;
      float4 v1 = *(const float4*)(src+4);
      v8[0]=(short)f2bf(v0.x); v8[1]=(short)f2bf(v0.y); v8[2]=(short)f2bf(v0.z); v8[3]=(short)f2bf(v0.w);
      v8[4]=(short)f2bf(v1.x); v8[5]=(short)f2bf(v1.y); v8[6]=(short)f2bf(v1.z); v8[7]=(short)f2bf(v1.w);
    } else if (degf[base+r]){
      const float* src = emb + (size_t)(base+r)*128 + (c-32)*8;
      float4 v0 = *(const float4*)src;
      float4 v1 = *(const float4*)(src+4);
      v8[0]=(short)f2bf(v0.x); v8[1]=(short)f2bf(v0.y); v8[2]=(short)f2bf(v0.z); v8[3]=(short)f2bf(v0.w);
      v8[4]=(short)f2bf(v1.x); v8[5]=(short)f2bf(v1.y); v8[6]=(short)f2bf(v1.z); v8[7]=(short)f2bf(v1.w);
    }
    *(s16x8*)(As + ((r*768 + c*16) ^ ((r&7)<<4))) = v8;
  }
  __syncthreads();
  int cl = lane & 15, kq = lane >> 4;
  f32x4 D0 = {0.f,0.f,0.f,0.f}, D1 = {0.f,0.f,0.f,0.f};
  const short* bp = fc1wbf + (size_t)(w*16 + cl)*384 + kq*8;
  #pragma unroll
  for (int ks=0; ks<12; ks++){
    s16x8 b = *(const s16x8*)(bp + ks*32);
    int kb = ks*64 + kq*16;
    s16x8 a0 = *(const s16x8*)(As + (((cl   )*768 + kb) ^ ((cl&7)<<4)));
    s16x8 a1 = *(const s16x8*)(As + (((cl+16)*768 + kb) ^ (((cl+16)&7)<<4)));
    D0 = __builtin_amdgcn_mfma_f32_16x16x32_bf16(a0, b, D0, 0, 0, 0);
    D1 = __builtin_amdgcn_mfma_f32_16x16x32_bf16(a1, b, D1, 0, 0, 0);
  }
  int col = w*16 + cl;
  float bb = fc1b[col];
  #pragma unroll
  for (int q=0;q<4;q++){
    hbuf[kq*4+q][col]    = D0[q] + bb;
    hbuf[16+kq*4+q][col] = D1[q] + bb;
  }
  __syncthreads();
  int sub = lane >> 4, l16 = lane & 15;
  int nd = w*4 + sub;
  float v[8];
  float s = 0.f;
  #pragma unroll
  for (int j=0;j<8;j++){ v[j] = hbuf[nd][l16*8+j]; s += v[j]; }
  #pragma unroll
  for (int m=1;m<16;m<<=1) s += __shfl_xor(s, m);
  float mu = s * (1.f/128.f);
  float va = 0.f;
  #pragma unroll
  for (int j=0;j<8;j++){ float dm = v[j]-mu; va += dm*dm; }
  #pragma unroll
  for (int m=1;m<16;m<<=1) va += __shfl_xor(va, m);
  float rstd = rsqrtf(va*(1.f/128.f) + 1e-5f);
  float o0=0.f, o1=0.f;
  #pragma unroll
  for (int j=0;j<8;j++){
    int c = l16*8+j;
    float h1 = (v[j]-mu)*rstd*lng[c] + lnb[c];
    h1 = fmaxf(h1, 0.f);
    o0 += h1*outw[c]; o1 += h1*outw[128+c];
  }
  #pragma unroll
  for (int m=1;m<16;m<<=1){ o0 += __shfl_xor(o0,m); o1 += __shfl_xor(o1,m); }
  if (l16==0){
    out[(size_t)(base+nd)*2]   = o0 + outb[0];
    out[(size_t)(base+nd)*2+1] = o1 + outb[1];
  }
}

extern "C" void kernel_launch(void* const* d_in, const int* in_sizes, int n_in,
                              void* d_out, int out_size, void* d_ws, size_t ws_size,
                              hipStream_t stream){
  const float* x      = (const float*)d_in[0];
  const int*   heads  = (const int*)d_in[1];
  const int*   rels   = (const int*)d_in[2];
  const int*   tails  = (const int*)d_in[3];
  const float* weeks  = (const float*)d_in[4];
  const int*   esrc   = (const int*)d_in[5];
  const int*   edst   = (const int*)d_in[6];
  const float* ent    = (const float*)d_in[10];
  const float* rel_e  = (const float*)d_in[11];
  const float* wfreq  = (const float*)d_in[12];
  const float* wphi   = (const float*)d_in[13];
  const float* wamp   = (const float*)d_in[14];
  const float* Wih    = (const float*)d_in[15];
  const float* Whh    = (const float*)d_in[16];
  const float* bih    = (const float*)d_in[17];
  const float* bhh    = (const float*)d_in[18];
  const float* fc1w   = (const float*)d_in[19];
  const float* fc1b   = (const float*)d_in[20];
  const float* lng    = (const float*)d_in[21];
  const float* lnb    = (const float*)d_in[22];
  const float* outw   = (const float*)d_in[23];
  const float* outb   = (const float*)d_in[24];
  float* out = (float*)d_out;

  char* ws = (char*)d_ws;
  size_t off = 0;
  auto alloc = [&](size_t bytes){ void* p = ws + off; off += (bytes + 255) & ~(size_t)255; return p; };
  short* pre2b  = (short*)alloc((size_t)N_EDGES*512*2);
  short* scores = (short*)alloc((size_t)N_EDGES*128*2);
  short* WihB   = (short*)alloc(512*128*2);
  short* WhhB2  = (short*)alloc(512*128*2);
  short* fc1wbf = (short*)alloc(128*384*2);
  float* emb    = (float*)alloc((size_t)N_NODES*128*4);
  int* sstart   = (int*)alloc((N_NODES+1)*4);
  int* dstart   = (int*)alloc((N_NODES+1)*4);
  int* zreg     = (int*)alloc((size_t)(3*N_NODES + 3)*4);
  int* scnt = zreg, *dcnt = zreg+N_NODES, *dc2 = zreg+2*N_NODES;
  int* nchains  = zreg + 3*N_NODES;
  int* ctr      = nchains + 2;
  int* bhist    = (int*)alloc((size_t)128*NBLK*4);
  int* boff     = (int*)alloc((size_t)128*NBLK*4);
  int* dlist    = (int*)alloc(N_EDGES*4);
  int* cnode    = (int*)alloc((size_t)2*N_NODES*4);
  int* cstart   = (int*)alloc((size_t)2*N_NODES*4);
  int* clen     = (int*)alloc((size_t)2*N_NODES*4);
  int* degf     = (int*)alloc((size_t)N_NODES*4);

  hipMemsetAsync(zreg, 0, (size_t)(3*N_NODES + 3)*4, stream);

  k_front<<<FRONT_BLKS, 256, 0, stream>>>(heads, rels, tails, weeks, ent, rel_e,
                                          wfreq, wphi, wamp, scores,
                                          Wih, Whh, fc1w, WihB, WhhB2, fc1wbf,
                                          esrc, edst, scnt, dcnt);
  k_pregemm<<<N_EDGES/32, 256, 0, stream>>>(scores, WihB, bih, bhh, pre2b);
  k_scan<<<2, 1024, 0, stream>>>(scnt, dcnt, sstart, dstart);
  k_scatcb1<<<HIST_BLKS + NBLK, 256, 0, stream>>>(edst, dstart, dc2, dlist, sstart, bhist);
  k_sortcb2<<<NBLK + 1, 256, 0, stream>>>(dstart, dlist, bhist, boff, nchains);
  k_cbin3<<<NBLK, 256, 0, stream>>>(sstart, dstart, boff, nchains, cnode, cstart, clen, degf);
  k_lstm7<<<256, 512, 0, stream>>>(pre2b, WhhB2, cnode, cstart, clen, nchains,
                                   dlist, ctr, emb);
  k_mlp2<<<N_NODES/32, 512, 0, stream>>>(x, emb, degf, fc1wbf, fc1b, lng, lnb, outw, outb, out);
}